// Round 7
// baseline (225.863 us; speedup 1.0000x reference)
//
#include <hip/hip_runtime.h>
#include <stdint.h>
#include <math.h>

#define DEVFN __device__ __forceinline__
typedef unsigned short u16;
typedef short bf16x8 __attribute__((ext_vector_type(8)));
typedef float f32x4  __attribute__((ext_vector_type(4)));

// ---------------------------------------------------------------- helpers
DEVFN float blk_sum(float v, float* s4) {          // 256-thread block sum
  #pragma unroll
  for (int o = 32; o > 0; o >>= 1) v += __shfl_down(v, o, 64);
  __syncthreads();
  if ((threadIdx.x & 63) == 0) s4[threadIdx.x >> 6] = v;
  __syncthreads();
  return s4[0] + s4[1] + s4[2] + s4[3];
}

DEVFN float gelu_f(float x) {
  return 0.5f * x * (1.f + erff(x * 0.7071067811865475f));
}

DEVFN u16 bf16_rne(float f) {                      // fp32 -> bf16 round-nearest-even
  uint32_t u = __float_as_uint(f);
  return (u16)((u + 0x7fffu + ((u >> 16) & 1u)) >> 16);
}

DEVFN float bf2f(u16 v) { return __uint_as_float(((uint32_t)v) << 16); }

// ---------------------------------------------------------------- local tok
// patch embed + LN1 ; block per (b,s) token; eln written as bf16 (GEMM A).
// g_part: raw-x partials, 8x over-counted (full patch read per sub-position).
__global__ void k_l_tok(const float* __restrict__ x, const float* __restrict__ pw,
                        const float* __restrict__ pb, const float* __restrict__ g1,
                        const float* __restrict__ b1,
                        float* __restrict__ res, u16* __restrict__ eln_bf,
                        float* __restrict__ g_part) {
  __shared__ float pws[64], s4[4];
  int t = blockIdx.x;
  int b = t / 216, s = t % 216;
  int z = s / 36, y = (s / 6) % 6, xx = s % 6;
  int d = z >> 1, p1 = z & 1, hh = y >> 1, p2 = y & 1, ww = xx >> 1, p3 = xx & 1;
  int p = p1 * 4 + p2 * 2 + p3;
  int c = threadIdx.x;
  if (c < 64) pws[c] = pw[c];
  __syncthreads();
  const float* xb = x + (b * 256 + c) * 216 + (2 * d) * 36 + (2 * hh) * 6 + 2 * ww;
  float v = pb[p];
  float xs = 0.f;
  #pragma unroll
  for (int q1 = 0; q1 < 2; ++q1)
    #pragma unroll
    for (int q2 = 0; q2 < 2; ++q2)
      #pragma unroll
      for (int q3 = 0; q3 < 2; ++q3) {
        float xv = xb[q1 * 36 + q2 * 6 + q3];
        xs += xv;
        v += xv * pws[p * 8 + (q1 * 4 + q2 * 2 + q3)];
      }
  float bs = blk_sum(xs, s4);
  if (c == 0) g_part[t] = bs;
  res[t * 256 + c] = v;
  float mu = blk_sum(v, s4) * (1.f / 256.f);
  float dd = v - mu;
  float var = blk_sum(dd * dd, s4) * (1.f / 256.f);
  eln_bf[t * 256 + c] = bf16_rne(dd * rsqrtf(var + 1e-6f) * g1[c] + b1[c]);
}

// ---------------------------------------------------------------- global branch
// One fused kernel: tok+LN1 -> qkv -> rank-1 IN+softmax attn -> wo+LN2 -> mo+gelu.
// 8 blocks (one per batch); all intermediates in LDS.
__global__ __launch_bounds__(256) void k_g_fused(
    const float* __restrict__ g_part, const float* __restrict__ tw,
    const float* __restrict__ tb, const float* __restrict__ g1,
    const float* __restrict__ b1, const float* __restrict__ wq,
    const float* __restrict__ wk, const float* __restrict__ wv,
    const float* __restrict__ wo, const float* __restrict__ g2,
    const float* __restrict__ b2, const float* __restrict__ mow,
    const float* __restrict__ mob, float* __restrict__ g_vec) {
  __shared__ float ts[256], qk[3072], os[1024], t2s[256], s4[4];
  int b = blockIdx.x, tid = threadIdx.x;
  // tok + LN1 (g_part is 8x over-counted -> /442368)
  float acc0 = (tid < 216) ? g_part[b * 216 + tid] : 0.f;
  float m = blk_sum(acc0, s4) * (1.f / 442368.f);
  float tok = m * tw[tid] + tb[tid];
  float mu = blk_sum(tok, s4) * (1.f / 256.f);
  float dd = tok - mu;
  float var = blk_sum(dd * dd, s4) * (1.f / 256.f);
  ts[tid] = dd * rsqrtf(var + 1e-6f) * g1[tid] + b1[tid];
  __syncthreads();
  // qkv: 12 columns per thread, weights read coalesced
  float accq[12] = {};
  for (int c = 0; c < 256; ++c) {
    float tc = ts[c];
    #pragma unroll
    for (int j = 0; j < 12; ++j) {
      const float* W = (j < 4) ? wq : (j < 8) ? wk : wv;
      accq[j] = fmaf(tc, W[c * 1024 + (j & 3) * 256 + tid], accq[j]);
    }
  }
  #pragma unroll
  for (int j = 0; j < 12; ++j) qk[j * 256 + tid] = accq[j];
  __syncthreads();
  // rank-1 IN stats factor exactly; row-max skipped (standardized scores bounded)
  float A4[4], B4[4];
  #pragma unroll
  for (int hh = 0; hh < 4; ++hh) {
    float q = qk[hh * 256 + tid], k = qk[1024 + hh * 256 + tid];
    float sq = blk_sum(q, s4), sq2 = blk_sum(q * q, s4);
    float sk = blk_sum(k, s4), sk2 = blk_sum(k * k, s4);
    float tot = sq * sk * (1.f / 65536.f), tot2 = sq2 * sk2 * (1.f / 65536.f);
    float rstd = rsqrtf(tot2 - tot * tot + 1e-5f);
    A4[hh] = rstd; B4[hh] = -tot * rstd;
  }
  #pragma unroll
  for (int hh = 0; hh < 4; ++hh) {
    float q = qk[hh * 256 + tid];
    const float* kb = &qk[1024 + hh * 256];
    const float* vb = &qk[2048 + hh * 256];
    float den = 0.f, num = 0.f;
    for (int j = 0; j < 256; ++j) {
      float wgt = __expf(fmaf(q * kb[j], A4[hh], B4[hh]));
      den += wgt; num = fmaf(wgt, vb[j], num);
    }
    os[(tid << 2) + hh] = num / den;   // (c outer, h inner)
  }
  __syncthreads();
  // out = o @ wo ; +res ; LN2 ; gelu(mo_w @ t2 + mo_b)
  float acc2 = 0.f;
  for (int k = 0; k < 1024; ++k) acc2 = fmaf(os[k], wo[k * 256 + tid], acc2);
  float val = acc2 + tok;
  float mu2 = blk_sum(val, s4) * (1.f / 256.f);
  float d2 = val - mu2;
  float v2 = blk_sum(d2 * d2, s4) * (1.f / 256.f);
  t2s[tid] = d2 * rsqrtf(v2 + 1e-6f) * g2[tid] + b2[tid];
  __syncthreads();
  float a2 = mob[tid];
  for (int c = 0; c < 256; ++c) a2 = fmaf(t2s[c], mow[tid * 256 + c], a2);
  g_vec[b * 256 + tid] = gelu_f(a2);
}

// ---------------------------------------------------------------- weight prep
// tiled transpose + cast: in fp32 [R][C] -> out bf16 [C][R]
__global__ void k_trc(const float* __restrict__ in, u16* __restrict__ out,
                      int R, int C) {
  __shared__ float tile[32][33];
  int r0 = blockIdx.x * 32, c0 = blockIdx.y * 32;
  int tx = threadIdx.x & 31, ty = threadIdx.x >> 5;
  for (int i = ty; i < 32; i += 8) tile[i][tx] = in[(r0 + i) * C + c0 + tx];
  __syncthreads();
  for (int i = ty; i < 32; i += 8)
    out[(size_t)(c0 + i) * R + r0 + tx] = bf16_rne(tile[tx][i]);
}

__global__ void k_cast(const float* __restrict__ in, u16* __restrict__ out, int n) {
  int i = blockIdx.x * 256 + threadIdx.x;
  if (i < n) out[i] = bf16_rne(in[i]);
}

// ---------------------------------------------------------------- bf16 MFMA GEMM
// C[M][N] fp32 = A[M][K] bf16 @ BT[N][K] bf16  (B stored N-major = B^T)
// 64x64 tile, BK=32, 4 waves (2x2), 16x16x32 MFMA, 2x2 frags per wave.
__global__ __launch_bounds__(256) void k_gemm_bf16(
    const u16* __restrict__ A, const u16* __restrict__ BT,
    float* __restrict__ C, int M, int N, int K) {
  __shared__ __align__(16) u16 a_s[64][40];   // pad 40: 80B rows, 2-way max
  __shared__ __align__(16) u16 b_s[64][40];
  int tid = threadIdx.x;
  int rowblk = blockIdx.x * 64, colblk = blockIdx.y * 64;
  int sr = tid & 63, sk = (tid >> 6) * 8;     // staging: row, k-chunk
  int lane = tid & 63, w = tid >> 6;
  int wr = (w >> 1) * 32, wc = (w & 1) * 32;  // wave's 32x32 quadrant
  int fm = lane & 15, fk = (lane >> 4) * 8;   // frag: m/n idx, k-chunk
  f32x4 acc[2][2] = {};
  for (int kt = 0; kt < K; kt += 32) {
    __syncthreads();
    *(uint4*)&a_s[sr][sk] = *(const uint4*)&A[(size_t)(rowblk + sr) * K + kt + sk];
    *(uint4*)&b_s[sr][sk] = *(const uint4*)&BT[(size_t)(colblk + sr) * K + kt + sk];
    __syncthreads();
    bf16x8 bn[2];
    #pragma unroll
    for (int ni = 0; ni < 2; ++ni) bn[ni] = *(const bf16x8*)&b_s[wc + ni * 16 + fm][fk];
    #pragma unroll
    for (int mi = 0; mi < 2; ++mi) {
      bf16x8 af = *(const bf16x8*)&a_s[wr + mi * 16 + fm][fk];
      #pragma unroll
      for (int ni = 0; ni < 2; ++ni)
        acc[mi][ni] = __builtin_amdgcn_mfma_f32_16x16x32_bf16(af, bn[ni], acc[mi][ni], 0, 0, 0);
    }
  }
  int crow0 = rowblk + wr + (lane >> 4) * 4;
  int ccol  = colblk + wc + fm;
  #pragma unroll
  for (int mi = 0; mi < 2; ++mi)
    #pragma unroll
    for (int ni = 0; ni < 2; ++ni)
      #pragma unroll
      for (int r = 0; r < 4; ++r)
        C[(size_t)(crow0 + mi * 16 + r) * N + ccol + ni * 16] = acc[mi][ni][r];
}

// ---------------------------------------------------------------- local attention (MFMA)
// Block = (n,h), 256 threads = 4 waves. Q,K bf16x8 rows in LDS; V^T (+ones row
// for the denominator) in LDS. Per 64-j chunk: S^T tiles via mfma(K,Q) with
// K=8 zero-padded to 32 (A-frag zeroed for lanes>=16; B side then irrelevant),
// exp+RTZ-pack -> ds_write_b64 into P[q][j] (A-frag layout), then PV via
// mfma(P, V^T) accumulating num (cols 0..7) and den (col 8, the ones row).
// Each wave owns q-columns [w*64, w*64+64): P region is wave-private -> no
// barriers in the main loop. den broadcast to the group via ds_bpermute.
__global__ __launch_bounds__(256) void k_l_attn(const float* __restrict__ qkv,
                                                u16* __restrict__ o_buf) {
  __shared__ __align__(16) uint4 Qb[256], Kb[256];   // bf16x8 per row (k=0..7)
  __shared__ __align__(16) u16 vt[16][264];          // V^T: rows 0..7 V, 8 ones, 9..15 zero
  __shared__ __align__(16) u16 Pl[256][72];          // P[q][j-in-chunk], bf16
  __shared__ float rqA[64][4], rkA[64][4], rlq[64][4], rlk[64][4], s_ab[2];
  int n = blockIdx.x, h = blockIdx.y;
  int b = n / 27, patch = n % 27;
  int bz = 2 * (patch / 9), by = 2 * ((patch / 3) % 3), bx = 2 * (patch % 3);
  int tid = threadIdx.x;
  // ---- stage Q/K/V (thread per channel c)
  {
    int c = tid;
    float qv[8], kv[8], vv[8];
    #pragma unroll
    for (int p = 0; p < 8; ++p) {
      int t_l = b * 216 + (bz + (p >> 2)) * 36 + (by + ((p >> 1) & 1)) * 6 + (bx + (p & 1));
      const float* row = qkv + (size_t)t_l * 3072 + (c << 2) + h;
      qv[p] = row[0]; kv[p] = row[1024]; vv[p] = row[2048];
    }
    uint32_t qw[4], kw[4];
    #pragma unroll
    for (int i = 0; i < 4; ++i) {
      qw[i] = (uint32_t)bf16_rne(qv[2 * i]) | ((uint32_t)bf16_rne(qv[2 * i + 1]) << 16);
      kw[i] = (uint32_t)bf16_rne(kv[2 * i]) | ((uint32_t)bf16_rne(kv[2 * i + 1]) << 16);
    }
    Qb[c] = make_uint4(qw[0], qw[1], qw[2], qw[3]);
    Kb[c] = make_uint4(kw[0], kw[1], kw[2], kw[3]);
    #pragma unroll
    for (int p = 0; p < 8; ++p) vt[p][c] = bf16_rne(vv[p]);
    vt[8][c] = 0x3F80u;                  // bf16(1.0): denominator ones-row
    #pragma unroll
    for (int r2 = 9; r2 < 16; ++r2) vt[r2][c] = 0;
  }
  __syncthreads();
  // ---- InstanceNorm stats via Gram factorization (on bf16-rounded Q,K):
  // sum_ij s = sum_d (colsum q_d)(colsum k_d); sum_ij s^2 = <Q^TQ, K^TK>.
  {
    int p = tid & 63, chunk = tid >> 6;
    int d = p >> 3, e = p & 7;
    float aq = 0.f, ak = 0.f, lq = 0.f, lk = 0.f;
    for (int cc = chunk * 64; cc < chunk * 64 + 64; ++cc) {
      const u16* qr = (const u16*)&Qb[cc];
      const u16* kr = (const u16*)&Kb[cc];
      float qd = bf2f(qr[d]), qe = bf2f(qr[e]);
      float kd = bf2f(kr[d]), ke = bf2f(kr[e]);
      aq = fmaf(qd, qe, aq); ak = fmaf(kd, ke, ak);
      if (e == 0) { lq += qd; lk += kd; }
    }
    rqA[p][chunk] = aq; rkA[p][chunk] = ak; rlq[p][chunk] = lq; rlk[p][chunk] = lk;
    __syncthreads();
    if (tid < 64) {
      float gq = rqA[tid][0] + rqA[tid][1] + rqA[tid][2] + rqA[tid][3];
      float gk = rkA[tid][0] + rkA[tid][1] + rkA[tid][2] + rkA[tid][3];
      float vprod = gq * gk, vmu = 0.f;
      if ((tid & 7) == 0) {
        float slq = rlq[tid][0] + rlq[tid][1] + rlq[tid][2] + rlq[tid][3];
        float slk = rlk[tid][0] + rlk[tid][1] + rlk[tid][2] + rlk[tid][3];
        vmu = slq * slk;
      }
      #pragma unroll
      for (int o = 32; o > 0; o >>= 1) {
        vprod += __shfl_down(vprod, o, 64);
        vmu   += __shfl_down(vmu, o, 64);
      }
      if (tid == 0) {
        float mu = vmu * (1.f / 65536.f), m2 = vprod * (1.f / 65536.f);
        float rstd = rsqrtf(m2 - mu * mu + 1e-5f);
        s_ab[0] = rstd; s_ab[1] = -mu * rstd;
      }
    }
    __syncthreads();
  }
  float Af = s_ab[0], Bf = s_ab[1];
  int lane = tid & 63, w = tid >> 6;
  int l15 = lane & 15, lg = lane >> 4;
  // Q B-frags for this wave's 4 q-tiles (constant across chunks). Lanes>=16
  // read k-duplicate data; harmless since the A-frag is zero there.
  bf16x8 qf[4];
  #pragma unroll
  for (int qt = 0; qt < 4; ++qt)
    qf[qt] = *(const bf16x8*)&Qb[w * 64 + qt * 16 + l15];
  f32x4 acc_o[4] = {};
  #pragma unroll 1
  for (int jc = 0; jc < 4; ++jc) {
    bf16x8 kf[4];
    #pragma unroll
    for (int jt = 0; jt < 4; ++jt) {
      bf16x8 z = {};
      if (lg == 0) z = *(const bf16x8*)&Kb[jc * 64 + jt * 16 + l15];
      kf[jt] = z;                        // K=8 zero-padded to 32
    }
    // S^T tiles -> exp -> bf16 pack -> P (wave-private q columns)
    #pragma unroll
    for (int jt = 0; jt < 4; ++jt) {
      #pragma unroll
      for (int qt = 0; qt < 4; ++qt) {
        f32x4 zc = {};
        f32x4 s = __builtin_amdgcn_mfma_f32_16x16x32_bf16(kf[jt], qf[qt], zc, 0, 0, 0);
        float e0 = __expf(fmaf(s[0], Af, Bf));
        float e1 = __expf(fmaf(s[1], Af, Bf));
        float e2 = __expf(fmaf(s[2], Af, Bf));
        float e3 = __expf(fmaf(s[3], Af, Bf));
        uint32_t w0 = (__float_as_uint(e0) >> 16) | (__float_as_uint(e1) & 0xFFFF0000u);
        uint32_t w1 = (__float_as_uint(e2) >> 16) | (__float_as_uint(e3) & 0xFFFF0000u);
        int q = w * 64 + qt * 16 + l15;
        *(uint2*)&Pl[q][jt * 16 + lg * 4] = make_uint2(w0, w1);
      }
    }
    // PV over this chunk (K=64 -> 2 ksteps); den accumulates in col 8
    #pragma unroll
    for (int ks = 0; ks < 2; ++ks) {
      bf16x8 vf = *(const bf16x8*)&vt[l15][jc * 64 + ks * 32 + lg * 8];
      #pragma unroll
      for (int qt = 0; qt < 4; ++qt) {
        bf16x8 pf = *(const bf16x8*)&Pl[w * 64 + qt * 16 + l15][ks * 32 + lg * 8];
        acc_o[qt] = __builtin_amdgcn_mfma_f32_16x16x32_bf16(pf, vf, acc_o[qt], 0, 0, 0);
      }
    }
  }
  // ---- output: col l15 = p (0..7 num, 8 den); rows q = w*64+qt*16+lg*4+r
  int src = ((lane & 48) + 8) << 2;      // byte index of this group's den lane
  int p = l15;
  int t_l = b * 216 + (bz + (p >> 2)) * 36 + (by + ((p >> 1) & 1)) * 6 + (bx + (p & 1));
  #pragma unroll
  for (int qt = 0; qt < 4; ++qt) {
    #pragma unroll
    for (int r = 0; r < 4; ++r) {
      float den = __int_as_float(__builtin_amdgcn_ds_bpermute(src, __float_as_int(acc_o[qt][r])));
      if (p < 8) {
        int q = w * 64 + qt * 16 + lg * 4 + r;
        o_buf[(size_t)t_l * 1024 + (q << 2) + h] = bf16_rne(acc_o[qt][r] / den);
      }
    }
  }
}

// t2 = LN(proj + res) -> bf16 (mo-GEMM A)
__global__ void k_l_ln2(const float* __restrict__ proj, const float* __restrict__ res,
                        const float* __restrict__ g2, const float* __restrict__ b2,
                        u16* __restrict__ t2b) {
  __shared__ float s4[4];
  int t = blockIdx.x, c = threadIdx.x;
  float v = proj[t * 256 + c] + res[t * 256 + c];
  float mu = blk_sum(v, s4) * (1.f / 256.f);
  float d = v - mu;
  float var = blk_sum(d * d, s4) * (1.f / 256.f);
  t2b[t * 256 + c] = bf16_rne(d * rsqrtf(var + 1e-6f) * g2[c] + b2[c]);
}

// out = x + g_broadcast + gelu(g3 + mo_b)
__global__ void k_final(const float* __restrict__ x, const float* __restrict__ gvec,
                        const float* __restrict__ g3, const float* __restrict__ mob,
                        float* __restrict__ out) {
  int idx = blockIdx.x * 256 + threadIdx.x;
  int b = idx / 55296;
  int r = idx % 55296;
  int c = r / 216, s = r % 216;
  float lv = gelu_f(g3[(b * 216 + s) * 256 + c] + mob[c]);
  out[idx] = x[idx] + gvec[b * 256 + c] + lv;
}

// ---------------------------------------------------------------- launcher
extern "C" void kernel_launch(void* const* d_in, const int* in_sizes, int n_in,
                              void* d_out, int out_size, void* d_ws, size_t ws_size,
                              hipStream_t stream) {
  const float* x     = (const float*)d_in[0];
  const float* g_tw  = (const float*)d_in[1];
  const float* g_tb  = (const float*)d_in[2];
  const float* g_l1g = (const float*)d_in[3];
  const float* g_l1b = (const float*)d_in[4];
  const float* g_wq  = (const float*)d_in[5];
  const float* g_wk  = (const float*)d_in[6];
  const float* g_wv  = (const float*)d_in[7];
  const float* g_wo  = (const float*)d_in[8];
  const float* g_l2g = (const float*)d_in[9];
  const float* g_l2b = (const float*)d_in[10];
  const float* g_mow = (const float*)d_in[11];
  const float* g_mob = (const float*)d_in[12];
  const float* l_pw  = (const float*)d_in[13];
  const float* l_pb  = (const float*)d_in[14];
  const float* l_l1g = (const float*)d_in[15];
  const float* l_l1b = (const float*)d_in[16];
  const float* l_wq  = (const float*)d_in[17];
  const float* l_wk  = (const float*)d_in[18];
  const float* l_wv  = (const float*)d_in[19];
  const float* l_wo  = (const float*)d_in[20];
  const float* l_l2g = (const float*)d_in[21];
  const float* l_l2b = (const float*)d_in[22];
  const float* l_mow = (const float*)d_in[23];
  const float* l_mob = (const float*)d_in[24];
  float* out = (float*)d_out;
  float* ws  = (float*)d_ws;

  // workspace layout (float offsets; bf16 regions hold 2 vals per float slot)
  float* g_vec  = ws + 36864;    // 2048
  float* g_part = ws + 38912;    // 1728
  float* res    = ws + 40960;    // 442368 f32
  u16*   eln_bf = (u16*)(ws + 483328);   // 442368 u16
  u16*   WcatT  = (u16*)(ws + 704512);   // 786432 u16 [3072 j][256 c]
  u16*   woT    = (u16*)(ws + 1097728);  // 262144 u16 [256][1024]
  u16*   moB    = (u16*)(ws + 1228800);  // 65536  u16 (mo_w as-is: [o][c]=BT)
  float* qkv    = ws + 1261568;  // 5308416 f32 ; dead after attn -> g3
  u16*   o_buf  = (u16*)(ws + 6569984);  // 1769472 u16
  float* proj   = ws + 7454720;  // 442368 f32
  u16*   t2b    = (u16*)(ws + 7897088);  // 442368 u16
  float* g3     = qkv;

  // weight prep (independent)
  k_trc<<<dim3(8, 32), 256, 0, stream>>>(l_wq, WcatT,          256, 1024);
  k_trc<<<dim3(8, 32), 256, 0, stream>>>(l_wk, WcatT + 262144, 256, 1024);
  k_trc<<<dim3(8, 32), 256, 0, stream>>>(l_wv, WcatT + 524288, 256, 1024);
  k_trc<<<dim3(32, 8), 256, 0, stream>>>(l_wo, woT, 1024, 256);
  k_cast<<<256, 256, 0, stream>>>(l_mow, moB, 65536);

  // local tok (feeds both branches)
  k_l_tok<<<1728, 256, 0, stream>>>(x, l_pw, l_pb, l_l1g, l_l1b, res, eln_bf, g_part);

  // global branch: one fused kernel
  k_g_fused<<<8, 256, 0, stream>>>(g_part, g_tw, g_tb, g_l1g, g_l1b,
                                   g_wq, g_wk, g_wv, g_wo, g_l2g, g_l2b,
                                   g_mow, g_mob, g_vec);

  // local branch (bf16 MFMA GEMMs + MFMA attention)
  k_gemm_bf16<<<dim3(27, 48), 256, 0, stream>>>(eln_bf, WcatT, qkv, 1728, 3072, 256);
  k_l_attn<<<dim3(216, 4), 256, 0, stream>>>(qkv, o_buf);
  k_gemm_bf16<<<dim3(27, 4), 256, 0, stream>>>(o_buf, woT, proj, 1728, 256, 1024);
  k_l_ln2<<<1728, 256, 0, stream>>>(proj, res, l_l2g, l_l2b, t2b);
  k_gemm_bf16<<<dim3(27, 4), 256, 0, stream>>>(t2b, moB, g3, 1728, 256, 256);
  k_final<<<1728, 256, 0, stream>>>(x, g_vec, g3, l_mob, out);
}

// Round 8
// 175.564 us; speedup vs baseline: 1.2865x; 1.2865x over previous
//
#include <hip/hip_runtime.h>
#include <stdint.h>
#include <math.h>

#define DEVFN __device__ __forceinline__
typedef unsigned short u16;
typedef short bf16x8 __attribute__((ext_vector_type(8)));
typedef float f32x4  __attribute__((ext_vector_type(4)));

// ---------------------------------------------------------------- helpers
DEVFN float blk_sum(float v, float* s4) {          // 256-thread block sum
  #pragma unroll
  for (int o = 32; o > 0; o >>= 1) v += __shfl_down(v, o, 64);
  __syncthreads();
  if ((threadIdx.x & 63) == 0) s4[threadIdx.x >> 6] = v;
  __syncthreads();
  return s4[0] + s4[1] + s4[2] + s4[3];
}

DEVFN float gelu_f(float x) {
  return 0.5f * x * (1.f + erff(x * 0.7071067811865475f));
}

DEVFN u16 bf16_rne(float f) {                      // fp32 -> bf16 round-nearest-even
  uint32_t u = __float_as_uint(f);
  return (u16)((u + 0x7fffu + ((u >> 16) & 1u)) >> 16);
}

DEVFN float bf2f(u16 v) { return __uint_as_float(((uint32_t)v) << 16); }

// ---------------------------------------------------------------- local tok
// patch embed + LN1 ; block per (b,s) token; eln written as bf16 (GEMM A).
// g_part: raw-x partials, 8x over-counted (full patch read per sub-position).
__global__ void k_l_tok(const float* __restrict__ x, const float* __restrict__ pw,
                        const float* __restrict__ pb, const float* __restrict__ g1,
                        const float* __restrict__ b1,
                        float* __restrict__ res, u16* __restrict__ eln_bf,
                        float* __restrict__ g_part) {
  __shared__ float pws[64], s4[4];
  int t = blockIdx.x;
  int b = t / 216, s = t % 216;
  int z = s / 36, y = (s / 6) % 6, xx = s % 6;
  int d = z >> 1, p1 = z & 1, hh = y >> 1, p2 = y & 1, ww = xx >> 1, p3 = xx & 1;
  int p = p1 * 4 + p2 * 2 + p3;
  int c = threadIdx.x;
  if (c < 64) pws[c] = pw[c];
  __syncthreads();
  const float* xb = x + (b * 256 + c) * 216 + (2 * d) * 36 + (2 * hh) * 6 + 2 * ww;
  float v = pb[p];
  float xs = 0.f;
  #pragma unroll
  for (int q1 = 0; q1 < 2; ++q1)
    #pragma unroll
    for (int q2 = 0; q2 < 2; ++q2)
      #pragma unroll
      for (int q3 = 0; q3 < 2; ++q3) {
        float xv = xb[q1 * 36 + q2 * 6 + q3];
        xs += xv;
        v += xv * pws[p * 8 + (q1 * 4 + q2 * 2 + q3)];
      }
  float bs = blk_sum(xs, s4);
  if (c == 0) g_part[t] = bs;
  res[t * 256 + c] = v;
  float mu = blk_sum(v, s4) * (1.f / 256.f);
  float dd = v - mu;
  float var = blk_sum(dd * dd, s4) * (1.f / 256.f);
  eln_bf[t * 256 + c] = bf16_rne(dd * rsqrtf(var + 1e-6f) * g1[c] + b1[c]);
}

// ---------------------------------------------------------------- global branch
// block per batch: reduce 216 partials (8x over-counted) -> mean, token, LN1
__global__ void k_g_tok2(const float* __restrict__ g_part, const float* __restrict__ tw,
                         const float* __restrict__ tb, const float* __restrict__ g1,
                         const float* __restrict__ b1,
                         float* __restrict__ g_res, float* __restrict__ g_t) {
  __shared__ float s4[4];
  int b = blockIdx.x, tid = threadIdx.x;
  float acc = (tid < 216) ? g_part[b * 216 + tid] : 0.f;
  float m = blk_sum(acc, s4) * (1.f / 442368.f);   // 8 * 55296
  float tok = m * tw[tid] + tb[tid];
  g_res[b * 256 + tid] = tok;
  float mu = blk_sum(tok, s4) * (1.f / 256.f);
  float d = tok - mu;
  float var = blk_sum(d * d, s4) * (1.f / 256.f);
  g_t[b * 256 + tid] = d * rsqrtf(var + 1e-6f) * g1[tid] + b1[tid];
}

// qkv for ALL 8 batches per block: block owns 256 cols, weights read once,
// coalesced. grid = 12 blocks (3072 cols / 256).
__global__ __launch_bounds__(256) void k_g_qkv(
    const float* __restrict__ g_t, const float* __restrict__ wq,
    const float* __restrict__ wk, const float* __restrict__ wv,
    float* __restrict__ gqkv) {
  __shared__ float ts[2048];
  int tid = threadIdx.x;
  for (int i = tid; i < 2048; i += 256) ts[i] = g_t[i];
  __syncthreads();
  int col = blockIdx.x * 256 + tid;
  int m = col >> 10, cc = col & 1023;
  const float* W = (m == 0) ? wq : (m == 1) ? wk : wv;
  float acc[8] = {};
  for (int c = 0; c < 256; ++c) {
    float w = W[c * 1024 + cc];
    #pragma unroll
    for (int b = 0; b < 8; ++b) acc[b] = fmaf(ts[b * 256 + c], w, acc[b]);
  }
  #pragma unroll
  for (int b = 0; b < 8; ++b) gqkv[b * 3072 + col] = acc[b];
}

// rank-1 score attention per (b,h); IN stats factor exactly through q,k sums.
__global__ void k_g_attn(const float* __restrict__ gq, float* __restrict__ g_o) {
  __shared__ float ks[256], vs[256], s4[4];
  int b = blockIdx.x >> 2, h = blockIdx.x & 3;
  int i = threadIdx.x;
  const float* base = gq + b * 3072 + h * 256;
  float q = base[i];
  float k = base[1024 + i];
  ks[i] = k;
  vs[i] = base[2048 + i];
  float sq  = blk_sum(q, s4);
  float sq2 = blk_sum(q * q, s4);
  float sk  = blk_sum(k, s4);
  float sk2 = blk_sum(k * k, s4);
  float tot  = sq * sk * (1.f / 65536.f);
  float tot2 = sq2 * sk2 * (1.f / 65536.f);
  float rstd = rsqrtf(tot2 - tot * tot + 1e-5f);
  float A = rstd, B = -tot * rstd;
  float den = 0.f, num = 0.f;
  for (int j = 0; j < 256; ++j) {
    float w = __expf(fmaf(q * ks[j], A, B));
    den += w; num += w * vs[j];
  }
  g_o[b * 1024 + (i << 2) + h] = num / den;   // (c outer, h inner)
}

// out = o @ wo ; +res ; LN2 ; gelu(mo_w @ t2 + mo_b) -> per-batch vector
__global__ void k_g_out(const float* __restrict__ g_o, const float* __restrict__ wo,
                        const float* __restrict__ g_res, const float* __restrict__ g2,
                        const float* __restrict__ b2, const float* __restrict__ mow,
                        const float* __restrict__ mob, float* __restrict__ g_vec) {
  __shared__ float os[1024], t2s[256], s4[4];
  int b = blockIdx.x, tid = threadIdx.x;
  for (int i = tid; i < 1024; i += 256) os[i] = g_o[b * 1024 + i];
  __syncthreads();
  float acc = 0.f;
  for (int k = 0; k < 1024; ++k) acc = fmaf(os[k], wo[k * 256 + tid], acc);
  float val = acc + g_res[b * 256 + tid];
  float mu = blk_sum(val, s4) * (1.f / 256.f);
  float d = val - mu;
  float var = blk_sum(d * d, s4) * (1.f / 256.f);
  float t2 = d * rsqrtf(var + 1e-6f) * g2[tid] + b2[tid];
  t2s[tid] = t2;
  __syncthreads();
  float a2 = mob[tid];
  for (int c = 0; c < 256; ++c) a2 = fmaf(t2s[c], mow[tid * 256 + c], a2);
  g_vec[b * 256 + tid] = gelu_f(a2);
}

// ---------------------------------------------------------------- weight prep
// one kernel, flattened grid: [0,768) wq/wk/wv transpose, [768,1024) wo
// transpose, [1024,1280) mo cast. All 256-thread blocks.
DEVFN void trc_tile(const float* __restrict__ in, u16* __restrict__ out,
                    int R, int C, int r0, int c0, float (*tile)[33], int tid) {
  int tx = tid & 31, ty = tid >> 5;
  for (int i = ty; i < 32; i += 8) tile[i][tx] = in[(size_t)(r0 + i) * C + c0 + tx];
  __syncthreads();
  for (int i = ty; i < 32; i += 8)
    out[(size_t)(c0 + i) * R + r0 + tx] = bf16_rne(tile[tx][i]);
}

__global__ void k_prep(const float* __restrict__ wq, const float* __restrict__ wk,
                       const float* __restrict__ wv, const float* __restrict__ wo,
                       const float* __restrict__ mow,
                       u16* __restrict__ WcatT, u16* __restrict__ woT,
                       u16* __restrict__ moB) {
  __shared__ float tile[32][33];
  int bid = blockIdx.x, tid = threadIdx.x;
  if (bid < 768) {            // wq/wk/wv: [256][1024] -> [1024][256], 8x32 tiles
    int which = bid >> 8, b2 = bid & 255;
    const float* in = (which == 0) ? wq : (which == 1) ? wk : wv;
    u16* out = WcatT + which * 262144;
    int r0 = (b2 & 7) * 32, c0 = (b2 >> 3) * 32;
    trc_tile(in, out, 256, 1024, r0, c0, tile, tid);
  } else if (bid < 1024) {    // wo: [1024][256] -> [256][1024], 32x8 tiles
    int b2 = bid - 768;
    int r0 = (b2 & 31) * 32, c0 = (b2 >> 5) * 32;
    trc_tile(wo, woT, 1024, 256, r0, c0, tile, tid);
  } else {                    // mo_w cast (layout [o][c] already = BT)
    int i = (bid - 1024) * 256 + tid;
    moB[i] = bf16_rne(mow[i]);
  }
}

// ---------------------------------------------------------------- bf16 MFMA GEMM
// C[M][N] fp32 = A[M][K] bf16 @ BT[N][K] bf16  (B stored N-major = B^T)
// 64x64 tile, BK=32, 4 waves (2x2), 16x16x32 MFMA, 2x2 frags per wave.
__global__ __launch_bounds__(256) void k_gemm_bf16(
    const u16* __restrict__ A, const u16* __restrict__ BT,
    float* __restrict__ C, int M, int N, int K) {
  __shared__ __align__(16) u16 a_s[64][40];   // pad 40: 80B rows, 2-way max
  __shared__ __align__(16) u16 b_s[64][40];
  int tid = threadIdx.x;
  int rowblk = blockIdx.x * 64, colblk = blockIdx.y * 64;
  int sr = tid & 63, sk = (tid >> 6) * 8;     // staging: row, k-chunk
  int lane = tid & 63, w = tid >> 6;
  int wr = (w >> 1) * 32, wc = (w & 1) * 32;  // wave's 32x32 quadrant
  int fm = lane & 15, fk = (lane >> 4) * 8;   // frag: m/n idx, k-chunk
  f32x4 acc[2][2] = {};
  for (int kt = 0; kt < K; kt += 32) {
    __syncthreads();
    *(uint4*)&a_s[sr][sk] = *(const uint4*)&A[(size_t)(rowblk + sr) * K + kt + sk];
    *(uint4*)&b_s[sr][sk] = *(const uint4*)&BT[(size_t)(colblk + sr) * K + kt + sk];
    __syncthreads();
    bf16x8 bn[2];
    #pragma unroll
    for (int ni = 0; ni < 2; ++ni) bn[ni] = *(const bf16x8*)&b_s[wc + ni * 16 + fm][fk];
    #pragma unroll
    for (int mi = 0; mi < 2; ++mi) {
      bf16x8 af = *(const bf16x8*)&a_s[wr + mi * 16 + fm][fk];
      #pragma unroll
      for (int ni = 0; ni < 2; ++ni)
        acc[mi][ni] = __builtin_amdgcn_mfma_f32_16x16x32_bf16(af, bn[ni], acc[mi][ni], 0, 0, 0);
    }
  }
  int crow0 = rowblk + wr + (lane >> 4) * 4;
  int ccol  = colblk + wc + fm;
  #pragma unroll
  for (int mi = 0; mi < 2; ++mi)
    #pragma unroll
    for (int ni = 0; ni < 2; ++ni)
      #pragma unroll
      for (int r = 0; r < 4; ++r)
        C[(size_t)(crow0 + mi * 16 + r) * N + ccol + ni * 16] = acc[mi][ni][r];
}

// ---------------------------------------------------------------- local attention (MFMA)
// Block = (n,h), 256 threads = 4 waves. Q,K bf16x8 rows in LDS; V^T (+ones row
// for the denominator) in LDS. Per 64-j chunk: S^T tiles via mfma(K,Q) with
// K=8 zero-padded to 32, exp -> bf16 pack -> P (A-frag layout, wave-private),
// then PV via mfma(P, V^T); den = col 8 (ones row), bpermute-broadcast.
__global__ __launch_bounds__(256) void k_l_attn(const float* __restrict__ qkv,
                                                u16* __restrict__ o_buf) {
  __shared__ __align__(16) uint4 Qb[256], Kb[256];   // bf16x8 per row (k=0..7)
  __shared__ __align__(16) u16 vt[16][264];          // V^T: rows 0..7 V, 8 ones, 9..15 zero
  __shared__ __align__(16) u16 Pl[256][72];          // P[q][j-in-chunk], bf16
  __shared__ float rqA[64][4], rkA[64][4], rlq[64][4], rlk[64][4], s_ab[2];
  int n = blockIdx.x, h = blockIdx.y;
  int b = n / 27, patch = n % 27;
  int bz = 2 * (patch / 9), by = 2 * ((patch / 3) % 3), bx = 2 * (patch % 3);
  int tid = threadIdx.x;
  // ---- stage Q/K/V (thread per channel c)
  {
    int c = tid;
    float qv[8], kv[8], vv[8];
    #pragma unroll
    for (int p = 0; p < 8; ++p) {
      int t_l = b * 216 + (bz + (p >> 2)) * 36 + (by + ((p >> 1) & 1)) * 6 + (bx + (p & 1));
      const float* row = qkv + (size_t)t_l * 3072 + (c << 2) + h;
      qv[p] = row[0]; kv[p] = row[1024]; vv[p] = row[2048];
    }
    uint32_t qw[4], kw[4];
    #pragma unroll
    for (int i = 0; i < 4; ++i) {
      qw[i] = (uint32_t)bf16_rne(qv[2 * i]) | ((uint32_t)bf16_rne(qv[2 * i + 1]) << 16);
      kw[i] = (uint32_t)bf16_rne(kv[2 * i]) | ((uint32_t)bf16_rne(kv[2 * i + 1]) << 16);
    }
    Qb[c] = make_uint4(qw[0], qw[1], qw[2], qw[3]);
    Kb[c] = make_uint4(kw[0], kw[1], kw[2], kw[3]);
    #pragma unroll
    for (int p = 0; p < 8; ++p) vt[p][c] = bf16_rne(vv[p]);
    vt[8][c] = 0x3F80u;                  // bf16(1.0): denominator ones-row
    #pragma unroll
    for (int r2 = 9; r2 < 16; ++r2) vt[r2][c] = 0;
  }
  __syncthreads();
  // ---- InstanceNorm stats via Gram factorization (on bf16-rounded Q,K)
  {
    int p = tid & 63, chunk = tid >> 6;
    int d = p >> 3, e = p & 7;
    float aq = 0.f, ak = 0.f, lq = 0.f, lk = 0.f;
    for (int cc = chunk * 64; cc < chunk * 64 + 64; ++cc) {
      const u16* qr = (const u16*)&Qb[cc];
      const u16* kr = (const u16*)&Kb[cc];
      float qd = bf2f(qr[d]), qe = bf2f(qr[e]);
      float kd = bf2f(kr[d]), ke = bf2f(kr[e]);
      aq = fmaf(qd, qe, aq); ak = fmaf(kd, ke, ak);
      if (e == 0) { lq += qd; lk += kd; }
    }
    rqA[p][chunk] = aq; rkA[p][chunk] = ak; rlq[p][chunk] = lq; rlk[p][chunk] = lk;
    __syncthreads();
    if (tid < 64) {
      float gq = rqA[tid][0] + rqA[tid][1] + rqA[tid][2] + rqA[tid][3];
      float gk = rkA[tid][0] + rkA[tid][1] + rkA[tid][2] + rkA[tid][3];
      float vprod = gq * gk, vmu = 0.f;
      if ((tid & 7) == 0) {
        float slq = rlq[tid][0] + rlq[tid][1] + rlq[tid][2] + rlq[tid][3];
        float slk = rlk[tid][0] + rlk[tid][1] + rlk[tid][2] + rlk[tid][3];
        vmu = slq * slk;
      }
      #pragma unroll
      for (int o = 32; o > 0; o >>= 1) {
        vprod += __shfl_down(vprod, o, 64);
        vmu   += __shfl_down(vmu, o, 64);
      }
      if (tid == 0) {
        float mu = vmu * (1.f / 65536.f), m2 = vprod * (1.f / 65536.f);
        float rstd = rsqrtf(m2 - mu * mu + 1e-5f);
        s_ab[0] = rstd; s_ab[1] = -mu * rstd;
      }
    }
    __syncthreads();
  }
  float Af = s_ab[0], Bf = s_ab[1];
  int lane = tid & 63, w = tid >> 6;
  int l15 = lane & 15, lg = lane >> 4;
  bf16x8 qf[4];
  #pragma unroll
  for (int qt = 0; qt < 4; ++qt)
    qf[qt] = *(const bf16x8*)&Qb[w * 64 + qt * 16 + l15];
  f32x4 acc_o[4] = {};
  #pragma unroll 1
  for (int jc = 0; jc < 4; ++jc) {
    bf16x8 kf[4];
    #pragma unroll
    for (int jt = 0; jt < 4; ++jt) {
      bf16x8 z = {};
      if (lg == 0) z = *(const bf16x8*)&Kb[jc * 64 + jt * 16 + l15];
      kf[jt] = z;                        // K=8 zero-padded to 32
    }
    #pragma unroll
    for (int jt = 0; jt < 4; ++jt) {
      #pragma unroll
      for (int qt = 0; qt < 4; ++qt) {
        f32x4 zc = {};
        f32x4 s = __builtin_amdgcn_mfma_f32_16x16x32_bf16(kf[jt], qf[qt], zc, 0, 0, 0);
        float e0 = __expf(fmaf(s[0], Af, Bf));
        float e1 = __expf(fmaf(s[1], Af, Bf));
        float e2 = __expf(fmaf(s[2], Af, Bf));
        float e3 = __expf(fmaf(s[3], Af, Bf));
        uint32_t w0 = (__float_as_uint(e0) >> 16) | (__float_as_uint(e1) & 0xFFFF0000u);
        uint32_t w1 = (__float_as_uint(e2) >> 16) | (__float_as_uint(e3) & 0xFFFF0000u);
        int q = w * 64 + qt * 16 + l15;
        *(uint2*)&Pl[q][jt * 16 + lg * 4] = make_uint2(w0, w1);
      }
    }
    #pragma unroll
    for (int ks = 0; ks < 2; ++ks) {
      bf16x8 vf = *(const bf16x8*)&vt[l15][jc * 64 + ks * 32 + lg * 8];
      #pragma unroll
      for (int qt = 0; qt < 4; ++qt) {
        bf16x8 pf = *(const bf16x8*)&Pl[w * 64 + qt * 16 + l15][ks * 32 + lg * 8];
        acc_o[qt] = __builtin_amdgcn_mfma_f32_16x16x32_bf16(pf, vf, acc_o[qt], 0, 0, 0);
      }
    }
  }
  int src = ((lane & 48) + 8) << 2;      // byte index of this group's den lane
  int p = l15;
  int t_l = b * 216 + (bz + (p >> 2)) * 36 + (by + ((p >> 1) & 1)) * 6 + (bx + (p & 1));
  #pragma unroll
  for (int qt = 0; qt < 4; ++qt) {
    #pragma unroll
    for (int r = 0; r < 4; ++r) {
      float den = __int_as_float(__builtin_amdgcn_ds_bpermute(src, __float_as_int(acc_o[qt][r])));
      if (p < 8) {
        int q = w * 64 + qt * 16 + lg * 4 + r;
        o_buf[(size_t)t_l * 1024 + (q << 2) + h] = bf16_rne(acc_o[qt][r] / den);
      }
    }
  }
}

// t2 = LN(proj + res) -> bf16 (mo-GEMM A)
__global__ void k_l_ln2(const float* __restrict__ proj, const float* __restrict__ res,
                        const float* __restrict__ g2, const float* __restrict__ b2,
                        u16* __restrict__ t2b) {
  __shared__ float s4[4];
  int t = blockIdx.x, c = threadIdx.x;
  float v = proj[t * 256 + c] + res[t * 256 + c];
  float mu = blk_sum(v, s4) * (1.f / 256.f);
  float d = v - mu;
  float var = blk_sum(d * d, s4) * (1.f / 256.f);
  t2b[t * 256 + c] = bf16_rne(d * rsqrtf(var + 1e-6f) * g2[c] + b2[c]);
}

// out = x + g_broadcast + gelu(g3 + mo_b)
__global__ void k_final(const float* __restrict__ x, const float* __restrict__ gvec,
                        const float* __restrict__ g3, const float* __restrict__ mob,
                        float* __restrict__ out) {
  int idx = blockIdx.x * 256 + threadIdx.x;
  int b = idx / 55296;
  int r = idx % 55296;
  int c = r / 216, s = r % 216;
  float lv = gelu_f(g3[(b * 216 + s) * 256 + c] + mob[c]);
  out[idx] = x[idx] + gvec[b * 256 + c] + lv;
}

// ---------------------------------------------------------------- launcher
extern "C" void kernel_launch(void* const* d_in, const int* in_sizes, int n_in,
                              void* d_out, int out_size, void* d_ws, size_t ws_size,
                              hipStream_t stream) {
  const float* x     = (const float*)d_in[0];
  const float* g_tw  = (const float*)d_in[1];
  const float* g_tb  = (const float*)d_in[2];
  const float* g_l1g = (const float*)d_in[3];
  const float* g_l1b = (const float*)d_in[4];
  const float* g_wq  = (const float*)d_in[5];
  const float* g_wk  = (const float*)d_in[6];
  const float* g_wv  = (const float*)d_in[7];
  const float* g_wo  = (const float*)d_in[8];
  const float* g_l2g = (const float*)d_in[9];
  const float* g_l2b = (const float*)d_in[10];
  const float* g_mow = (const float*)d_in[11];
  const float* g_mob = (const float*)d_in[12];
  const float* l_pw  = (const float*)d_in[13];
  const float* l_pb  = (const float*)d_in[14];
  const float* l_l1g = (const float*)d_in[15];
  const float* l_l1b = (const float*)d_in[16];
  const float* l_wq  = (const float*)d_in[17];
  const float* l_wk  = (const float*)d_in[18];
  const float* l_wv  = (const float*)d_in[19];
  const float* l_wo  = (const float*)d_in[20];
  const float* l_l2g = (const float*)d_in[21];
  const float* l_l2b = (const float*)d_in[22];
  const float* l_mow = (const float*)d_in[23];
  const float* l_mob = (const float*)d_in[24];
  float* out = (float*)d_out;
  float* ws  = (float*)d_ws;

  // workspace layout (float offsets; bf16 regions hold 2 vals per float slot)
  float* g_res  = ws + 0;        // 2048
  float* g_t    = ws + 2048;     // 2048
  float* g_qkv  = ws + 4096;     // 24576
  float* g_o    = ws + 28672;    // 8192
  float* g_vec  = ws + 36864;    // 2048
  float* g_part = ws + 38912;    // 1728
  float* res    = ws + 40960;    // 442368 f32
  u16*   eln_bf = (u16*)(ws + 483328);   // 442368 u16
  u16*   WcatT  = (u16*)(ws + 704512);   // 786432 u16 [3072 j][256 c]
  u16*   woT    = (u16*)(ws + 1097728);  // 262144 u16 [256][1024]
  u16*   moB    = (u16*)(ws + 1228800);  // 65536  u16 (mo_w as-is: [o][c]=BT)
  float* qkv    = ws + 1261568;  // 5308416 f32 ; dead after attn -> g3
  u16*   o_buf  = (u16*)(ws + 6569984);  // 1769472 u16
  float* proj   = ws + 7454720;  // 442368 f32
  u16*   t2b    = (u16*)(ws + 7897088);  // 442368 u16
  float* g3     = qkv;

  // weight prep: one kernel
  k_prep<<<1280, 256, 0, stream>>>(l_wq, l_wk, l_wv, l_wo, l_mow, WcatT, woT, moB);

  // local tok (feeds both branches)
  k_l_tok<<<1728, 256, 0, stream>>>(x, l_pw, l_pb, l_l1g, l_l1b, res, eln_bf, g_part);

  // global branch (4 small kernels; qkv batched over all 8 batches)
  k_g_tok2<<<8, 256, 0, stream>>>(g_part, g_tw, g_tb, g_l1g, g_l1b, g_res, g_t);
  k_g_qkv<<<12, 256, 0, stream>>>(g_t, g_wq, g_wk, g_wv, g_qkv);
  k_g_attn<<<32, 256, 0, stream>>>(g_qkv, g_o);
  k_g_out<<<8, 256, 0, stream>>>(g_o, g_wo, g_res, g_l2g, g_l2b, g_mow, g_mob, g_vec);

  // local branch (bf16 MFMA GEMMs + MFMA attention)
  k_gemm_bf16<<<dim3(27, 48), 256, 0, stream>>>(eln_bf, WcatT, qkv, 1728, 3072, 256);
  k_l_attn<<<dim3(216, 4), 256, 0, stream>>>(qkv, o_buf);
  k_gemm_bf16<<<dim3(27, 4), 256, 0, stream>>>(o_buf, woT, proj, 1728, 256, 1024);
  k_l_ln2<<<1728, 256, 0, stream>>>(proj, res, l_l2g, l_l2b, t2b);
  k_gemm_bf16<<<dim3(27, 4), 256, 0, stream>>>(t2b, moB, g3, 1728, 256, 256);
  k_final<<<1728, 256, 0, stream>>>(x, g_vec, g3, l_mob, out);
}

// Round 9
// 145.896 us; speedup vs baseline: 1.5481x; 1.2033x over previous
//
#include <hip/hip_runtime.h>
#include <stdint.h>
#include <math.h>

#define DEVFN __device__ __forceinline__
typedef unsigned short u16;
typedef short bf16x8 __attribute__((ext_vector_type(8)));
typedef float f32x4  __attribute__((ext_vector_type(4)));

// ---------------------------------------------------------------- helpers
DEVFN float blk_sum(float v, float* s4) {          // 256-thread block sum
  #pragma unroll
  for (int o = 32; o > 0; o >>= 1) v += __shfl_down(v, o, 64);
  __syncthreads();
  if ((threadIdx.x & 63) == 0) s4[threadIdx.x >> 6] = v;
  __syncthreads();
  return s4[0] + s4[1] + s4[2] + s4[3];
}

DEVFN float gelu_f(float x) {
  return 0.5f * x * (1.f + erff(x * 0.7071067811865475f));
}

DEVFN u16 bf16_rne(float f) {                      // fp32 -> bf16 round-nearest-even
  uint32_t u = __float_as_uint(f);
  return (u16)((u + 0x7fffu + ((u >> 16) & 1u)) >> 16);
}

DEVFN float bf2f(u16 v) { return __uint_as_float(((uint32_t)v) << 16); }

// ---------------------------------------------------------------- local tok
// patch embed + LN1 ; block per (b,s) token; eln written as bf16 (GEMM A).
// g_part: raw-x partials, 8x over-counted (full patch read per sub-position).
__global__ void k_l_tok(const float* __restrict__ x, const float* __restrict__ pw,
                        const float* __restrict__ pb, const float* __restrict__ g1,
                        const float* __restrict__ b1,
                        float* __restrict__ res, u16* __restrict__ eln_bf,
                        float* __restrict__ g_part) {
  __shared__ float pws[64], s4[4];
  int t = blockIdx.x;
  int b = t / 216, s = t % 216;
  int z = s / 36, y = (s / 6) % 6, xx = s % 6;
  int d = z >> 1, p1 = z & 1, hh = y >> 1, p2 = y & 1, ww = xx >> 1, p3 = xx & 1;
  int p = p1 * 4 + p2 * 2 + p3;
  int c = threadIdx.x;
  if (c < 64) pws[c] = pw[c];
  __syncthreads();
  const float* xb = x + (b * 256 + c) * 216 + (2 * d) * 36 + (2 * hh) * 6 + 2 * ww;
  float v = pb[p];
  float xs = 0.f;
  #pragma unroll
  for (int q1 = 0; q1 < 2; ++q1)
    #pragma unroll
    for (int q2 = 0; q2 < 2; ++q2)
      #pragma unroll
      for (int q3 = 0; q3 < 2; ++q3) {
        float xv = xb[q1 * 36 + q2 * 6 + q3];
        xs += xv;
        v += xv * pws[p * 8 + (q1 * 4 + q2 * 2 + q3)];
      }
  float bs = blk_sum(xs, s4);
  if (c == 0) g_part[t] = bs;
  res[t * 256 + c] = v;
  float mu = blk_sum(v, s4) * (1.f / 256.f);
  float dd = v - mu;
  float var = blk_sum(dd * dd, s4) * (1.f / 256.f);
  eln_bf[t * 256 + c] = bf16_rne(dd * rsqrtf(var + 1e-6f) * g1[c] + b1[c]);
}

// ---------------------------------------------------------------- global branch
// block per batch: reduce 216 partials (8x over-counted) -> mean, token, LN1
__global__ void k_g_tok2(const float* __restrict__ g_part, const float* __restrict__ tw,
                         const float* __restrict__ tb, const float* __restrict__ g1,
                         const float* __restrict__ b1,
                         float* __restrict__ g_res, float* __restrict__ g_t) {
  __shared__ float s4[4];
  int b = blockIdx.x, tid = threadIdx.x;
  float acc = (tid < 216) ? g_part[b * 216 + tid] : 0.f;
  float m = blk_sum(acc, s4) * (1.f / 442368.f);   // 8 * 55296
  float tok = m * tw[tid] + tb[tid];
  g_res[b * 256 + tid] = tok;
  float mu = blk_sum(tok, s4) * (1.f / 256.f);
  float d = tok - mu;
  float var = blk_sum(d * d, s4) * (1.f / 256.f);
  g_t[b * 256 + tid] = d * rsqrtf(var + 1e-6f) * g1[tid] + b1[tid];
}

// qkv all batches; block = 64 cols x 4 k-chunks, LDS cross-reduce. grid 48.
__global__ __launch_bounds__(256) void k_g_qkv(
    const float* __restrict__ g_t, const float* __restrict__ wq,
    const float* __restrict__ wk, const float* __restrict__ wv,
    float* __restrict__ gqkv) {
  __shared__ float ts[2048];
  __shared__ float red[64][4][8];
  int tid = threadIdx.x;
  for (int i = tid; i < 2048; i += 256) ts[i] = g_t[i];
  __syncthreads();
  int col0 = blockIdx.x * 64;
  int cl = tid & 63, kq = tid >> 6;
  int col = col0 + cl;
  int m = col >> 10, cc = col & 1023;
  const float* W = (m == 0) ? wq : (m == 1) ? wk : wv;
  float acc[8] = {};
  for (int c = kq * 64; c < kq * 64 + 64; ++c) {
    float w = W[c * 1024 + cc];
    #pragma unroll
    for (int b = 0; b < 8; ++b) acc[b] = fmaf(ts[b * 256 + c], w, acc[b]);
  }
  #pragma unroll
  for (int b = 0; b < 8; ++b) red[cl][kq][b] = acc[b];
  __syncthreads();
  if (kq == 0) {
    #pragma unroll
    for (int b = 0; b < 8; ++b)
      gqkv[b * 3072 + col] = red[cl][0][b] + red[cl][1][b] + red[cl][2][b] + red[cl][3][b];
  }
}

// rank-1 score attention per (b,h); IN stats factor exactly through q,k sums.
__global__ void k_g_attn(const float* __restrict__ gq, float* __restrict__ g_o) {
  __shared__ float ks[256], vs[256], s4[4];
  int b = blockIdx.x >> 2, h = blockIdx.x & 3;
  int i = threadIdx.x;
  const float* base = gq + b * 3072 + h * 256;
  float q = base[i];
  float k = base[1024 + i];
  ks[i] = k;
  vs[i] = base[2048 + i];
  float sq  = blk_sum(q, s4);
  float sq2 = blk_sum(q * q, s4);
  float sk  = blk_sum(k, s4);
  float sk2 = blk_sum(k * k, s4);
  float tot  = sq * sk * (1.f / 65536.f);
  float tot2 = sq2 * sk2 * (1.f / 65536.f);
  float rstd = rsqrtf(tot2 - tot * tot + 1e-5f);
  float A = rstd, B = -tot * rstd;
  float den = 0.f, num = 0.f;
  for (int j = 0; j < 256; ++j) {
    float w = __expf(fmaf(q * ks[j], A, B));
    den += w; num += w * vs[j];
  }
  g_o[b * 1024 + (i << 2) + h] = num / den;   // (c outer, h inner)
}

// wo partials: block kc owns 32 rows of wo (32KB); all 8 batches. grid 32.
__global__ __launch_bounds__(256) void k_g_wo(
    const float* __restrict__ g_o, const float* __restrict__ wo,
    float* __restrict__ part) {
  __shared__ float os[256];                  // o[b][k-slice]: 8 x 32
  int kc = blockIdx.x, tid = threadIdx.x;
  os[tid] = g_o[(tid >> 5) * 1024 + kc * 32 + (tid & 31)];
  __syncthreads();
  float acc[8] = {};
  #pragma unroll
  for (int kk = 0; kk < 32; ++kk) {
    float w = wo[(size_t)(kc * 32 + kk) * 256 + tid];
    #pragma unroll
    for (int b = 0; b < 8; ++b) acc[b] = fmaf(os[b * 32 + kk], w, acc[b]);
  }
  #pragma unroll
  for (int b = 0; b < 8; ++b) part[kc * 2048 + b * 256 + tid] = acc[b];
}

// reduce wo-partials + res -> LN2 -> t2g. grid 8 (block per batch).
__global__ void k_g_ln2g(const float* __restrict__ part, const float* __restrict__ g_res,
                         const float* __restrict__ g2, const float* __restrict__ b2,
                         float* __restrict__ t2g) {
  __shared__ float s4[4];
  int b = blockIdx.x, c = threadIdx.x;
  float v = g_res[b * 256 + c];
  #pragma unroll
  for (int kc = 0; kc < 32; ++kc) v += part[kc * 2048 + b * 256 + c];
  float mu = blk_sum(v, s4) * (1.f / 256.f);
  float d = v - mu;
  float var = blk_sum(d * d, s4) * (1.f / 256.f);
  t2g[b * 256 + c] = d * rsqrtf(var + 1e-6f) * g2[c] + b2[c];
}

// g_vec[b][o] = gelu(dot(t2[b], mow[o]) + mob[o]). grid 32 x (8 o-rows each);
// thread = (o_local, c_slot); mow reads coalesced; width-32 shuffle reduce.
__global__ __launch_bounds__(256) void k_g_mo(
    const float* __restrict__ t2g, const float* __restrict__ mow,
    const float* __restrict__ mob, float* __restrict__ g_vec) {
  __shared__ float ts[2048];
  int tid = threadIdx.x;
  for (int i = tid; i < 2048; i += 256) ts[i] = t2g[i];
  __syncthreads();
  int ol = tid >> 5, cs = tid & 31;
  int o = blockIdx.x * 8 + ol;
  const float* wrow = mow + (size_t)o * 256;
  float acc[8] = {};
  #pragma unroll
  for (int i = 0; i < 8; ++i) {
    float w = wrow[i * 32 + cs];
    #pragma unroll
    for (int b = 0; b < 8; ++b) acc[b] = fmaf(ts[b * 256 + i * 32 + cs], w, acc[b]);
  }
  #pragma unroll
  for (int b = 0; b < 8; ++b) {
    float v = acc[b];
    #pragma unroll
    for (int off = 16; off > 0; off >>= 1) v += __shfl_down(v, off, 32);
    if (cs == 0) g_vec[b * 256 + o] = gelu_f(v + mob[o]);
  }
}

// ---------------------------------------------------------------- weight prep
// one kernel, flattened grid: [0,768) wq/wk/wv transpose, [768,1024) wo
// transpose, [1024,1280) mo cast. All 256-thread blocks.
DEVFN void trc_tile(const float* __restrict__ in, u16* __restrict__ out,
                    int R, int C, int r0, int c0, float (*tile)[33], int tid) {
  int tx = tid & 31, ty = tid >> 5;
  for (int i = ty; i < 32; i += 8) tile[i][tx] = in[(size_t)(r0 + i) * C + c0 + tx];
  __syncthreads();
  for (int i = ty; i < 32; i += 8)
    out[(size_t)(c0 + i) * R + r0 + tx] = bf16_rne(tile[tx][i]);
}

__global__ void k_prep(const float* __restrict__ wq, const float* __restrict__ wk,
                       const float* __restrict__ wv, const float* __restrict__ wo,
                       const float* __restrict__ mow,
                       u16* __restrict__ WcatT, u16* __restrict__ woT,
                       u16* __restrict__ moB) {
  __shared__ float tile[32][33];
  int bid = blockIdx.x, tid = threadIdx.x;
  if (bid < 768) {            // wq/wk/wv: [256][1024] -> [1024][256], 8x32 tiles
    int which = bid >> 8, b2 = bid & 255;
    const float* in = (which == 0) ? wq : (which == 1) ? wk : wv;
    u16* out = WcatT + which * 262144;
    int r0 = (b2 & 7) * 32, c0 = (b2 >> 3) * 32;
    trc_tile(in, out, 256, 1024, r0, c0, tile, tid);
  } else if (bid < 1024) {    // wo: [1024][256] -> [256][1024], 32x8 tiles
    int b2 = bid - 768;
    int r0 = (b2 & 31) * 32, c0 = (b2 >> 5) * 32;
    trc_tile(wo, woT, 1024, 256, r0, c0, tile, tid);
  } else {                    // mo_w cast (layout [o][c] already = BT)
    int i = (bid - 1024) * 256 + tid;
    moB[i] = bf16_rne(mow[i]);
  }
}

// ---------------------------------------------------------------- bf16 MFMA GEMM
// C[M][N] fp32 = A[M][K] bf16 @ BT[N][K] bf16  (B stored N-major = B^T)
// 64x64 tile, BK=32, 4 waves (2x2), 16x16x32 MFMA, 2x2 frags per wave.
__global__ __launch_bounds__(256) void k_gemm_bf16(
    const u16* __restrict__ A, const u16* __restrict__ BT,
    float* __restrict__ C, int M, int N, int K) {
  __shared__ __align__(16) u16 a_s[64][40];   // pad 40: 80B rows, 2-way max
  __shared__ __align__(16) u16 b_s[64][40];
  int tid = threadIdx.x;
  int rowblk = blockIdx.x * 64, colblk = blockIdx.y * 64;
  int sr = tid & 63, sk = (tid >> 6) * 8;     // staging: row, k-chunk
  int lane = tid & 63, w = tid >> 6;
  int wr = (w >> 1) * 32, wc = (w & 1) * 32;  // wave's 32x32 quadrant
  int fm = lane & 15, fk = (lane >> 4) * 8;   // frag: m/n idx, k-chunk
  f32x4 acc[2][2] = {};
  for (int kt = 0; kt < K; kt += 32) {
    __syncthreads();
    *(uint4*)&a_s[sr][sk] = *(const uint4*)&A[(size_t)(rowblk + sr) * K + kt + sk];
    *(uint4*)&b_s[sr][sk] = *(const uint4*)&BT[(size_t)(colblk + sr) * K + kt + sk];
    __syncthreads();
    bf16x8 bn[2];
    #pragma unroll
    for (int ni = 0; ni < 2; ++ni) bn[ni] = *(const bf16x8*)&b_s[wc + ni * 16 + fm][fk];
    #pragma unroll
    for (int mi = 0; mi < 2; ++mi) {
      bf16x8 af = *(const bf16x8*)&a_s[wr + mi * 16 + fm][fk];
      #pragma unroll
      for (int ni = 0; ni < 2; ++ni)
        acc[mi][ni] = __builtin_amdgcn_mfma_f32_16x16x32_bf16(af, bn[ni], acc[mi][ni], 0, 0, 0);
    }
  }
  int crow0 = rowblk + wr + (lane >> 4) * 4;
  int ccol  = colblk + wc + fm;
  #pragma unroll
  for (int mi = 0; mi < 2; ++mi)
    #pragma unroll
    for (int ni = 0; ni < 2; ++ni)
      #pragma unroll
      for (int r = 0; r < 4; ++r)
        C[(size_t)(crow0 + mi * 16 + r) * N + ccol + ni * 16] = acc[mi][ni][r];
}

// ---------------------------------------------------------------- local attention (MFMA)
// Block = (n,h), 256 threads = 4 waves. Q,K bf16x8 rows in LDS; V^T (+ones row
// for the denominator) in LDS. Per 64-j chunk: S^T tiles via mfma(K,Q) with
// K=8 zero-padded to 32, exp -> bf16 pack -> P (A-frag layout, wave-private),
// then PV via mfma(P, V^T); den = col 8 (ones row), bpermute-broadcast.
__global__ __launch_bounds__(256) void k_l_attn(const float* __restrict__ qkv,
                                                u16* __restrict__ o_buf) {
  __shared__ __align__(16) uint4 Qb[256], Kb[256];   // bf16x8 per row (k=0..7)
  __shared__ __align__(16) u16 vt[16][264];          // V^T: rows 0..7 V, 8 ones, 9..15 zero
  __shared__ __align__(16) u16 Pl[256][72];          // P[q][j-in-chunk], bf16
  __shared__ float rqA[64][4], rkA[64][4], rlq[64][4], rlk[64][4], s_ab[2];
  int n = blockIdx.x, h = blockIdx.y;
  int b = n / 27, patch = n % 27;
  int bz = 2 * (patch / 9), by = 2 * ((patch / 3) % 3), bx = 2 * (patch % 3);
  int tid = threadIdx.x;
  // ---- stage Q/K/V (thread per channel c)
  {
    int c = tid;
    float qv[8], kv[8], vv[8];
    #pragma unroll
    for (int p = 0; p < 8; ++p) {
      int t_l = b * 216 + (bz + (p >> 2)) * 36 + (by + ((p >> 1) & 1)) * 6 + (bx + (p & 1));
      const float* row = qkv + (size_t)t_l * 3072 + (c << 2) + h;
      qv[p] = row[0]; kv[p] = row[1024]; vv[p] = row[2048];
    }
    uint32_t qw[4], kw[4];
    #pragma unroll
    for (int i = 0; i < 4; ++i) {
      qw[i] = (uint32_t)bf16_rne(qv[2 * i]) | ((uint32_t)bf16_rne(qv[2 * i + 1]) << 16);
      kw[i] = (uint32_t)bf16_rne(kv[2 * i]) | ((uint32_t)bf16_rne(kv[2 * i + 1]) << 16);
    }
    Qb[c] = make_uint4(qw[0], qw[1], qw[2], qw[3]);
    Kb[c] = make_uint4(kw[0], kw[1], kw[2], kw[3]);
    #pragma unroll
    for (int p = 0; p < 8; ++p) vt[p][c] = bf16_rne(vv[p]);
    vt[8][c] = 0x3F80u;                  // bf16(1.0): denominator ones-row
    #pragma unroll
    for (int r2 = 9; r2 < 16; ++r2) vt[r2][c] = 0;
  }
  __syncthreads();
  // ---- InstanceNorm stats via Gram factorization (on bf16-rounded Q,K)
  {
    int p = tid & 63, chunk = tid >> 6;
    int d = p >> 3, e = p & 7;
    float aq = 0.f, ak = 0.f, lq = 0.f, lk = 0.f;
    for (int cc = chunk * 64; cc < chunk * 64 + 64; ++cc) {
      const u16* qr = (const u16*)&Qb[cc];
      const u16* kr = (const u16*)&Kb[cc];
      float qd = bf2f(qr[d]), qe = bf2f(qr[e]);
      float kd = bf2f(kr[d]), ke = bf2f(kr[e]);
      aq = fmaf(qd, qe, aq); ak = fmaf(kd, ke, ak);
      if (e == 0) { lq += qd; lk += kd; }
    }
    rqA[p][chunk] = aq; rkA[p][chunk] = ak; rlq[p][chunk] = lq; rlk[p][chunk] = lk;
    __syncthreads();
    if (tid < 64) {
      float gq = rqA[tid][0] + rqA[tid][1] + rqA[tid][2] + rqA[tid][3];
      float gk = rkA[tid][0] + rkA[tid][1] + rkA[tid][2] + rkA[tid][3];
      float vprod = gq * gk, vmu = 0.f;
      if ((tid & 7) == 0) {
        float slq = rlq[tid][0] + rlq[tid][1] + rlq[tid][2] + rlq[tid][3];
        float slk = rlk[tid][0] + rlk[tid][1] + rlk[tid][2] + rlk[tid][3];
        vmu = slq * slk;
      }
      #pragma unroll
      for (int o = 32; o > 0; o >>= 1) {
        vprod += __shfl_down(vprod, o, 64);
        vmu   += __shfl_down(vmu, o, 64);
      }
      if (tid == 0) {
        float mu = vmu * (1.f / 65536.f), m2 = vprod * (1.f / 65536.f);
        float rstd = rsqrtf(m2 - mu * mu + 1e-5f);
        s_ab[0] = rstd; s_ab[1] = -mu * rstd;
      }
    }
    __syncthreads();
  }
  float Af = s_ab[0], Bf = s_ab[1];
  int lane = tid & 63, w = tid >> 6;
  int l15 = lane & 15, lg = lane >> 4;
  bf16x8 qf[4];
  #pragma unroll
  for (int qt = 0; qt < 4; ++qt)
    qf[qt] = *(const bf16x8*)&Qb[w * 64 + qt * 16 + l15];
  f32x4 acc_o[4] = {};
  #pragma unroll 1
  for (int jc = 0; jc < 4; ++jc) {
    bf16x8 kf[4];
    #pragma unroll
    for (int jt = 0; jt < 4; ++jt) {
      bf16x8 z = {};
      if (lg == 0) z = *(const bf16x8*)&Kb[jc * 64 + jt * 16 + l15];
      kf[jt] = z;                        // K=8 zero-padded to 32
    }
    #pragma unroll
    for (int jt = 0; jt < 4; ++jt) {
      #pragma unroll
      for (int qt = 0; qt < 4; ++qt) {
        f32x4 zc = {};
        f32x4 s = __builtin_amdgcn_mfma_f32_16x16x32_bf16(kf[jt], qf[qt], zc, 0, 0, 0);
        float e0 = __expf(fmaf(s[0], Af, Bf));
        float e1 = __expf(fmaf(s[1], Af, Bf));
        float e2 = __expf(fmaf(s[2], Af, Bf));
        float e3 = __expf(fmaf(s[3], Af, Bf));
        uint32_t w0 = (__float_as_uint(e0) >> 16) | (__float_as_uint(e1) & 0xFFFF0000u);
        uint32_t w1 = (__float_as_uint(e2) >> 16) | (__float_as_uint(e3) & 0xFFFF0000u);
        int q = w * 64 + qt * 16 + l15;
        *(uint2*)&Pl[q][jt * 16 + lg * 4] = make_uint2(w0, w1);
      }
    }
    #pragma unroll
    for (int ks = 0; ks < 2; ++ks) {
      bf16x8 vf = *(const bf16x8*)&vt[l15][jc * 64 + ks * 32 + lg * 8];
      #pragma unroll
      for (int qt = 0; qt < 4; ++qt) {
        bf16x8 pf = *(const bf16x8*)&Pl[w * 64 + qt * 16 + l15][ks * 32 + lg * 8];
        acc_o[qt] = __builtin_amdgcn_mfma_f32_16x16x32_bf16(pf, vf, acc_o[qt], 0, 0, 0);
      }
    }
  }
  int src = ((lane & 48) + 8) << 2;      // byte index of this group's den lane
  int p = l15;
  int t_l = b * 216 + (bz + (p >> 2)) * 36 + (by + ((p >> 1) & 1)) * 6 + (bx + (p & 1));
  #pragma unroll
  for (int qt = 0; qt < 4; ++qt) {
    #pragma unroll
    for (int r = 0; r < 4; ++r) {
      float den = __int_as_float(__builtin_amdgcn_ds_bpermute(src, __float_as_int(acc_o[qt][r])));
      if (p < 8) {
        int q = w * 64 + qt * 16 + lg * 4 + r;
        o_buf[(size_t)t_l * 1024 + (q << 2) + h] = bf16_rne(acc_o[qt][r] / den);
      }
    }
  }
}

// t2 = LN(proj + res) -> bf16 (mo-GEMM A)
__global__ void k_l_ln2(const float* __restrict__ proj, const float* __restrict__ res,
                        const float* __restrict__ g2, const float* __restrict__ b2,
                        u16* __restrict__ t2b) {
  __shared__ float s4[4];
  int t = blockIdx.x, c = threadIdx.x;
  float v = proj[t * 256 + c] + res[t * 256 + c];
  float mu = blk_sum(v, s4) * (1.f / 256.f);
  float d = v - mu;
  float var = blk_sum(d * d, s4) * (1.f / 256.f);
  t2b[t * 256 + c] = bf16_rne(d * rsqrtf(var + 1e-6f) * g2[c] + b2[c]);
}

// out = x + g_broadcast + gelu(g3 + mo_b)
__global__ void k_final(const float* __restrict__ x, const float* __restrict__ gvec,
                        const float* __restrict__ g3, const float* __restrict__ mob,
                        float* __restrict__ out) {
  int idx = blockIdx.x * 256 + threadIdx.x;
  int b = idx / 55296;
  int r = idx % 55296;
  int c = r / 216, s = r % 216;
  float lv = gelu_f(g3[(b * 216 + s) * 256 + c] + mob[c]);
  out[idx] = x[idx] + gvec[b * 256 + c] + lv;
}

// ---------------------------------------------------------------- launcher
extern "C" void kernel_launch(void* const* d_in, const int* in_sizes, int n_in,
                              void* d_out, int out_size, void* d_ws, size_t ws_size,
                              hipStream_t stream) {
  const float* x     = (const float*)d_in[0];
  const float* g_tw  = (const float*)d_in[1];
  const float* g_tb  = (const float*)d_in[2];
  const float* g_l1g = (const float*)d_in[3];
  const float* g_l1b = (const float*)d_in[4];
  const float* g_wq  = (const float*)d_in[5];
  const float* g_wk  = (const float*)d_in[6];
  const float* g_wv  = (const float*)d_in[7];
  const float* g_wo  = (const float*)d_in[8];
  const float* g_l2g = (const float*)d_in[9];
  const float* g_l2b = (const float*)d_in[10];
  const float* g_mow = (const float*)d_in[11];
  const float* g_mob = (const float*)d_in[12];
  const float* l_pw  = (const float*)d_in[13];
  const float* l_pb  = (const float*)d_in[14];
  const float* l_l1g = (const float*)d_in[15];
  const float* l_l1b = (const float*)d_in[16];
  const float* l_wq  = (const float*)d_in[17];
  const float* l_wk  = (const float*)d_in[18];
  const float* l_wv  = (const float*)d_in[19];
  const float* l_wo  = (const float*)d_in[20];
  const float* l_l2g = (const float*)d_in[21];
  const float* l_l2b = (const float*)d_in[22];
  const float* l_mow = (const float*)d_in[23];
  const float* l_mob = (const float*)d_in[24];
  float* out = (float*)d_out;
  float* ws  = (float*)d_ws;

  // workspace layout (float offsets; bf16 regions hold 2 vals per float slot)
  float* g_res  = ws + 0;        // 2048
  float* g_t    = ws + 2048;     // 2048
  float* g_qkv  = ws + 4096;     // 24576
  float* g_o    = ws + 28672;    // 8192
  float* g_vec  = ws + 36864;    // 2048
  float* g_part = ws + 38912;    // 1728
  float* res    = ws + 40960;    // 442368 f32
  u16*   eln_bf = (u16*)(ws + 483328);   // 442368 u16
  u16*   WcatT  = (u16*)(ws + 704512);   // 786432 u16 [3072 j][256 c]
  u16*   woT    = (u16*)(ws + 1097728);  // 262144 u16 [256][1024]
  u16*   moB    = (u16*)(ws + 1228800);  // 65536  u16 (mo_w as-is: [o][c]=BT)
  float* qkv    = ws + 1261568;  // 5308416 f32 ; dead after attn -> g3
  u16*   o_buf  = (u16*)(ws + 6569984);  // 1769472 u16
  float* proj   = ws + 7454720;  // 442368 f32
  u16*   t2b    = (u16*)(ws + 7897088);  // 442368 u16
  float* part_wo= ws + 8118272;  // 65536 (32 kc x 8 b x 256 c)
  float* t2g    = ws + 8183808;  // 2048
  float* g3     = qkv;

  // weight prep: one kernel
  k_prep<<<1280, 256, 0, stream>>>(l_wq, l_wk, l_wv, l_wo, l_mow, WcatT, woT, moB);

  // local tok (feeds both branches)
  k_l_tok<<<1728, 256, 0, stream>>>(x, l_pw, l_pb, l_l1g, l_l1b, res, eln_bf, g_part);

  // global branch (parallelized small kernels)
  k_g_tok2<<<8, 256, 0, stream>>>(g_part, g_tw, g_tb, g_l1g, g_l1b, g_res, g_t);
  k_g_qkv<<<48, 256, 0, stream>>>(g_t, g_wq, g_wk, g_wv, g_qkv);
  k_g_attn<<<32, 256, 0, stream>>>(g_qkv, g_o);
  k_g_wo<<<32, 256, 0, stream>>>(g_o, g_wo, part_wo);
  k_g_ln2g<<<8, 256, 0, stream>>>(part_wo, g_res, g_l2g, g_l2b, t2g);
  k_g_mo<<<32, 256, 0, stream>>>(t2g, g_mow, g_mob, g_vec);

  // local branch (bf16 MFMA GEMMs + MFMA attention)
  k_gemm_bf16<<<dim3(27, 48), 256, 0, stream>>>(eln_bf, WcatT, qkv, 1728, 3072, 256);
  k_l_attn<<<dim3(216, 4), 256, 0, stream>>>(qkv, o_buf);
  k_gemm_bf16<<<dim3(27, 4), 256, 0, stream>>>(o_buf, woT, proj, 1728, 256, 1024);
  k_l_ln2<<<1728, 256, 0, stream>>>(proj, res, l_l2g, l_l2b, t2b);
  k_gemm_bf16<<<dim3(27, 4), 256, 0, stream>>>(t2b, moB, g3, 1728, 256, 256);
  k_final<<<1728, 256, 0, stream>>>(x, g_vec, g3, l_mob, out);
}

// Round 10
// 137.935 us; speedup vs baseline: 1.6375x; 1.0577x over previous
//
#include <hip/hip_runtime.h>
#include <stdint.h>
#include <math.h>

#define DEVFN __device__ __forceinline__
typedef unsigned short u16;
typedef short bf16x8 __attribute__((ext_vector_type(8)));
typedef float f32x4  __attribute__((ext_vector_type(4)));

// ---------------------------------------------------------------- helpers
DEVFN float blk_sum(float v, float* s4) {          // 256-thread block sum
  #pragma unroll
  for (int o = 32; o > 0; o >>= 1) v += __shfl_down(v, o, 64);
  __syncthreads();
  if ((threadIdx.x & 63) == 0) s4[threadIdx.x >> 6] = v;
  __syncthreads();
  return s4[0] + s4[1] + s4[2] + s4[3];
}

DEVFN float gelu_f(float x) {
  return 0.5f * x * (1.f + erff(x * 0.7071067811865475f));
}

DEVFN u16 bf16_rne(float f) {                      // fp32 -> bf16 round-nearest-even
  uint32_t u = __float_as_uint(f);
  return (u16)((u + 0x7fffu + ((u >> 16) & 1u)) >> 16);
}

DEVFN float bf2f(u16 v) { return __uint_as_float(((uint32_t)v) << 16); }

// ---------------------------------------------------------------- local tok
// patch embed + LN1 ; block per (b,s) token; eln written as bf16 (GEMM A).
// g_part: raw-x partials, 8x over-counted (full patch read per sub-position).
__global__ void k_l_tok(const float* __restrict__ x, const float* __restrict__ pw,
                        const float* __restrict__ pb, const float* __restrict__ g1,
                        const float* __restrict__ b1,
                        float* __restrict__ res, u16* __restrict__ eln_bf,
                        float* __restrict__ g_part) {
  __shared__ float pws[64], s4[4];
  int t = blockIdx.x;
  int b = t / 216, s = t % 216;
  int z = s / 36, y = (s / 6) % 6, xx = s % 6;
  int d = z >> 1, p1 = z & 1, hh = y >> 1, p2 = y & 1, ww = xx >> 1, p3 = xx & 1;
  int p = p1 * 4 + p2 * 2 + p3;
  int c = threadIdx.x;
  if (c < 64) pws[c] = pw[c];
  __syncthreads();
  const float* xb = x + (b * 256 + c) * 216 + (2 * d) * 36 + (2 * hh) * 6 + 2 * ww;
  float v = pb[p];
  float xs = 0.f;
  #pragma unroll
  for (int q1 = 0; q1 < 2; ++q1)
    #pragma unroll
    for (int q2 = 0; q2 < 2; ++q2)
      #pragma unroll
      for (int q3 = 0; q3 < 2; ++q3) {
        float xv = xb[q1 * 36 + q2 * 6 + q3];
        xs += xv;
        v += xv * pws[p * 8 + (q1 * 4 + q2 * 2 + q3)];
      }
  float bs = blk_sum(xs, s4);
  if (c == 0) g_part[t] = bs;
  res[t * 256 + c] = v;
  float mu = blk_sum(v, s4) * (1.f / 256.f);
  float dd = v - mu;
  float var = blk_sum(dd * dd, s4) * (1.f / 256.f);
  eln_bf[t * 256 + c] = bf16_rne(dd * rsqrtf(var + 1e-6f) * g1[c] + b1[c]);
}

// ---------------------------------------------------------------- global branch
// fused tok+LN1+qkv, all 8 batches; grid 48 (64 cols x 4 k-chunks each).
// tok LN stats are closed-form in m: tok = m*tw+tb -> mu,var from S1..S5.
__global__ __launch_bounds__(256) void k_g_qkv(
    const float* __restrict__ g_part, const float* __restrict__ tw_,
    const float* __restrict__ tb_, const float* __restrict__ g1,
    const float* __restrict__ b1, const float* __restrict__ wq,
    const float* __restrict__ wk, const float* __restrict__ wv,
    float* __restrict__ gqkv) {
  __shared__ float ts[2048];
  __shared__ float red[64][4][8];
  __shared__ float s4[4], m_s[8];
  int tid = threadIdx.x;
  float tw = tw_[tid], tb = tb_[tid], gg = g1[tid], bb = b1[tid];
  float S1 = blk_sum(tw, s4);
  float S2 = blk_sum(tw * tw, s4);
  float S3 = blk_sum(tb, s4);
  float S4 = blk_sum(tb * tb, s4);
  float S5 = blk_sum(tw * tb, s4);
  {
    int b = tid >> 5, sl = tid & 31;
    float a = 0.f;
    for (int k = sl; k < 216; k += 32) a += g_part[b * 216 + k];
    #pragma unroll
    for (int o = 16; o > 0; o >>= 1) a += __shfl_down(a, o, 32);
    if (sl == 0) m_s[b] = a * (1.f / 442368.f);   // 8 * 55296 over-count
  }
  __syncthreads();
  #pragma unroll
  for (int b = 0; b < 8; ++b) {
    float m = m_s[b];
    float mu = (m * S1 + S3) * (1.f / 256.f);
    float var = (m * m * S2 + 2.f * m * S5 + S4) * (1.f / 256.f) - mu * mu;
    ts[b * 256 + tid] = (m * tw + tb - mu) * rsqrtf(var + 1e-6f) * gg + bb;
  }
  __syncthreads();
  int col0 = blockIdx.x * 64;
  int cl = tid & 63, kq = tid >> 6;
  int col = col0 + cl;
  int m = col >> 10, cc = col & 1023;
  const float* W = (m == 0) ? wq : (m == 1) ? wk : wv;
  float acc[8] = {};
  for (int c = kq * 64; c < kq * 64 + 64; ++c) {
    float w = W[c * 1024 + cc];
    #pragma unroll
    for (int b = 0; b < 8; ++b) acc[b] = fmaf(ts[b * 256 + c], w, acc[b]);
  }
  #pragma unroll
  for (int b = 0; b < 8; ++b) red[cl][kq][b] = acc[b];
  __syncthreads();
  if (kq == 0) {
    #pragma unroll
    for (int b = 0; b < 8; ++b)
      gqkv[b * 3072 + col] = red[cl][0][b] + red[cl][1][b] + red[cl][2][b] + red[cl][3][b];
  }
}

// rank-1 score attention per (b,h); IN stats factor exactly through q,k sums.
__global__ void k_g_attn(const float* __restrict__ gq, float* __restrict__ g_o) {
  __shared__ float ks[256], vs[256], s4[4];
  int b = blockIdx.x >> 2, h = blockIdx.x & 3;
  int i = threadIdx.x;
  const float* base = gq + b * 3072 + h * 256;
  float q = base[i];
  float k = base[1024 + i];
  ks[i] = k;
  vs[i] = base[2048 + i];
  float sq  = blk_sum(q, s4);
  float sq2 = blk_sum(q * q, s4);
  float sk  = blk_sum(k, s4);
  float sk2 = blk_sum(k * k, s4);
  float tot  = sq * sk * (1.f / 65536.f);
  float tot2 = sq2 * sk2 * (1.f / 65536.f);
  float rstd = rsqrtf(tot2 - tot * tot + 1e-5f);
  float A = rstd, B = -tot * rstd;
  float den = 0.f, num = 0.f;
  for (int j = 0; j < 256; ++j) {
    float w = __expf(fmaf(q * ks[j], A, B));
    den += w; num += w * vs[j];
  }
  g_o[b * 1024 + (i << 2) + h] = num / den;   // (c outer, h inner)
}

// wo partials: block kc owns 32 rows of wo (32KB); all 8 batches. grid 32.
__global__ __launch_bounds__(256) void k_g_wo(
    const float* __restrict__ g_o, const float* __restrict__ wo,
    float* __restrict__ part) {
  __shared__ float os[256];                  // o[b][k-slice]: 8 x 32
  int kc = blockIdx.x, tid = threadIdx.x;
  os[tid] = g_o[(tid >> 5) * 1024 + kc * 32 + (tid & 31)];
  __syncthreads();
  float acc[8] = {};
  #pragma unroll
  for (int kk = 0; kk < 32; ++kk) {
    float w = wo[(size_t)(kc * 32 + kk) * 256 + tid];
    #pragma unroll
    for (int b = 0; b < 8; ++b) acc[b] = fmaf(os[b * 32 + kk], w, acc[b]);
  }
  #pragma unroll
  for (int b = 0; b < 8; ++b) part[kc * 2048 + b * 256 + tid] = acc[b];
}

// reduce wo-partials + recomputed tok residual -> LN2 -> t2g. grid 8.
__global__ void k_g_ln2g(const float* __restrict__ part, const float* __restrict__ g_part,
                         const float* __restrict__ tw_, const float* __restrict__ tb_,
                         const float* __restrict__ g2, const float* __restrict__ b2,
                         float* __restrict__ t2g) {
  __shared__ float s4[4];
  int b = blockIdx.x, c = threadIdx.x;
  float a = (c < 216) ? g_part[b * 216 + c] : 0.f;
  float m = blk_sum(a, s4) * (1.f / 442368.f);
  float v = m * tw_[c] + tb_[c];               // tok residual
  #pragma unroll
  for (int kc = 0; kc < 32; ++kc) v += part[kc * 2048 + b * 256 + c];
  float mu = blk_sum(v, s4) * (1.f / 256.f);
  float d = v - mu;
  float var = blk_sum(d * d, s4) * (1.f / 256.f);
  t2g[b * 256 + c] = d * rsqrtf(var + 1e-6f) * g2[c] + b2[c];
}

// g_vec[b][o] = gelu(dot(t2[b], mow[o]) + mob[o]). grid 32 x (8 o-rows each).
__global__ __launch_bounds__(256) void k_g_mo(
    const float* __restrict__ t2g, const float* __restrict__ mow,
    const float* __restrict__ mob, float* __restrict__ g_vec) {
  __shared__ float ts[2048];
  int tid = threadIdx.x;
  for (int i = tid; i < 2048; i += 256) ts[i] = t2g[i];
  __syncthreads();
  int ol = tid >> 5, cs = tid & 31;
  int o = blockIdx.x * 8 + ol;
  const float* wrow = mow + (size_t)o * 256;
  float acc[8] = {};
  #pragma unroll
  for (int i = 0; i < 8; ++i) {
    float w = wrow[i * 32 + cs];
    #pragma unroll
    for (int b = 0; b < 8; ++b) acc[b] = fmaf(ts[b * 256 + i * 32 + cs], w, acc[b]);
  }
  #pragma unroll
  for (int b = 0; b < 8; ++b) {
    float v = acc[b];
    #pragma unroll
    for (int off = 16; off > 0; off >>= 1) v += __shfl_down(v, off, 32);
    if (cs == 0) g_vec[b * 256 + o] = gelu_f(v + mob[o]);
  }
}

// ---------------------------------------------------------------- weight prep
DEVFN void trc_tile(const float* __restrict__ in, u16* __restrict__ out,
                    int R, int C, int r0, int c0, float (*tile)[33], int tid) {
  int tx = tid & 31, ty = tid >> 5;
  for (int i = ty; i < 32; i += 8) tile[i][tx] = in[(size_t)(r0 + i) * C + c0 + tx];
  __syncthreads();
  for (int i = ty; i < 32; i += 8)
    out[(size_t)(c0 + i) * R + r0 + tx] = bf16_rne(tile[tx][i]);
}

__global__ void k_prep(const float* __restrict__ wq, const float* __restrict__ wk,
                       const float* __restrict__ wv, const float* __restrict__ wo,
                       const float* __restrict__ mow,
                       u16* __restrict__ WcatT, u16* __restrict__ woT,
                       u16* __restrict__ moB) {
  __shared__ float tile[32][33];
  int bid = blockIdx.x, tid = threadIdx.x;
  if (bid < 768) {            // wq/wk/wv: [256][1024] -> [1024][256]
    int which = bid >> 8, b2 = bid & 255;
    const float* in = (which == 0) ? wq : (which == 1) ? wk : wv;
    u16* out = WcatT + which * 262144;
    int r0 = (b2 & 7) * 32, c0 = (b2 >> 3) * 32;
    trc_tile(in, out, 256, 1024, r0, c0, tile, tid);
  } else if (bid < 1024) {    // wo: [1024][256] -> [256][1024]
    int b2 = bid - 768;
    int r0 = (b2 & 31) * 32, c0 = (b2 >> 5) * 32;
    trc_tile(wo, woT, 1024, 256, r0, c0, tile, tid);
  } else {                    // mo_w cast (layout [o][c] already = BT)
    int i = (bid - 1024) * 256 + tid;
    moB[i] = bf16_rne(mow[i]);
  }
}

// ---------------------------------------------------------------- bf16 MFMA GEMM
// C[M][N] fp32 = A[M][K] bf16 @ BT[N][K] bf16. 64x64 tile, BK=32, 4 waves 2x2.
__global__ __launch_bounds__(256) void k_gemm_bf16(
    const u16* __restrict__ A, const u16* __restrict__ BT,
    float* __restrict__ C, int M, int N, int K) {
  __shared__ __align__(16) u16 a_s[64][40];
  __shared__ __align__(16) u16 b_s[64][40];
  int tid = threadIdx.x;
  int rowblk = blockIdx.x * 64, colblk = blockIdx.y * 64;
  int sr = tid & 63, sk = (tid >> 6) * 8;
  int lane = tid & 63, w = tid >> 6;
  int wr = (w >> 1) * 32, wc = (w & 1) * 32;
  int fm = lane & 15, fk = (lane >> 4) * 8;
  f32x4 acc[2][2] = {};
  for (int kt = 0; kt < K; kt += 32) {
    __syncthreads();
    *(uint4*)&a_s[sr][sk] = *(const uint4*)&A[(size_t)(rowblk + sr) * K + kt + sk];
    *(uint4*)&b_s[sr][sk] = *(const uint4*)&BT[(size_t)(colblk + sr) * K + kt + sk];
    __syncthreads();
    bf16x8 bn[2];
    #pragma unroll
    for (int ni = 0; ni < 2; ++ni) bn[ni] = *(const bf16x8*)&b_s[wc + ni * 16 + fm][fk];
    #pragma unroll
    for (int mi = 0; mi < 2; ++mi) {
      bf16x8 af = *(const bf16x8*)&a_s[wr + mi * 16 + fm][fk];
      #pragma unroll
      for (int ni = 0; ni < 2; ++ni)
        acc[mi][ni] = __builtin_amdgcn_mfma_f32_16x16x32_bf16(af, bn[ni], acc[mi][ni], 0, 0, 0);
    }
  }
  int crow0 = rowblk + wr + (lane >> 4) * 4;
  int ccol  = colblk + wc + fm;
  #pragma unroll
  for (int mi = 0; mi < 2; ++mi)
    #pragma unroll
    for (int ni = 0; ni < 2; ++ni)
      #pragma unroll
      for (int r = 0; r < 4; ++r)
        C[(size_t)(crow0 + mi * 16 + r) * N + ccol + ni * 16] = acc[mi][ni][r];
}

// split-K variant (local wo GEMM): grid (M/64, N/64, 2); z-half of K each,
// writes its own partial buffer Cp + z*M*N.
__global__ __launch_bounds__(256) void k_gemm_bf16_sk(
    const u16* __restrict__ A, const u16* __restrict__ BT,
    float* __restrict__ Cp, int M, int N, int K) {
  __shared__ __align__(16) u16 a_s[64][40];
  __shared__ __align__(16) u16 b_s[64][40];
  int tid = threadIdx.x;
  int rowblk = blockIdx.x * 64, colblk = blockIdx.y * 64;
  int kz = blockIdx.z, khalf = K >> 1;
  float* C = Cp + (size_t)kz * M * N;
  int sr = tid & 63, sk = (tid >> 6) * 8;
  int lane = tid & 63, w = tid >> 6;
  int wr = (w >> 1) * 32, wc = (w & 1) * 32;
  int fm = lane & 15, fk = (lane >> 4) * 8;
  f32x4 acc[2][2] = {};
  for (int kt = kz * khalf; kt < (kz + 1) * khalf; kt += 32) {
    __syncthreads();
    *(uint4*)&a_s[sr][sk] = *(const uint4*)&A[(size_t)(rowblk + sr) * K + kt + sk];
    *(uint4*)&b_s[sr][sk] = *(const uint4*)&BT[(size_t)(colblk + sr) * K + kt + sk];
    __syncthreads();
    bf16x8 bn[2];
    #pragma unroll
    for (int ni = 0; ni < 2; ++ni) bn[ni] = *(const bf16x8*)&b_s[wc + ni * 16 + fm][fk];
    #pragma unroll
    for (int mi = 0; mi < 2; ++mi) {
      bf16x8 af = *(const bf16x8*)&a_s[wr + mi * 16 + fm][fk];
      #pragma unroll
      for (int ni = 0; ni < 2; ++ni)
        acc[mi][ni] = __builtin_amdgcn_mfma_f32_16x16x32_bf16(af, bn[ni], acc[mi][ni], 0, 0, 0);
    }
  }
  int crow0 = rowblk + wr + (lane >> 4) * 4;
  int ccol  = colblk + wc + fm;
  #pragma unroll
  for (int mi = 0; mi < 2; ++mi)
    #pragma unroll
    for (int ni = 0; ni < 2; ++ni)
      #pragma unroll
      for (int r = 0; r < 4; ++r)
        C[(size_t)(crow0 + mi * 16 + r) * N + ccol + ni * 16] = acc[mi][ni][r];
}

// mo GEMM + fused final: out = x + gvec + gelu(C + mob). A=t2b, BT=moB, N=256.
__global__ __launch_bounds__(256) void k_gemm_mo_final(
    const u16* __restrict__ A, const u16* __restrict__ BT,
    const float* __restrict__ x, const float* __restrict__ gvec,
    const float* __restrict__ mob, float* __restrict__ out) {
  __shared__ __align__(16) u16 a_s[64][40];
  __shared__ __align__(16) u16 b_s[64][40];
  const int N = 256, K = 256;
  int tid = threadIdx.x;
  int rowblk = blockIdx.x * 64, colblk = blockIdx.y * 64;
  int sr = tid & 63, sk = (tid >> 6) * 8;
  int lane = tid & 63, w = tid >> 6;
  int wr = (w >> 1) * 32, wc = (w & 1) * 32;
  int fm = lane & 15, fk = (lane >> 4) * 8;
  f32x4 acc[2][2] = {};
  for (int kt = 0; kt < K; kt += 32) {
    __syncthreads();
    *(uint4*)&a_s[sr][sk] = *(const uint4*)&A[(size_t)(rowblk + sr) * K + kt + sk];
    *(uint4*)&b_s[sr][sk] = *(const uint4*)&BT[(size_t)(colblk + sr) * K + kt + sk];
    __syncthreads();
    bf16x8 bn[2];
    #pragma unroll
    for (int ni = 0; ni < 2; ++ni) bn[ni] = *(const bf16x8*)&b_s[wc + ni * 16 + fm][fk];
    #pragma unroll
    for (int mi = 0; mi < 2; ++mi) {
      bf16x8 af = *(const bf16x8*)&a_s[wr + mi * 16 + fm][fk];
      #pragma unroll
      for (int ni = 0; ni < 2; ++ni)
        acc[mi][ni] = __builtin_amdgcn_mfma_f32_16x16x32_bf16(af, bn[ni], acc[mi][ni], 0, 0, 0);
    }
  }
  int crow0 = rowblk + wr + (lane >> 4) * 4;
  int ccol  = colblk + wc + fm;
  #pragma unroll
  for (int mi = 0; mi < 2; ++mi)
    #pragma unroll
    for (int ni = 0; ni < 2; ++ni) {
      int col = ccol + ni * 16;
      float mb = mob[col];
      #pragma unroll
      for (int r = 0; r < 4; ++r) {
        int row = crow0 + mi * 16 + r;
        int b = row / 216, s = row - b * 216;
        size_t idx = (size_t)b * 55296 + (size_t)col * 216 + s;
        out[idx] = x[idx] + gvec[b * 256 + col] + gelu_f(acc[mi][ni][r] + mb);
      }
    }
}

// ---------------------------------------------------------------- local attention (MFMA)
// Block = (n,h), 256 threads = 4 waves. S^T via mfma(K,Q) (K=8 zero-padded),
// exp -> bf16 P (wave-private), PV via mfma(P, V^T) with ones-row denominator.
__global__ __launch_bounds__(256) void k_l_attn(const float* __restrict__ qkv,
                                                u16* __restrict__ o_buf) {
  __shared__ __align__(16) uint4 Qb[256], Kb[256];
  __shared__ __align__(16) u16 vt[16][264];
  __shared__ __align__(16) u16 Pl[256][72];
  __shared__ float rqA[64][4], rkA[64][4], rlq[64][4], rlk[64][4], s_ab[2];
  int n = blockIdx.x, h = blockIdx.y;
  int b = n / 27, patch = n % 27;
  int bz = 2 * (patch / 9), by = 2 * ((patch / 3) % 3), bx = 2 * (patch % 3);
  int tid = threadIdx.x;
  {
    int c = tid;
    float qv[8], kv[8], vv[8];
    #pragma unroll
    for (int p = 0; p < 8; ++p) {
      int t_l = b * 216 + (bz + (p >> 2)) * 36 + (by + ((p >> 1) & 1)) * 6 + (bx + (p & 1));
      const float* row = qkv + (size_t)t_l * 3072 + (c << 2) + h;
      qv[p] = row[0]; kv[p] = row[1024]; vv[p] = row[2048];
    }
    uint32_t qw[4], kw[4];
    #pragma unroll
    for (int i = 0; i < 4; ++i) {
      qw[i] = (uint32_t)bf16_rne(qv[2 * i]) | ((uint32_t)bf16_rne(qv[2 * i + 1]) << 16);
      kw[i] = (uint32_t)bf16_rne(kv[2 * i]) | ((uint32_t)bf16_rne(kv[2 * i + 1]) << 16);
    }
    Qb[c] = make_uint4(qw[0], qw[1], qw[2], qw[3]);
    Kb[c] = make_uint4(kw[0], kw[1], kw[2], kw[3]);
    #pragma unroll
    for (int p = 0; p < 8; ++p) vt[p][c] = bf16_rne(vv[p]);
    vt[8][c] = 0x3F80u;
    #pragma unroll
    for (int r2 = 9; r2 < 16; ++r2) vt[r2][c] = 0;
  }
  __syncthreads();
  {
    int p = tid & 63, chunk = tid >> 6;
    int d = p >> 3, e = p & 7;
    float aq = 0.f, ak = 0.f, lq = 0.f, lk = 0.f;
    for (int cc = chunk * 64; cc < chunk * 64 + 64; ++cc) {
      const u16* qr = (const u16*)&Qb[cc];
      const u16* kr = (const u16*)&Kb[cc];
      float qd = bf2f(qr[d]), qe = bf2f(qr[e]);
      float kd = bf2f(kr[d]), ke = bf2f(kr[e]);
      aq = fmaf(qd, qe, aq); ak = fmaf(kd, ke, ak);
      if (e == 0) { lq += qd; lk += kd; }
    }
    rqA[p][chunk] = aq; rkA[p][chunk] = ak; rlq[p][chunk] = lq; rlk[p][chunk] = lk;
    __syncthreads();
    if (tid < 64) {
      float gq = rqA[tid][0] + rqA[tid][1] + rqA[tid][2] + rqA[tid][3];
      float gk = rkA[tid][0] + rkA[tid][1] + rkA[tid][2] + rkA[tid][3];
      float vprod = gq * gk, vmu = 0.f;
      if ((tid & 7) == 0) {
        float slq = rlq[tid][0] + rlq[tid][1] + rlq[tid][2] + rlq[tid][3];
        float slk = rlk[tid][0] + rlk[tid][1] + rlk[tid][2] + rlk[tid][3];
        vmu = slq * slk;
      }
      #pragma unroll
      for (int o = 32; o > 0; o >>= 1) {
        vprod += __shfl_down(vprod, o, 64);
        vmu   += __shfl_down(vmu, o, 64);
      }
      if (tid == 0) {
        float mu = vmu * (1.f / 65536.f), m2 = vprod * (1.f / 65536.f);
        float rstd = rsqrtf(m2 - mu * mu + 1e-5f);
        s_ab[0] = rstd; s_ab[1] = -mu * rstd;
      }
    }
    __syncthreads();
  }
  float Af = s_ab[0], Bf = s_ab[1];
  int lane = tid & 63, w = tid >> 6;
  int l15 = lane & 15, lg = lane >> 4;
  bf16x8 qf[4];
  #pragma unroll
  for (int qt = 0; qt < 4; ++qt)
    qf[qt] = *(const bf16x8*)&Qb[w * 64 + qt * 16 + l15];
  f32x4 acc_o[4] = {};
  #pragma unroll 1
  for (int jc = 0; jc < 4; ++jc) {
    bf16x8 kf[4];
    #pragma unroll
    for (int jt = 0; jt < 4; ++jt) {
      bf16x8 z = {};
      if (lg == 0) z = *(const bf16x8*)&Kb[jc * 64 + jt * 16 + l15];
      kf[jt] = z;
    }
    #pragma unroll
    for (int jt = 0; jt < 4; ++jt) {
      #pragma unroll
      for (int qt = 0; qt < 4; ++qt) {
        f32x4 zc = {};
        f32x4 s = __builtin_amdgcn_mfma_f32_16x16x32_bf16(kf[jt], qf[qt], zc, 0, 0, 0);
        float e0 = __expf(fmaf(s[0], Af, Bf));
        float e1 = __expf(fmaf(s[1], Af, Bf));
        float e2 = __expf(fmaf(s[2], Af, Bf));
        float e3 = __expf(fmaf(s[3], Af, Bf));
        uint32_t w0 = (__float_as_uint(e0) >> 16) | (__float_as_uint(e1) & 0xFFFF0000u);
        uint32_t w1 = (__float_as_uint(e2) >> 16) | (__float_as_uint(e3) & 0xFFFF0000u);
        int q = w * 64 + qt * 16 + l15;
        *(uint2*)&Pl[q][jt * 16 + lg * 4] = make_uint2(w0, w1);
      }
    }
    #pragma unroll
    for (int ks = 0; ks < 2; ++ks) {
      bf16x8 vf = *(const bf16x8*)&vt[l15][jc * 64 + ks * 32 + lg * 8];
      #pragma unroll
      for (int qt = 0; qt < 4; ++qt) {
        bf16x8 pf = *(const bf16x8*)&Pl[w * 64 + qt * 16 + l15][ks * 32 + lg * 8];
        acc_o[qt] = __builtin_amdgcn_mfma_f32_16x16x32_bf16(pf, vf, acc_o[qt], 0, 0, 0);
      }
    }
  }
  int src = ((lane & 48) + 8) << 2;
  int p = l15;
  int t_l = b * 216 + (bz + (p >> 2)) * 36 + (by + ((p >> 1) & 1)) * 6 + (bx + (p & 1));
  #pragma unroll
  for (int qt = 0; qt < 4; ++qt) {
    #pragma unroll
    for (int r = 0; r < 4; ++r) {
      float den = __int_as_float(__builtin_amdgcn_ds_bpermute(src, __float_as_int(acc_o[qt][r])));
      if (p < 8) {
        int q = w * 64 + qt * 16 + lg * 4 + r;
        o_buf[(size_t)t_l * 1024 + (q << 2) + h] = bf16_rne(acc_o[qt][r] / den);
      }
    }
  }
}

// t2 = LN(proj0 + proj1 + res) -> bf16 (mo-GEMM A). proj split-K partials.
__global__ void k_l_ln2(const float* __restrict__ proj0, const float* __restrict__ proj1,
                        const float* __restrict__ res,
                        const float* __restrict__ g2, const float* __restrict__ b2,
                        u16* __restrict__ t2b) {
  __shared__ float s4[4];
  int t = blockIdx.x, c = threadIdx.x;
  float v = proj0[t * 256 + c] + proj1[t * 256 + c] + res[t * 256 + c];
  float mu = blk_sum(v, s4) * (1.f / 256.f);
  float d = v - mu;
  float var = blk_sum(d * d, s4) * (1.f / 256.f);
  t2b[t * 256 + c] = bf16_rne(d * rsqrtf(var + 1e-6f) * g2[c] + b2[c]);
}

// ---------------------------------------------------------------- launcher
extern "C" void kernel_launch(void* const* d_in, const int* in_sizes, int n_in,
                              void* d_out, int out_size, void* d_ws, size_t ws_size,
                              hipStream_t stream) {
  const float* x     = (const float*)d_in[0];
  const float* g_tw  = (const float*)d_in[1];
  const float* g_tb  = (const float*)d_in[2];
  const float* g_l1g = (const float*)d_in[3];
  const float* g_l1b = (const float*)d_in[4];
  const float* g_wq  = (const float*)d_in[5];
  const float* g_wk  = (const float*)d_in[6];
  const float* g_wv  = (const float*)d_in[7];
  const float* g_wo  = (const float*)d_in[8];
  const float* g_l2g = (const float*)d_in[9];
  const float* g_l2b = (const float*)d_in[10];
  const float* g_mow = (const float*)d_in[11];
  const float* g_mob = (const float*)d_in[12];
  const float* l_pw  = (const float*)d_in[13];
  const float* l_pb  = (const float*)d_in[14];
  const float* l_l1g = (const float*)d_in[15];
  const float* l_l1b = (const float*)d_in[16];
  const float* l_wq  = (const float*)d_in[17];
  const float* l_wk  = (const float*)d_in[18];
  const float* l_wv  = (const float*)d_in[19];
  const float* l_wo  = (const float*)d_in[20];
  const float* l_l2g = (const float*)d_in[21];
  const float* l_l2b = (const float*)d_in[22];
  const float* l_mow = (const float*)d_in[23];
  const float* l_mob = (const float*)d_in[24];
  float* out = (float*)d_out;
  float* ws  = (float*)d_ws;

  // workspace layout (float offsets; bf16 regions hold 2 vals per float slot)
  float* g_qkv  = ws + 4096;     // 24576
  float* g_o    = ws + 28672;    // 8192
  float* g_vec  = ws + 36864;    // 2048
  float* g_part = ws + 38912;    // 1728
  float* res    = ws + 40960;    // 442368 f32
  u16*   eln_bf = (u16*)(ws + 483328);   // 442368 u16
  u16*   WcatT  = (u16*)(ws + 704512);   // 786432 u16 [3072 j][256 c]
  u16*   woT    = (u16*)(ws + 1097728);  // 262144 u16 [256][1024]
  u16*   moB    = (u16*)(ws + 1228800);  // 65536  u16
  float* qkv    = ws + 1261568;  // 5308416 f32
  u16*   o_buf  = (u16*)(ws + 6569984);  // 1769472 u16
  float* proj   = ws + 7454720;  // 2 x 442368 f32 (split-K partials)
  u16*   t2b    = (u16*)(ws + 8339456);  // 442368 u16
  float* part_wo= ws + 8560640;  // 65536 (32 kc x 8 b x 256 c)
  float* t2g    = ws + 8626176;  // 2048

  // weight prep: one kernel
  k_prep<<<1280, 256, 0, stream>>>(l_wq, l_wk, l_wv, l_wo, l_mow, WcatT, woT, moB);

  // local tok (feeds both branches)
  k_l_tok<<<1728, 256, 0, stream>>>(x, l_pw, l_pb, l_l1g, l_l1b, res, eln_bf, g_part);

  // global branch
  k_g_qkv<<<48, 256, 0, stream>>>(g_part, g_tw, g_tb, g_l1g, g_l1b,
                                  g_wq, g_wk, g_wv, g_qkv);
  k_g_attn<<<32, 256, 0, stream>>>(g_qkv, g_o);
  k_g_wo<<<32, 256, 0, stream>>>(g_o, g_wo, part_wo);
  k_g_ln2g<<<8, 256, 0, stream>>>(part_wo, g_part, g_tw, g_tb, g_l2g, g_l2b, t2g);
  k_g_mo<<<32, 256, 0, stream>>>(t2g, g_mow, g_mob, g_vec);

  // local branch
  k_gemm_bf16<<<dim3(27, 48), 256, 0, stream>>>(eln_bf, WcatT, qkv, 1728, 3072, 256);
  k_l_attn<<<dim3(216, 4), 256, 0, stream>>>(qkv, o_buf);
  k_gemm_bf16_sk<<<dim3(27, 4, 2), 256, 0, stream>>>(o_buf, woT, proj, 1728, 256, 1024);
  k_l_ln2<<<1728, 256, 0, stream>>>(proj, proj + 442368, res, l_l2g, l_l2b, t2b);
  k_gemm_mo_final<<<dim3(27, 4), 256, 0, stream>>>(t2b, moB, x, g_vec, l_mob, out);
}

// Round 11
// 115.553 us; speedup vs baseline: 1.9546x; 1.1937x over previous
//
#include <hip/hip_runtime.h>
#include <stdint.h>
#include <math.h>

#define DEVFN __device__ __forceinline__
typedef unsigned short u16;
typedef short bf16x8 __attribute__((ext_vector_type(8)));
typedef float f32x4  __attribute__((ext_vector_type(4)));

// ---------------------------------------------------------------- helpers
DEVFN float blk_sum(float v, float* s4) {          // 256-thread block sum
  #pragma unroll
  for (int o = 32; o > 0; o >>= 1) v += __shfl_down(v, o, 64);
  __syncthreads();
  if ((threadIdx.x & 63) == 0) s4[threadIdx.x >> 6] = v;
  __syncthreads();
  return s4[0] + s4[1] + s4[2] + s4[3];
}

DEVFN float gelu_f(float x) {
  return 0.5f * x * (1.f + erff(x * 0.7071067811865475f));
}

DEVFN u16 bf16_rne(float f) {                      // fp32 -> bf16 round-nearest-even
  uint32_t u = __float_as_uint(f);
  return (u16)((u + 0x7fffu + ((u >> 16) & 1u)) >> 16);
}

DEVFN float bf2f(u16 v) { return __uint_as_float(((uint32_t)v) << 16); }

// ---------------------------------------------------------------- L1: local tok + weight prep rider
DEVFN void trc_tile(const float* __restrict__ in, u16* __restrict__ out,
                    int R, int C, int r0, int c0, float (*tile)[33], int tid) {
  int tx = tid & 31, ty = tid >> 5;
  for (int i = ty; i < 32; i += 8) tile[i][tx] = in[(size_t)(r0 + i) * C + c0 + tx];
  __syncthreads();
  for (int i = ty; i < 32; i += 8)
    out[(size_t)(c0 + i) * R + r0 + tx] = bf16_rne(tile[tx][i]);
}

// blocks [0,1728): patch embed + LN1 (+ raw-x partial sums, 8x over-counted).
// blocks [1728,3008): weight prep (wq/wk/wv/wo transpose+cast, mo cast).
__global__ __launch_bounds__(256) void k_l_tok_prep(
    const float* __restrict__ x, const float* __restrict__ pw,
    const float* __restrict__ pb, const float* __restrict__ g1,
    const float* __restrict__ b1, float* __restrict__ res,
    u16* __restrict__ eln_bf, float* __restrict__ g_part,
    const float* __restrict__ wq, const float* __restrict__ wk,
    const float* __restrict__ wv, const float* __restrict__ wo,
    const float* __restrict__ mow, u16* __restrict__ WcatT,
    u16* __restrict__ woT, u16* __restrict__ moB) {
  __shared__ __align__(16) char smem[8448];
  int bid0 = blockIdx.x, tid = threadIdx.x;
  if (bid0 < 1728) {
    float* pws = (float*)smem;
    float* s4 = (float*)(smem + 256);
    int t = bid0;
    int b = t / 216, s = t % 216;
    int z = s / 36, y = (s / 6) % 6, xx = s % 6;
    int d = z >> 1, p1 = z & 1, hh = y >> 1, p2 = y & 1, ww = xx >> 1, p3 = xx & 1;
    int p = p1 * 4 + p2 * 2 + p3;
    int c = tid;
    if (c < 64) pws[c] = pw[c];
    __syncthreads();
    const float* xb = x + (b * 256 + c) * 216 + (2 * d) * 36 + (2 * hh) * 6 + 2 * ww;
    float v = pb[p];
    float xs = 0.f;
    #pragma unroll
    for (int q1 = 0; q1 < 2; ++q1)
      #pragma unroll
      for (int q2 = 0; q2 < 2; ++q2)
        #pragma unroll
        for (int q3 = 0; q3 < 2; ++q3) {
          float xv = xb[q1 * 36 + q2 * 6 + q3];
          xs += xv;
          v += xv * pws[p * 8 + (q1 * 4 + q2 * 2 + q3)];
        }
    float bs = blk_sum(xs, s4);
    if (c == 0) g_part[t] = bs;
    res[t * 256 + c] = v;
    float mu = blk_sum(v, s4) * (1.f / 256.f);
    float dd = v - mu;
    float var = blk_sum(dd * dd, s4) * (1.f / 256.f);
    eln_bf[t * 256 + c] = bf16_rne(dd * rsqrtf(var + 1e-6f) * g1[c] + b1[c]);
  } else {
    float (*tile)[33] = (float(*)[33])smem;
    int bid = bid0 - 1728;
    if (bid < 768) {            // wq/wk/wv: [256][1024] -> [1024][256]
      int which = bid >> 8, b2 = bid & 255;
      const float* in = (which == 0) ? wq : (which == 1) ? wk : wv;
      u16* out = WcatT + which * 262144;
      int r0 = (b2 & 7) * 32, c0 = (b2 >> 3) * 32;
      trc_tile(in, out, 256, 1024, r0, c0, tile, tid);
    } else if (bid < 1024) {    // wo: [1024][256] -> [256][1024]
      int b2 = bid - 768;
      int r0 = (b2 & 31) * 32, c0 = (b2 >> 5) * 32;
      trc_tile(wo, woT, 1024, 256, r0, c0, tile, tid);
    } else {                    // mo_w cast
      int i = (bid - 1024) * 256 + tid;
      moB[i] = bf16_rne(mow[i]);
    }
  }
}

// ---------------------------------------------------------------- L2: local qkv GEMM + global qkv rider
// blocks [0,1296): bf16 MFMA GEMM qkv (M=1728,N=3072,K=256), 64x64 tile.
// blocks [1296,1344): fused global tok+LN1+qkv (closed-form LN stats).
__global__ __launch_bounds__(256) void k_gemm_qkv_fused(
    const u16* __restrict__ A, const u16* __restrict__ BT, float* __restrict__ C,
    const float* __restrict__ g_part, const float* __restrict__ tw_,
    const float* __restrict__ tb_, const float* __restrict__ g1,
    const float* __restrict__ b1, const float* __restrict__ wq,
    const float* __restrict__ wk, const float* __restrict__ wv,
    float* __restrict__ gqkv) {
  __shared__ __align__(16) char smem[16640];
  int bid = blockIdx.x, tid = threadIdx.x;
  if (bid < 1296) {
    const int N = 3072, K = 256;
    u16 (*a_s)[40] = (u16(*)[40])smem;
    u16 (*b_s)[40] = (u16(*)[40])(smem + 5120);
    int rowblk = (bid % 27) * 64, colblk = (bid / 27) * 64;
    int sr = tid & 63, sk = (tid >> 6) * 8;
    int lane = tid & 63, w = tid >> 6;
    int wr = (w >> 1) * 32, wc = (w & 1) * 32;
    int fm = lane & 15, fk = (lane >> 4) * 8;
    f32x4 acc[2][2] = {};
    for (int kt = 0; kt < K; kt += 32) {
      __syncthreads();
      *(uint4*)&a_s[sr][sk] = *(const uint4*)&A[(size_t)(rowblk + sr) * K + kt + sk];
      *(uint4*)&b_s[sr][sk] = *(const uint4*)&BT[(size_t)(colblk + sr) * K + kt + sk];
      __syncthreads();
      bf16x8 bn[2];
      #pragma unroll
      for (int ni = 0; ni < 2; ++ni) bn[ni] = *(const bf16x8*)&b_s[wc + ni * 16 + fm][fk];
      #pragma unroll
      for (int mi = 0; mi < 2; ++mi) {
        bf16x8 af = *(const bf16x8*)&a_s[wr + mi * 16 + fm][fk];
        #pragma unroll
        for (int ni = 0; ni < 2; ++ni)
          acc[mi][ni] = __builtin_amdgcn_mfma_f32_16x16x32_bf16(af, bn[ni], acc[mi][ni], 0, 0, 0);
      }
    }
    int crow0 = rowblk + wr + (lane >> 4) * 4;
    int ccol  = colblk + wc + fm;
    #pragma unroll
    for (int mi = 0; mi < 2; ++mi)
      #pragma unroll
      for (int ni = 0; ni < 2; ++ni)
        #pragma unroll
        for (int r = 0; r < 4; ++r)
          C[(size_t)(crow0 + mi * 16 + r) * N + ccol + ni * 16] = acc[mi][ni][r];
  } else {
    float* ts = (float*)smem;                       // 2048 f
    float (*red)[4][8] = (float(*)[4][8])(smem + 8192);
    float* s4 = (float*)(smem + 16384);
    float* m_s = (float*)(smem + 16400);
    int rb = bid - 1296;
    float tw = tw_[tid], tb = tb_[tid], gg = g1[tid], bb = b1[tid];
    float S1 = blk_sum(tw, s4);
    float S2 = blk_sum(tw * tw, s4);
    float S3 = blk_sum(tb, s4);
    float S4 = blk_sum(tb * tb, s4);
    float S5 = blk_sum(tw * tb, s4);
    {
      int b = tid >> 5, sl = tid & 31;
      float a = 0.f;
      for (int k = sl; k < 216; k += 32) a += g_part[b * 216 + k];
      #pragma unroll
      for (int o = 16; o > 0; o >>= 1) a += __shfl_down(a, o, 32);
      if (sl == 0) m_s[b] = a * (1.f / 442368.f);   // 8 * 55296 over-count
    }
    __syncthreads();
    #pragma unroll
    for (int b = 0; b < 8; ++b) {
      float m = m_s[b];
      float mu = (m * S1 + S3) * (1.f / 256.f);
      float var = (m * m * S2 + 2.f * m * S5 + S4) * (1.f / 256.f) - mu * mu;
      ts[b * 256 + tid] = (m * tw + tb - mu) * rsqrtf(var + 1e-6f) * gg + bb;
    }
    __syncthreads();
    int col0 = rb * 64;
    int cl = tid & 63, kq = tid >> 6;
    int col = col0 + cl;
    int m = col >> 10, cc = col & 1023;
    const float* W = (m == 0) ? wq : (m == 1) ? wk : wv;
    float acc[8] = {};
    for (int c = kq * 64; c < kq * 64 + 64; ++c) {
      float w = W[c * 1024 + cc];
      #pragma unroll
      for (int b = 0; b < 8; ++b) acc[b] = fmaf(ts[b * 256 + c], w, acc[b]);
    }
    #pragma unroll
    for (int b = 0; b < 8; ++b) red[cl][kq][b] = acc[b];
    __syncthreads();
    if (kq == 0) {
      #pragma unroll
      for (int b = 0; b < 8; ++b)
        gqkv[b * 3072 + col] = red[cl][0][b] + red[cl][1][b] + red[cl][2][b] + red[cl][3][b];
    }
  }
}

// ---------------------------------------------------------------- L3: local attention + global attn rider
// blocks [0,864): MFMA local attention (n=bid>>2, h=bid&3).
// blocks [864,896): rank-1 global attention.
__global__ __launch_bounds__(256) void k_l_attn_fused(
    const float* __restrict__ qkv, u16* __restrict__ o_buf,
    const float* __restrict__ gq, float* __restrict__ g_o) {
  __shared__ __align__(16) uint4 Qb[256], Kb[256];
  __shared__ __align__(16) u16 vt[16][264];
  __shared__ __align__(16) u16 Pl[256][72];
  __shared__ float rqA[64][4], rkA[64][4], rlq[64][4], rlk[64][4], s_ab[2];
  int bid = blockIdx.x, tid = threadIdx.x;
  if (bid >= 864) {                       // ---- global attn rider
    float* ks = (float*)Qb;               // overlay: 1KB
    float* vs = ks + 256;
    float* s4 = (float*)Kb;
    int idx = bid - 864;
    int b = idx >> 2, h = idx & 3;
    int i = tid;
    const float* base = gq + b * 3072 + h * 256;
    float q = base[i];
    float k = base[1024 + i];
    ks[i] = k;
    vs[i] = base[2048 + i];
    float sq  = blk_sum(q, s4);
    float sq2 = blk_sum(q * q, s4);
    float sk  = blk_sum(k, s4);
    float sk2 = blk_sum(k * k, s4);
    float tot  = sq * sk * (1.f / 65536.f);
    float tot2 = sq2 * sk2 * (1.f / 65536.f);
    float rstd = rsqrtf(tot2 - tot * tot + 1e-5f);
    float A = rstd, B = -tot * rstd;
    float den = 0.f, num = 0.f;
    for (int j = 0; j < 256; ++j) {
      float w = __expf(fmaf(q * ks[j], A, B));
      den += w; num += w * vs[j];
    }
    g_o[b * 1024 + (i << 2) + h] = num / den;
    return;
  }
  int n = bid >> 2, h = bid & 3;
  int b = n / 27, patch = n % 27;
  int bz = 2 * (patch / 9), by = 2 * ((patch / 3) % 3), bx = 2 * (patch % 3);
  {
    int c = tid;
    float qv[8], kv[8], vv[8];
    #pragma unroll
    for (int p = 0; p < 8; ++p) {
      int t_l = b * 216 + (bz + (p >> 2)) * 36 + (by + ((p >> 1) & 1)) * 6 + (bx + (p & 1));
      const float* row = qkv + (size_t)t_l * 3072 + (c << 2) + h;
      qv[p] = row[0]; kv[p] = row[1024]; vv[p] = row[2048];
    }
    uint32_t qw[4], kw[4];
    #pragma unroll
    for (int i = 0; i < 4; ++i) {
      qw[i] = (uint32_t)bf16_rne(qv[2 * i]) | ((uint32_t)bf16_rne(qv[2 * i + 1]) << 16);
      kw[i] = (uint32_t)bf16_rne(kv[2 * i]) | ((uint32_t)bf16_rne(kv[2 * i + 1]) << 16);
    }
    Qb[c] = make_uint4(qw[0], qw[1], qw[2], qw[3]);
    Kb[c] = make_uint4(kw[0], kw[1], kw[2], kw[3]);
    #pragma unroll
    for (int p = 0; p < 8; ++p) vt[p][c] = bf16_rne(vv[p]);
    vt[8][c] = 0x3F80u;
    #pragma unroll
    for (int r2 = 9; r2 < 16; ++r2) vt[r2][c] = 0;
  }
  __syncthreads();
  {
    int p = tid & 63, chunk = tid >> 6;
    int d = p >> 3, e = p & 7;
    float aq = 0.f, ak = 0.f, lq = 0.f, lk = 0.f;
    for (int cc = chunk * 64; cc < chunk * 64 + 64; ++cc) {
      const u16* qr = (const u16*)&Qb[cc];
      const u16* kr = (const u16*)&Kb[cc];
      float qd = bf2f(qr[d]), qe = bf2f(qr[e]);
      float kd = bf2f(kr[d]), ke = bf2f(kr[e]);
      aq = fmaf(qd, qe, aq); ak = fmaf(kd, ke, ak);
      if (e == 0) { lq += qd; lk += kd; }
    }
    rqA[p][chunk] = aq; rkA[p][chunk] = ak; rlq[p][chunk] = lq; rlk[p][chunk] = lk;
    __syncthreads();
    if (tid < 64) {
      float gq2 = rqA[tid][0] + rqA[tid][1] + rqA[tid][2] + rqA[tid][3];
      float gk = rkA[tid][0] + rkA[tid][1] + rkA[tid][2] + rkA[tid][3];
      float vprod = gq2 * gk, vmu = 0.f;
      if ((tid & 7) == 0) {
        float slq = rlq[tid][0] + rlq[tid][1] + rlq[tid][2] + rlq[tid][3];
        float slk = rlk[tid][0] + rlk[tid][1] + rlk[tid][2] + rlk[tid][3];
        vmu = slq * slk;
      }
      #pragma unroll
      for (int o = 32; o > 0; o >>= 1) {
        vprod += __shfl_down(vprod, o, 64);
        vmu   += __shfl_down(vmu, o, 64);
      }
      if (tid == 0) {
        float mu = vmu * (1.f / 65536.f), m2 = vprod * (1.f / 65536.f);
        float rstd = rsqrtf(m2 - mu * mu + 1e-5f);
        s_ab[0] = rstd; s_ab[1] = -mu * rstd;
      }
    }
    __syncthreads();
  }
  float Af = s_ab[0], Bf = s_ab[1];
  int lane = tid & 63, w = tid >> 6;
  int l15 = lane & 15, lg = lane >> 4;
  bf16x8 qf[4];
  #pragma unroll
  for (int qt = 0; qt < 4; ++qt)
    qf[qt] = *(const bf16x8*)&Qb[w * 64 + qt * 16 + l15];
  f32x4 acc_o[4] = {};
  #pragma unroll 1
  for (int jc = 0; jc < 4; ++jc) {
    bf16x8 kf[4];
    #pragma unroll
    for (int jt = 0; jt < 4; ++jt) {
      bf16x8 z = {};
      if (lg == 0) z = *(const bf16x8*)&Kb[jc * 64 + jt * 16 + l15];
      kf[jt] = z;
    }
    #pragma unroll
    for (int jt = 0; jt < 4; ++jt) {
      #pragma unroll
      for (int qt = 0; qt < 4; ++qt) {
        f32x4 zc = {};
        f32x4 s = __builtin_amdgcn_mfma_f32_16x16x32_bf16(kf[jt], qf[qt], zc, 0, 0, 0);
        float e0 = __expf(fmaf(s[0], Af, Bf));
        float e1 = __expf(fmaf(s[1], Af, Bf));
        float e2 = __expf(fmaf(s[2], Af, Bf));
        float e3 = __expf(fmaf(s[3], Af, Bf));
        uint32_t w0 = (__float_as_uint(e0) >> 16) | (__float_as_uint(e1) & 0xFFFF0000u);
        uint32_t w1 = (__float_as_uint(e2) >> 16) | (__float_as_uint(e3) & 0xFFFF0000u);
        int q = w * 64 + qt * 16 + l15;
        *(uint2*)&Pl[q][jt * 16 + lg * 4] = make_uint2(w0, w1);
      }
    }
    #pragma unroll
    for (int ks2 = 0; ks2 < 2; ++ks2) {
      bf16x8 vf = *(const bf16x8*)&vt[l15][jc * 64 + ks2 * 32 + lg * 8];
      #pragma unroll
      for (int qt = 0; qt < 4; ++qt) {
        bf16x8 pf = *(const bf16x8*)&Pl[w * 64 + qt * 16 + l15][ks2 * 32 + lg * 8];
        acc_o[qt] = __builtin_amdgcn_mfma_f32_16x16x32_bf16(pf, vf, acc_o[qt], 0, 0, 0);
      }
    }
  }
  int src = ((lane & 48) + 8) << 2;
  int p = l15;
  int t_l = b * 216 + (bz + (p >> 2)) * 36 + (by + ((p >> 1) & 1)) * 6 + (bx + (p & 1));
  #pragma unroll
  for (int qt = 0; qt < 4; ++qt) {
    #pragma unroll
    for (int r = 0; r < 4; ++r) {
      float den = __int_as_float(__builtin_amdgcn_ds_bpermute(src, __float_as_int(acc_o[qt][r])));
      if (p < 8) {
        int q = w * 64 + qt * 16 + lg * 4 + r;
        o_buf[(size_t)t_l * 1024 + (q << 2) + h] = bf16_rne(acc_o[qt][r] / den);
      }
    }
  }
}

// ---------------------------------------------------------------- L4: split-K wo GEMM + global wo rider
// blocks [0,216): split-K bf16 GEMM (M=1728,N=256,K=1024, 2 K-halves).
// blocks [216,248): global wo partials.
__global__ __launch_bounds__(256) void k_gemm_sk_fused(
    const u16* __restrict__ A, const u16* __restrict__ BT, float* __restrict__ Cp,
    const float* __restrict__ g_o, const float* __restrict__ wo,
    float* __restrict__ part) {
  __shared__ __align__(16) char smem[10240];
  int bid = blockIdx.x, tid = threadIdx.x;
  if (bid < 216) {
    const int M = 1728, N = 256, K = 1024;
    u16 (*a_s)[40] = (u16(*)[40])smem;
    u16 (*b_s)[40] = (u16(*)[40])(smem + 5120);
    int rowblk = (bid % 27) * 64, colblk = ((bid / 27) & 3) * 64;
    int kz = bid / 108, khalf = K >> 1;
    float* C = Cp + (size_t)kz * M * N;
    int sr = tid & 63, sk = (tid >> 6) * 8;
    int lane = tid & 63, w = tid >> 6;
    int wr = (w >> 1) * 32, wc = (w & 1) * 32;
    int fm = lane & 15, fk = (lane >> 4) * 8;
    f32x4 acc[2][2] = {};
    for (int kt = kz * khalf; kt < (kz + 1) * khalf; kt += 32) {
      __syncthreads();
      *(uint4*)&a_s[sr][sk] = *(const uint4*)&A[(size_t)(rowblk + sr) * K + kt + sk];
      *(uint4*)&b_s[sr][sk] = *(const uint4*)&BT[(size_t)(colblk + sr) * K + kt + sk];
      __syncthreads();
      bf16x8 bn[2];
      #pragma unroll
      for (int ni = 0; ni < 2; ++ni) bn[ni] = *(const bf16x8*)&b_s[wc + ni * 16 + fm][fk];
      #pragma unroll
      for (int mi = 0; mi < 2; ++mi) {
        bf16x8 af = *(const bf16x8*)&a_s[wr + mi * 16 + fm][fk];
        #pragma unroll
        for (int ni = 0; ni < 2; ++ni)
          acc[mi][ni] = __builtin_amdgcn_mfma_f32_16x16x32_bf16(af, bn[ni], acc[mi][ni], 0, 0, 0);
      }
    }
    int crow0 = rowblk + wr + (lane >> 4) * 4;
    int ccol  = colblk + wc + fm;
    #pragma unroll
    for (int mi = 0; mi < 2; ++mi)
      #pragma unroll
      for (int ni = 0; ni < 2; ++ni)
        #pragma unroll
        for (int r = 0; r < 4; ++r)
          C[(size_t)(crow0 + mi * 16 + r) * N + ccol + ni * 16] = acc[mi][ni][r];
  } else {
    float* os = (float*)smem;               // 8 x 32
    int kc = bid - 216;
    os[tid] = g_o[(tid >> 5) * 1024 + kc * 32 + (tid & 31)];
    __syncthreads();
    float acc[8] = {};
    #pragma unroll
    for (int kk = 0; kk < 32; ++kk) {
      float w = wo[(size_t)(kc * 32 + kk) * 256 + tid];
      #pragma unroll
      for (int b = 0; b < 8; ++b) acc[b] = fmaf(os[b * 32 + kk], w, acc[b]);
    }
    #pragma unroll
    for (int b = 0; b < 8; ++b) part[kc * 2048 + b * 256 + tid] = acc[b];
  }
}

// ---------------------------------------------------------------- L5: local LN2 + global LN2 rider
// blocks [0,1728): t2 = LN(proj0+proj1+res) -> bf16.
// blocks [1728,1736): global LN2 (reduce partials + recomputed tok residual).
__global__ __launch_bounds__(256) void k_l_ln2_fused(
    const float* __restrict__ proj0, const float* __restrict__ proj1,
    const float* __restrict__ res, const float* __restrict__ g2,
    const float* __restrict__ b2, u16* __restrict__ t2b,
    const float* __restrict__ part, const float* __restrict__ g_part,
    const float* __restrict__ tw_, const float* __restrict__ tb_,
    const float* __restrict__ gg2, const float* __restrict__ gb2,
    float* __restrict__ t2g) {
  __shared__ float s4[4];
  int bid = blockIdx.x, c = threadIdx.x;
  if (bid < 1728) {
    int t = bid;
    float v = proj0[t * 256 + c] + proj1[t * 256 + c] + res[t * 256 + c];
    float mu = blk_sum(v, s4) * (1.f / 256.f);
    float d = v - mu;
    float var = blk_sum(d * d, s4) * (1.f / 256.f);
    t2b[t * 256 + c] = bf16_rne(d * rsqrtf(var + 1e-6f) * g2[c] + b2[c]);
  } else {
    int b = bid - 1728;
    float a = (c < 216) ? g_part[b * 216 + c] : 0.f;
    float m = blk_sum(a, s4) * (1.f / 442368.f);
    float v = m * tw_[c] + tb_[c];
    #pragma unroll
    for (int kc = 0; kc < 32; ++kc) v += part[kc * 2048 + b * 256 + c];
    float mu = blk_sum(v, s4) * (1.f / 256.f);
    float d = v - mu;
    float var = blk_sum(d * d, s4) * (1.f / 256.f);
    t2g[b * 256 + c] = d * rsqrtf(var + 1e-6f) * gg2[c] + gb2[c];
  }
}

// ---------------------------------------------------------------- L6: global mo (standalone)
__global__ __launch_bounds__(256) void k_g_mo(
    const float* __restrict__ t2g, const float* __restrict__ mow,
    const float* __restrict__ mob, float* __restrict__ g_vec) {
  __shared__ float ts[2048];
  int tid = threadIdx.x;
  for (int i = tid; i < 2048; i += 256) ts[i] = t2g[i];
  __syncthreads();
  int ol = tid >> 5, cs = tid & 31;
  int o = blockIdx.x * 8 + ol;
  const float* wrow = mow + (size_t)o * 256;
  float acc[8] = {};
  #pragma unroll
  for (int i = 0; i < 8; ++i) {
    float w = wrow[i * 32 + cs];
    #pragma unroll
    for (int b = 0; b < 8; ++b) acc[b] = fmaf(ts[b * 256 + i * 32 + cs], w, acc[b]);
  }
  #pragma unroll
  for (int b = 0; b < 8; ++b) {
    float v = acc[b];
    #pragma unroll
    for (int off = 16; off > 0; off >>= 1) v += __shfl_down(v, off, 32);
    if (cs == 0) g_vec[b * 256 + o] = gelu_f(v + mob[o]);
  }
}

// ---------------------------------------------------------------- L7: mo GEMM + fused final, LDS-transposed epilogue
// out = x + gvec + gelu(C + mob); C-tile staged in LDS, column-walked so
// lanes map to consecutive s -> coalesced x/out traffic.
__global__ __launch_bounds__(256) void k_gemm_mo_final(
    const u16* __restrict__ A, const u16* __restrict__ BT,
    const float* __restrict__ x, const float* __restrict__ gvec,
    const float* __restrict__ mob, float* __restrict__ out) {
  __shared__ __align__(16) char smem[16640];
  u16 (*a_s)[40] = (u16(*)[40])smem;
  u16 (*b_s)[40] = (u16(*)[40])(smem + 5120);
  float (*ct)[65] = (float(*)[65])smem;       // reused after k-loop
  const int K = 256;
  int tid = threadIdx.x;
  int rowblk = blockIdx.x * 64, colblk = blockIdx.y * 64;
  int sr = tid & 63, sk = (tid >> 6) * 8;
  int lane = tid & 63, w = tid >> 6;
  int wr = (w >> 1) * 32, wc = (w & 1) * 32;
  int fm = lane & 15, fk = (lane >> 4) * 8;
  f32x4 acc[2][2] = {};
  for (int kt = 0; kt < K; kt += 32) {
    __syncthreads();
    *(uint4*)&a_s[sr][sk] = *(const uint4*)&A[(size_t)(rowblk + sr) * K + kt + sk];
    *(uint4*)&b_s[sr][sk] = *(const uint4*)&BT[(size_t)(colblk + sr) * K + kt + sk];
    __syncthreads();
    bf16x8 bn[2];
    #pragma unroll
    for (int ni = 0; ni < 2; ++ni) bn[ni] = *(const bf16x8*)&b_s[wc + ni * 16 + fm][fk];
    #pragma unroll
    for (int mi = 0; mi < 2; ++mi) {
      bf16x8 af = *(const bf16x8*)&a_s[wr + mi * 16 + fm][fk];
      #pragma unroll
      for (int ni = 0; ni < 2; ++ni)
        acc[mi][ni] = __builtin_amdgcn_mfma_f32_16x16x32_bf16(af, bn[ni], acc[mi][ni], 0, 0, 0);
    }
  }
  __syncthreads();                            // LDS now safe to repurpose
  int row_l0 = wr + (lane >> 4) * 4;
  #pragma unroll
  for (int mi = 0; mi < 2; ++mi)
    #pragma unroll
    for (int ni = 0; ni < 2; ++ni)
      #pragma unroll
      for (int r = 0; r < 4; ++r)
        ct[row_l0 + mi * 16 + r][wc + ni * 16 + fm] = acc[mi][ni][r];
  __syncthreads();
  int s_l = tid & 63;
  #pragma unroll 4
  for (int pass = 0; pass < 16; ++pass) {
    int col_l = (tid >> 6) * 16 + pass;
    int row = rowblk + s_l, col = colblk + col_l;
    int b = row / 216, s = row - b * 216;
    size_t idx = (size_t)b * 55296 + (size_t)col * 216 + s;
    out[idx] = x[idx] + gvec[b * 256 + col] + gelu_f(ct[s_l][col_l] + mob[col]);
  }
}

// ---------------------------------------------------------------- launcher
extern "C" void kernel_launch(void* const* d_in, const int* in_sizes, int n_in,
                              void* d_out, int out_size, void* d_ws, size_t ws_size,
                              hipStream_t stream) {
  const float* x     = (const float*)d_in[0];
  const float* g_tw  = (const float*)d_in[1];
  const float* g_tb  = (const float*)d_in[2];
  const float* g_l1g = (const float*)d_in[3];
  const float* g_l1b = (const float*)d_in[4];
  const float* g_wq  = (const float*)d_in[5];
  const float* g_wk  = (const float*)d_in[6];
  const float* g_wv  = (const float*)d_in[7];
  const float* g_wo  = (const float*)d_in[8];
  const float* g_l2g = (const float*)d_in[9];
  const float* g_l2b = (const float*)d_in[10];
  const float* g_mow = (const float*)d_in[11];
  const float* g_mob = (const float*)d_in[12];
  const float* l_pw  = (const float*)d_in[13];
  const float* l_pb  = (const float*)d_in[14];
  const float* l_l1g = (const float*)d_in[15];
  const float* l_l1b = (const float*)d_in[16];
  const float* l_wq  = (const float*)d_in[17];
  const float* l_wk  = (const float*)d_in[18];
  const float* l_wv  = (const float*)d_in[19];
  const float* l_wo  = (const float*)d_in[20];
  const float* l_l2g = (const float*)d_in[21];
  const float* l_l2b = (const float*)d_in[22];
  const float* l_mow = (const float*)d_in[23];
  const float* l_mob = (const float*)d_in[24];
  float* out = (float*)d_out;
  float* ws  = (float*)d_ws;

  // workspace layout (float offsets; bf16 regions hold 2 vals per float slot)
  float* g_qkv  = ws + 4096;     // 24576
  float* g_o    = ws + 28672;    // 8192
  float* g_vec  = ws + 36864;    // 2048
  float* g_part = ws + 38912;    // 1728
  float* res    = ws + 40960;    // 442368 f32
  u16*   eln_bf = (u16*)(ws + 483328);   // 442368 u16
  u16*   WcatT  = (u16*)(ws + 704512);   // 786432 u16 [3072 j][256 c]
  u16*   woT    = (u16*)(ws + 1097728);  // 262144 u16 [256][1024]
  u16*   moB    = (u16*)(ws + 1228800);  // 65536  u16
  float* qkv    = ws + 1261568;  // 5308416 f32
  u16*   o_buf  = (u16*)(ws + 6569984);  // 1769472 u16
  float* proj   = ws + 7454720;  // 2 x 442368 f32 (split-K partials)
  u16*   t2b    = (u16*)(ws + 8339456);  // 442368 u16
  float* part_wo= ws + 8560640;  // 65536 (32 kc x 8 b x 256 c)
  float* t2g    = ws + 8626176;  // 2048

  // L1: local tok + weight prep rider
  k_l_tok_prep<<<3008, 256, 0, stream>>>(x, l_pw, l_pb, l_l1g, l_l1b,
                                         res, eln_bf, g_part,
                                         l_wq, l_wk, l_wv, l_wo, l_mow,
                                         WcatT, woT, moB);
  // L2: local qkv GEMM + global qkv rider
  k_gemm_qkv_fused<<<1344, 256, 0, stream>>>(eln_bf, WcatT, qkv,
                                             g_part, g_tw, g_tb, g_l1g, g_l1b,
                                             g_wq, g_wk, g_wv, g_qkv);
  // L3: local attention + global attn rider
  k_l_attn_fused<<<896, 256, 0, stream>>>(qkv, o_buf, g_qkv, g_o);
  // L4: split-K wo GEMM + global wo rider
  k_gemm_sk_fused<<<248, 256, 0, stream>>>(o_buf, woT, proj, g_o, g_wo, part_wo);
  // L5: local LN2 + global LN2 rider
  k_l_ln2_fused<<<1736, 256, 0, stream>>>(proj, proj + 442368, res,
                                          l_l2g, l_l2b, t2b,
                                          part_wo, g_part, g_tw, g_tb,
                                          g_l2g, g_l2b, t2g);
  // L6: global mo
  k_g_mo<<<32, 256, 0, stream>>>(t2g, g_mow, g_mob, g_vec);
  // L7: mo GEMM + fused final (coalesced epilogue)
  k_gemm_mo_final<<<dim3(27, 4), 256, 0, stream>>>(t2b, moB, x, g_vec, l_mob, out);
}

// Round 12
// 108.456 us; speedup vs baseline: 2.0825x; 1.0654x over previous
//
#include <hip/hip_runtime.h>
#include <stdint.h>
#include <math.h>

#define DEVFN __device__ __forceinline__
typedef unsigned short u16;
typedef short bf16x8 __attribute__((ext_vector_type(8)));
typedef float f32x4  __attribute__((ext_vector_type(4)));

// ---------------------------------------------------------------- helpers
DEVFN float blk_sum(float v, float* s4) {          // 256-thread block sum
  #pragma unroll
  for (int o = 32; o > 0; o >>= 1) v += __shfl_down(v, o, 64);
  __syncthreads();
  if ((threadIdx.x & 63) == 0) s4[threadIdx.x >> 6] = v;
  __syncthreads();
  return s4[0] + s4[1] + s4[2] + s4[3];
}

DEVFN float gelu_f(float x) {
  return 0.5f * x * (1.f + erff(x * 0.7071067811865475f));
}

DEVFN u16 bf16_rne(float f) {                      // fp32 -> bf16 round-nearest-even
  uint32_t u = __float_as_uint(f);
  return (u16)((u + 0x7fffu + ((u >> 16) & 1u)) >> 16);
}

DEVFN float bf2f(u16 v) { return __uint_as_float(((uint32_t)v) << 16); }

// async global->LDS, 16B per lane. LDS dest is wave-uniform base + lane*16.
DEVFN void gload16(const u16* g, u16* l) {
  auto gp = (const __attribute__((address_space(1))) uint32_t*)(uintptr_t)g;
  auto lp = (__attribute__((address_space(3))) uint32_t*)(uintptr_t)l;
  __builtin_amdgcn_global_load_lds(gp, lp, 16, 0, 0);
}

// ---------------------------------------------------------------- L1: local tok + weight prep rider
DEVFN void trc_tile(const float* __restrict__ in, u16* __restrict__ out,
                    int R, int C, int r0, int c0, float (*tile)[33], int tid) {
  int tx = tid & 31, ty = tid >> 5;
  for (int i = ty; i < 32; i += 8) tile[i][tx] = in[(size_t)(r0 + i) * C + c0 + tx];
  __syncthreads();
  for (int i = ty; i < 32; i += 8)
    out[(size_t)(c0 + i) * R + r0 + tx] = bf16_rne(tile[tx][i]);
}

// blocks [0,1728): patch embed + LN1 (+ raw-x partial sums, 8x over-counted).
// blocks [1728,3008): weight prep (wq/wk/wv/wo transpose+cast, mo cast).
__global__ __launch_bounds__(256) void k_l_tok_prep(
    const float* __restrict__ x, const float* __restrict__ pw,
    const float* __restrict__ pb, const float* __restrict__ g1,
    const float* __restrict__ b1, float* __restrict__ res,
    u16* __restrict__ eln_bf, float* __restrict__ g_part,
    const float* __restrict__ wq, const float* __restrict__ wk,
    const float* __restrict__ wv, const float* __restrict__ wo,
    const float* __restrict__ mow, u16* __restrict__ WcatT,
    u16* __restrict__ woT, u16* __restrict__ moB) {
  __shared__ __align__(16) char smem[8448];
  int bid0 = blockIdx.x, tid = threadIdx.x;
  if (bid0 < 1728) {
    float* pws = (float*)smem;
    float* s4 = (float*)(smem + 256);
    int t = bid0;
    int b = t / 216, s = t % 216;
    int z = s / 36, y = (s / 6) % 6, xx = s % 6;
    int d = z >> 1, p1 = z & 1, hh = y >> 1, p2 = y & 1, ww = xx >> 1, p3 = xx & 1;
    int p = p1 * 4 + p2 * 2 + p3;
    int c = tid;
    if (c < 64) pws[c] = pw[c];
    __syncthreads();
    const float* xb = x + (b * 256 + c) * 216 + (2 * d) * 36 + (2 * hh) * 6 + 2 * ww;
    float v = pb[p];
    float xs = 0.f;
    #pragma unroll
    for (int q1 = 0; q1 < 2; ++q1)
      #pragma unroll
      for (int q2 = 0; q2 < 2; ++q2)
        #pragma unroll
        for (int q3 = 0; q3 < 2; ++q3) {
          float xv = xb[q1 * 36 + q2 * 6 + q3];
          xs += xv;
          v += xv * pws[p * 8 + (q1 * 4 + q2 * 2 + q3)];
        }
    float bs = blk_sum(xs, s4);
    if (c == 0) g_part[t] = bs;
    res[t * 256 + c] = v;
    float mu = blk_sum(v, s4) * (1.f / 256.f);
    float dd = v - mu;
    float var = blk_sum(dd * dd, s4) * (1.f / 256.f);
    eln_bf[t * 256 + c] = bf16_rne(dd * rsqrtf(var + 1e-6f) * g1[c] + b1[c]);
  } else {
    float (*tile)[33] = (float(*)[33])smem;
    int bid = bid0 - 1728;
    if (bid < 768) {            // wq/wk/wv: [256][1024] -> [1024][256]
      int which = bid >> 8, b2 = bid & 255;
      const float* in = (which == 0) ? wq : (which == 1) ? wk : wv;
      u16* out = WcatT + which * 262144;
      int r0 = (b2 & 7) * 32, c0 = (b2 >> 3) * 32;
      trc_tile(in, out, 256, 1024, r0, c0, tile, tid);
    } else if (bid < 1024) {    // wo: [1024][256] -> [256][1024]
      int b2 = bid - 768;
      int r0 = (b2 & 31) * 32, c0 = (b2 >> 5) * 32;
      trc_tile(wo, woT, 1024, 256, r0, c0, tile, tid);
    } else {                    // mo_w cast
      int i = (bid - 1024) * 256 + tid;
      moB[i] = bf16_rne(mow[i]);
    }
  }
}

// ---------------------------------------------------------------- L2: local qkv GEMM + global qkv rider
// blocks [0,1296): bf16 MFMA GEMM qkv (M=1728,N=3072,K=256), 64x64 tile,
// global_load_lds staging ([chunk][row][16B] layout, conflict-free b128 reads),
// OUTPUT IN BF16 (identical RNE rounding the attention applied anyway).
// blocks [1296,1344): fused global tok+LN1+qkv (closed-form LN stats).
__global__ __launch_bounds__(256) void k_gemm_qkv_fused(
    const u16* __restrict__ A, const u16* __restrict__ BT, u16* __restrict__ C,
    const float* __restrict__ g_part, const float* __restrict__ tw_,
    const float* __restrict__ tb_, const float* __restrict__ g1,
    const float* __restrict__ b1, const float* __restrict__ wq,
    const float* __restrict__ wk, const float* __restrict__ wv,
    float* __restrict__ gqkv) {
  __shared__ __align__(16) char smem[16640];
  int bid = blockIdx.x, tid = threadIdx.x;
  if (bid < 1296) {
    const int N = 3072, K = 256;
    u16* aL = (u16*)smem;          // 2048 u16: 4 chunks x 64 rows x 16B
    u16* bL = (u16*)smem + 2048;   // 2048 u16
    int rowblk = (bid % 27) * 64, colblk = (bid / 27) * 64;
    int lane = tid & 63, w = tid >> 6;
    int wr = (w >> 1) * 32, wc = (w & 1) * 32;
    int fm = lane & 15, lg = lane >> 4;
    f32x4 acc[2][2] = {};
    for (int kt = 0; kt < K; kt += 32) {
      __syncthreads();
      gload16(&A[(size_t)(rowblk + lane) * K + kt + w * 8], aL + w * 512);
      gload16(&BT[(size_t)(colblk + lane) * K + kt + w * 8], bL + w * 512);
      __syncthreads();
      bf16x8 bn[2];
      #pragma unroll
      for (int ni = 0; ni < 2; ++ni)
        bn[ni] = *(const bf16x8*)&bL[lg * 512 + (wc + ni * 16 + fm) * 8];
      #pragma unroll
      for (int mi = 0; mi < 2; ++mi) {
        bf16x8 af = *(const bf16x8*)&aL[lg * 512 + (wr + mi * 16 + fm) * 8];
        #pragma unroll
        for (int ni = 0; ni < 2; ++ni)
          acc[mi][ni] = __builtin_amdgcn_mfma_f32_16x16x32_bf16(af, bn[ni], acc[mi][ni], 0, 0, 0);
      }
    }
    int crow0 = rowblk + wr + lg * 4;
    int ccol  = colblk + wc + fm;
    #pragma unroll
    for (int mi = 0; mi < 2; ++mi)
      #pragma unroll
      for (int ni = 0; ni < 2; ++ni)
        #pragma unroll
        for (int r = 0; r < 4; ++r)
          C[(size_t)(crow0 + mi * 16 + r) * N + ccol + ni * 16] = bf16_rne(acc[mi][ni][r]);
  } else {
    float* ts = (float*)smem;                       // 2048 f
    float (*red)[4][8] = (float(*)[4][8])(smem + 8192);
    float* s4 = (float*)(smem + 16384);
    float* m_s = (float*)(smem + 16400);
    int rb = bid - 1296;
    float tw = tw_[tid], tb = tb_[tid], gg = g1[tid], bb = b1[tid];
    float S1 = blk_sum(tw, s4);
    float S2 = blk_sum(tw * tw, s4);
    float S3 = blk_sum(tb, s4);
    float S4 = blk_sum(tb * tb, s4);
    float S5 = blk_sum(tw * tb, s4);
    {
      int b = tid >> 5, sl = tid & 31;
      float a = 0.f;
      for (int k = sl; k < 216; k += 32) a += g_part[b * 216 + k];
      #pragma unroll
      for (int o = 16; o > 0; o >>= 1) a += __shfl_down(a, o, 32);
      if (sl == 0) m_s[b] = a * (1.f / 442368.f);   // 8 * 55296 over-count
    }
    __syncthreads();
    #pragma unroll
    for (int b = 0; b < 8; ++b) {
      float m = m_s[b];
      float mu = (m * S1 + S3) * (1.f / 256.f);
      float var = (m * m * S2 + 2.f * m * S5 + S4) * (1.f / 256.f) - mu * mu;
      ts[b * 256 + tid] = (m * tw + tb - mu) * rsqrtf(var + 1e-6f) * gg + bb;
    }
    __syncthreads();
    int col0 = rb * 64;
    int cl = tid & 63, kq = tid >> 6;
    int col = col0 + cl;
    int m = col >> 10, cc = col & 1023;
    const float* W = (m == 0) ? wq : (m == 1) ? wk : wv;
    float acc[8] = {};
    for (int c = kq * 64; c < kq * 64 + 64; ++c) {
      float w = W[c * 1024 + cc];
      #pragma unroll
      for (int b = 0; b < 8; ++b) acc[b] = fmaf(ts[b * 256 + c], w, acc[b]);
    }
    #pragma unroll
    for (int b = 0; b < 8; ++b) red[cl][kq][b] = acc[b];
    __syncthreads();
    if (kq == 0) {
      #pragma unroll
      for (int b = 0; b < 8; ++b)
        gqkv[b * 3072 + col] = red[cl][0][b] + red[cl][1][b] + red[cl][2][b] + red[cl][3][b];
    }
  }
}

// ---------------------------------------------------------------- L3: local attention + global attn rider
// blocks [0,864): MFMA local attention (n=bid>>2, h=bid&3), qkv now bf16.
// blocks [864,896): rank-1 global attention.
__global__ __launch_bounds__(256) void k_l_attn_fused(
    const u16* __restrict__ qkv, u16* __restrict__ o_buf,
    const float* __restrict__ gq, float* __restrict__ g_o) {
  __shared__ __align__(16) uint4 Qb[256], Kb[256];
  __shared__ __align__(16) u16 vt[16][264];
  __shared__ __align__(16) u16 Pl[256][72];
  __shared__ float rqA[64][4], rkA[64][4], rlq[64][4], rlk[64][4], s_ab[2];
  int bid = blockIdx.x, tid = threadIdx.x;
  if (bid >= 864) {                       // ---- global attn rider
    float* ks = (float*)Qb;               // overlay: 1KB
    float* vs = ks + 256;
    float* s4 = (float*)Kb;
    int idx = bid - 864;
    int b = idx >> 2, h = idx & 3;
    int i = tid;
    const float* base = gq + b * 3072 + h * 256;
    float q = base[i];
    float k = base[1024 + i];
    ks[i] = k;
    vs[i] = base[2048 + i];
    float sq  = blk_sum(q, s4);
    float sq2 = blk_sum(q * q, s4);
    float sk  = blk_sum(k, s4);
    float sk2 = blk_sum(k * k, s4);
    float tot  = sq * sk * (1.f / 65536.f);
    float tot2 = sq2 * sk2 * (1.f / 65536.f);
    float rstd = rsqrtf(tot2 - tot * tot + 1e-5f);
    float A = rstd, B = -tot * rstd;
    float den = 0.f, num = 0.f;
    for (int j = 0; j < 256; ++j) {
      float w = __expf(fmaf(q * ks[j], A, B));
      den += w; num += w * vs[j];
    }
    g_o[b * 1024 + (i << 2) + h] = num / den;
    return;
  }
  int n = bid >> 2, h = bid & 3;
  int b = n / 27, patch = n % 27;
  int bz = 2 * (patch / 9), by = 2 * ((patch / 3) % 3), bx = 2 * (patch % 3);
  {
    int c = tid;
    u16 qv[8], kv[8], vv[8];
    #pragma unroll
    for (int p = 0; p < 8; ++p) {
      int t_l = b * 216 + (bz + (p >> 2)) * 36 + (by + ((p >> 1) & 1)) * 6 + (bx + (p & 1));
      const u16* row = qkv + (size_t)t_l * 3072 + (c << 2) + h;
      qv[p] = row[0]; kv[p] = row[1024]; vv[p] = row[2048];
    }
    uint32_t qw[4], kw[4];
    #pragma unroll
    for (int i = 0; i < 4; ++i) {
      qw[i] = (uint32_t)qv[2 * i] | ((uint32_t)qv[2 * i + 1] << 16);
      kw[i] = (uint32_t)kv[2 * i] | ((uint32_t)kv[2 * i + 1] << 16);
    }
    Qb[c] = make_uint4(qw[0], qw[1], qw[2], qw[3]);
    Kb[c] = make_uint4(kw[0], kw[1], kw[2], kw[3]);
    #pragma unroll
    for (int p = 0; p < 8; ++p) vt[p][c] = vv[p];
    vt[8][c] = 0x3F80u;                  // bf16(1.0): denominator ones-row
    #pragma unroll
    for (int r2 = 9; r2 < 16; ++r2) vt[r2][c] = 0;
  }
  __syncthreads();
  {
    int p = tid & 63, chunk = tid >> 6;
    int d = p >> 3, e = p & 7;
    float aq = 0.f, ak = 0.f, lq = 0.f, lk = 0.f;
    for (int cc = chunk * 64; cc < chunk * 64 + 64; ++cc) {
      const u16* qr = (const u16*)&Qb[cc];
      const u16* kr = (const u16*)&Kb[cc];
      float qd = bf2f(qr[d]), qe = bf2f(qr[e]);
      float kd = bf2f(kr[d]), ke = bf2f(kr[e]);
      aq = fmaf(qd, qe, aq); ak = fmaf(kd, ke, ak);
      if (e == 0) { lq += qd; lk += kd; }
    }
    rqA[p][chunk] = aq; rkA[p][chunk] = ak; rlq[p][chunk] = lq; rlk[p][chunk] = lk;
    __syncthreads();
    if (tid < 64) {
      float gq2 = rqA[tid][0] + rqA[tid][1] + rqA[tid][2] + rqA[tid][3];
      float gk = rkA[tid][0] + rkA[tid][1] + rkA[tid][2] + rkA[tid][3];
      float vprod = gq2 * gk, vmu = 0.f;
      if ((tid & 7) == 0) {
        float slq = rlq[tid][0] + rlq[tid][1] + rlq[tid][2] + rlq[tid][3];
        float slk = rlk[tid][0] + rlk[tid][1] + rlk[tid][2] + rlk[tid][3];
        vmu = slq * slk;
      }
      #pragma unroll
      for (int o = 32; o > 0; o >>= 1) {
        vprod += __shfl_down(vprod, o, 64);
        vmu   += __shfl_down(vmu, o, 64);
      }
      if (tid == 0) {
        float mu = vmu * (1.f / 65536.f), m2 = vprod * (1.f / 65536.f);
        float rstd = rsqrtf(m2 - mu * mu + 1e-5f);
        s_ab[0] = rstd; s_ab[1] = -mu * rstd;
      }
    }
    __syncthreads();
  }
  float Af = s_ab[0], Bf = s_ab[1];
  int lane = tid & 63, w = tid >> 6;
  int l15 = lane & 15, lg = lane >> 4;
  bf16x8 qf[4];
  #pragma unroll
  for (int qt = 0; qt < 4; ++qt)
    qf[qt] = *(const bf16x8*)&Qb[w * 64 + qt * 16 + l15];
  f32x4 acc_o[4] = {};
  #pragma unroll 1
  for (int jc = 0; jc < 4; ++jc) {
    bf16x8 kf[4];
    #pragma unroll
    for (int jt = 0; jt < 4; ++jt) {
      bf16x8 z = {};
      if (lg == 0) z = *(const bf16x8*)&Kb[jc * 64 + jt * 16 + l15];
      kf[jt] = z;
    }
    #pragma unroll
    for (int jt = 0; jt < 4; ++jt) {
      #pragma unroll
      for (int qt = 0; qt < 4; ++qt) {
        f32x4 zc = {};
        f32x4 s = __builtin_amdgcn_mfma_f32_16x16x32_bf16(kf[jt], qf[qt], zc, 0, 0, 0);
        float e0 = __expf(fmaf(s[0], Af, Bf));
        float e1 = __expf(fmaf(s[1], Af, Bf));
        float e2 = __expf(fmaf(s[2], Af, Bf));
        float e3 = __expf(fmaf(s[3], Af, Bf));
        uint32_t w0 = (__float_as_uint(e0) >> 16) | (__float_as_uint(e1) & 0xFFFF0000u);
        uint32_t w1 = (__float_as_uint(e2) >> 16) | (__float_as_uint(e3) & 0xFFFF0000u);
        int q = w * 64 + qt * 16 + l15;
        *(uint2*)&Pl[q][jt * 16 + lg * 4] = make_uint2(w0, w1);
      }
    }
    #pragma unroll
    for (int ks2 = 0; ks2 < 2; ++ks2) {
      bf16x8 vf = *(const bf16x8*)&vt[l15][jc * 64 + ks2 * 32 + lg * 8];
      #pragma unroll
      for (int qt = 0; qt < 4; ++qt) {
        bf16x8 pf = *(const bf16x8*)&Pl[w * 64 + qt * 16 + l15][ks2 * 32 + lg * 8];
        acc_o[qt] = __builtin_amdgcn_mfma_f32_16x16x32_bf16(pf, vf, acc_o[qt], 0, 0, 0);
      }
    }
  }
  int src = ((lane & 48) + 8) << 2;
  int p = l15;
  int t_l = b * 216 + (bz + (p >> 2)) * 36 + (by + ((p >> 1) & 1)) * 6 + (bx + (p & 1));
  #pragma unroll
  for (int qt = 0; qt < 4; ++qt) {
    #pragma unroll
    for (int r = 0; r < 4; ++r) {
      float den = __int_as_float(__builtin_amdgcn_ds_bpermute(src, __float_as_int(acc_o[qt][r])));
      if (p < 8) {
        int q = w * 64 + qt * 16 + lg * 4 + r;
        o_buf[(size_t)t_l * 1024 + (q << 2) + h] = bf16_rne(acc_o[qt][r] / den);
      }
    }
  }
}

// ---------------------------------------------------------------- L4: split-K wo GEMM + global wo rider
// blocks [0,216): split-K bf16 GEMM (M=1728,N=256,K=1024, 2 K-halves),
// global_load_lds staging. blocks [216,248): global wo partials.
__global__ __launch_bounds__(256) void k_gemm_sk_fused(
    const u16* __restrict__ A, const u16* __restrict__ BT, float* __restrict__ Cp,
    const float* __restrict__ g_o, const float* __restrict__ wo,
    float* __restrict__ part) {
  __shared__ __align__(16) char smem[8192];
  int bid = blockIdx.x, tid = threadIdx.x;
  if (bid < 216) {
    const int M = 1728, N = 256, K = 1024;
    u16* aL = (u16*)smem;
    u16* bL = (u16*)smem + 2048;
    int rowblk = (bid % 27) * 64, colblk = ((bid / 27) & 3) * 64;
    int kz = bid / 108, khalf = K >> 1;
    float* C = Cp + (size_t)kz * M * N;
    int lane = tid & 63, w = tid >> 6;
    int wr = (w >> 1) * 32, wc = (w & 1) * 32;
    int fm = lane & 15, lg = lane >> 4;
    f32x4 acc[2][2] = {};
    for (int kt = kz * khalf; kt < (kz + 1) * khalf; kt += 32) {
      __syncthreads();
      gload16(&A[(size_t)(rowblk + lane) * K + kt + w * 8], aL + w * 512);
      gload16(&BT[(size_t)(colblk + lane) * K + kt + w * 8], bL + w * 512);
      __syncthreads();
      bf16x8 bn[2];
      #pragma unroll
      for (int ni = 0; ni < 2; ++ni)
        bn[ni] = *(const bf16x8*)&bL[lg * 512 + (wc + ni * 16 + fm) * 8];
      #pragma unroll
      for (int mi = 0; mi < 2; ++mi) {
        bf16x8 af = *(const bf16x8*)&aL[lg * 512 + (wr + mi * 16 + fm) * 8];
        #pragma unroll
        for (int ni = 0; ni < 2; ++ni)
          acc[mi][ni] = __builtin_amdgcn_mfma_f32_16x16x32_bf16(af, bn[ni], acc[mi][ni], 0, 0, 0);
      }
    }
    int crow0 = rowblk + wr + lg * 4;
    int ccol  = colblk + wc + fm;
    #pragma unroll
    for (int mi = 0; mi < 2; ++mi)
      #pragma unroll
      for (int ni = 0; ni < 2; ++ni)
        #pragma unroll
        for (int r = 0; r < 4; ++r)
          C[(size_t)(crow0 + mi * 16 + r) * N + ccol + ni * 16] = acc[mi][ni][r];
  } else {
    float* os = (float*)smem;               // 8 x 32
    int kc = bid - 216;
    os[tid] = g_o[(tid >> 5) * 1024 + kc * 32 + (tid & 31)];
    __syncthreads();
    float acc[8] = {};
    #pragma unroll
    for (int kk = 0; kk < 32; ++kk) {
      float w = wo[(size_t)(kc * 32 + kk) * 256 + tid];
      #pragma unroll
      for (int b = 0; b < 8; ++b) acc[b] = fmaf(os[b * 32 + kk], w, acc[b]);
    }
    #pragma unroll
    for (int b = 0; b < 8; ++b) part[kc * 2048 + b * 256 + tid] = acc[b];
  }
}

// ---------------------------------------------------------------- L5: local LN2 + global LN2 rider
__global__ __launch_bounds__(256) void k_l_ln2_fused(
    const float* __restrict__ proj0, const float* __restrict__ proj1,
    const float* __restrict__ res, const float* __restrict__ g2,
    const float* __restrict__ b2, u16* __restrict__ t2b,
    const float* __restrict__ part, const float* __restrict__ g_part,
    const float* __restrict__ tw_, const float* __restrict__ tb_,
    const float* __restrict__ gg2, const float* __restrict__ gb2,
    float* __restrict__ t2g) {
  __shared__ float s4[4];
  int bid = blockIdx.x, c = threadIdx.x;
  if (bid < 1728) {
    int t = bid;
    float v = proj0[t * 256 + c] + proj1[t * 256 + c] + res[t * 256 + c];
    float mu = blk_sum(v, s4) * (1.f / 256.f);
    float d = v - mu;
    float var = blk_sum(d * d, s4) * (1.f / 256.f);
    t2b[t * 256 + c] = bf16_rne(d * rsqrtf(var + 1e-6f) * g2[c] + b2[c]);
  } else {
    int b = bid - 1728;
    float a = (c < 216) ? g_part[b * 216 + c] : 0.f;
    float m = blk_sum(a, s4) * (1.f / 442368.f);
    float v = m * tw_[c] + tb_[c];
    #pragma unroll
    for (int kc = 0; kc < 32; ++kc) v += part[kc * 2048 + b * 256 + c];
    float mu = blk_sum(v, s4) * (1.f / 256.f);
    float d = v - mu;
    float var = blk_sum(d * d, s4) * (1.f / 256.f);
    t2g[b * 256 + c] = d * rsqrtf(var + 1e-6f) * gg2[c] + gb2[c];
  }
}

// ---------------------------------------------------------------- L6: global mo (standalone)
__global__ __launch_bounds__(256) void k_g_mo(
    const float* __restrict__ t2g, const float* __restrict__ mow,
    const float* __restrict__ mob, float* __restrict__ g_vec) {
  __shared__ float ts[2048];
  int tid = threadIdx.x;
  for (int i = tid; i < 2048; i += 256) ts[i] = t2g[i];
  __syncthreads();
  int ol = tid >> 5, cs = tid & 31;
  int o = blockIdx.x * 8 + ol;
  const float* wrow = mow + (size_t)o * 256;
  float acc[8] = {};
  #pragma unroll
  for (int i = 0; i < 8; ++i) {
    float w = wrow[i * 32 + cs];
    #pragma unroll
    for (int b = 0; b < 8; ++b) acc[b] = fmaf(ts[b * 256 + i * 32 + cs], w, acc[b]);
  }
  #pragma unroll
  for (int b = 0; b < 8; ++b) {
    float v = acc[b];
    #pragma unroll
    for (int off = 16; off > 0; off >>= 1) v += __shfl_down(v, off, 32);
    if (cs == 0) g_vec[b * 256 + o] = gelu_f(v + mob[o]);
  }
}

// ---------------------------------------------------------------- L7: mo GEMM + fused final, LDS-transposed epilogue
__global__ __launch_bounds__(256) void k_gemm_mo_final(
    const u16* __restrict__ A, const u16* __restrict__ BT,
    const float* __restrict__ x, const float* __restrict__ gvec,
    const float* __restrict__ mob, float* __restrict__ out) {
  __shared__ __align__(16) char smem[16640];
  u16* aL = (u16*)smem;
  u16* bL = (u16*)smem + 2048;
  float (*ct)[65] = (float(*)[65])smem;       // reused after k-loop
  const int K = 256;
  int tid = threadIdx.x;
  int rowblk = blockIdx.x * 64, colblk = blockIdx.y * 64;
  int lane = tid & 63, w = tid >> 6;
  int wr = (w >> 1) * 32, wc = (w & 1) * 32;
  int fm = lane & 15, lg = lane >> 4;
  f32x4 acc[2][2] = {};
  for (int kt = 0; kt < K; kt += 32) {
    __syncthreads();
    gload16(&A[(size_t)(rowblk + lane) * K + kt + w * 8], aL + w * 512);
    gload16(&BT[(size_t)(colblk + lane) * K + kt + w * 8], bL + w * 512);
    __syncthreads();
    bf16x8 bn[2];
    #pragma unroll
    for (int ni = 0; ni < 2; ++ni)
      bn[ni] = *(const bf16x8*)&bL[lg * 512 + (wc + ni * 16 + fm) * 8];
    #pragma unroll
    for (int mi = 0; mi < 2; ++mi) {
      bf16x8 af = *(const bf16x8*)&aL[lg * 512 + (wr + mi * 16 + fm) * 8];
      #pragma unroll
      for (int ni = 0; ni < 2; ++ni)
        acc[mi][ni] = __builtin_amdgcn_mfma_f32_16x16x32_bf16(af, bn[ni], acc[mi][ni], 0, 0, 0);
    }
  }
  __syncthreads();                            // LDS now safe to repurpose
  int row_l0 = wr + lg * 4;
  #pragma unroll
  for (int mi = 0; mi < 2; ++mi)
    #pragma unroll
    for (int ni = 0; ni < 2; ++ni)
      #pragma unroll
      for (int r = 0; r < 4; ++r)
        ct[row_l0 + mi * 16 + r][wc + ni * 16 + fm] = acc[mi][ni][r];
  __syncthreads();
  int s_l = tid & 63;
  #pragma unroll 4
  for (int pass = 0; pass < 16; ++pass) {
    int col_l = (tid >> 6) * 16 + pass;
    int row = rowblk + s_l, col = colblk + col_l;
    int b = row / 216, s = row - b * 216;
    size_t idx = (size_t)b * 55296 + (size_t)col * 216 + s;
    out[idx] = x[idx] + gvec[b * 256 + col] + gelu_f(ct[s_l][col_l] + mob[col]);
  }
}

// ---------------------------------------------------------------- launcher
extern "C" void kernel_launch(void* const* d_in, const int* in_sizes, int n_in,
                              void* d_out, int out_size, void* d_ws, size_t ws_size,
                              hipStream_t stream) {
  const float* x     = (const float*)d_in[0];
  const float* g_tw  = (const float*)d_in[1];
  const float* g_tb  = (const float*)d_in[2];
  const float* g_l1g = (const float*)d_in[3];
  const float* g_l1b = (const float*)d_in[4];
  const float* g_wq  = (const float*)d_in[5];
  const float* g_wk  = (const float*)d_in[6];
  const float* g_wv  = (const float*)d_in[7];
  const float* g_wo  = (const float*)d_in[8];
  const float* g_l2g = (const float*)d_in[9];
  const float* g_l2b = (const float*)d_in[10];
  const float* g_mow = (const float*)d_in[11];
  const float* g_mob = (const float*)d_in[12];
  const float* l_pw  = (const float*)d_in[13];
  const float* l_pb  = (const float*)d_in[14];
  const float* l_l1g = (const float*)d_in[15];
  const float* l_l1b = (const float*)d_in[16];
  const float* l_wq  = (const float*)d_in[17];
  const float* l_wk  = (const float*)d_in[18];
  const float* l_wv  = (const float*)d_in[19];
  const float* l_wo  = (const float*)d_in[20];
  const float* l_l2g = (const float*)d_in[21];
  const float* l_l2b = (const float*)d_in[22];
  const float* l_mow = (const float*)d_in[23];
  const float* l_mob = (const float*)d_in[24];
  float* out = (float*)d_out;
  float* ws  = (float*)d_ws;

  // workspace layout (float offsets; bf16 regions hold 2 vals per float slot)
  float* g_qkv  = ws + 4096;     // 24576
  float* g_o    = ws + 28672;    // 8192
  float* g_vec  = ws + 36864;    // 2048
  float* g_part = ws + 38912;    // 1728
  float* res    = ws + 40960;    // 442368 f32
  u16*   eln_bf = (u16*)(ws + 483328);   // 442368 u16
  u16*   WcatT  = (u16*)(ws + 704512);   // 786432 u16 [3072 j][256 c]
  u16*   woT    = (u16*)(ws + 1097728);  // 262144 u16 [256][1024]
  u16*   moB    = (u16*)(ws + 1228800);  // 65536  u16
  u16*   qkvb   = (u16*)(ws + 1261568);  // 5308416 u16 (bf16 qkv)
  u16*   o_buf  = (u16*)(ws + 6569984);  // 1769472 u16
  float* proj   = ws + 7454720;  // 2 x 442368 f32 (split-K partials)
  u16*   t2b    = (u16*)(ws + 8339456);  // 442368 u16
  float* part_wo= ws + 8560640;  // 65536 (32 kc x 8 b x 256 c)
  float* t2g    = ws + 8626176;  // 2048

  // L1: local tok + weight prep rider
  k_l_tok_prep<<<3008, 256, 0, stream>>>(x, l_pw, l_pb, l_l1g, l_l1b,
                                         res, eln_bf, g_part,
                                         l_wq, l_wk, l_wv, l_wo, l_mow,
                                         WcatT, woT, moB);
  // L2: local qkv GEMM (bf16 out, global_load_lds) + global qkv rider
  k_gemm_qkv_fused<<<1344, 256, 0, stream>>>(eln_bf, WcatT, qkvb,
                                             g_part, g_tw, g_tb, g_l1g, g_l1b,
                                             g_wq, g_wk, g_wv, g_qkv);
  // L3: local attention (bf16 qkv) + global attn rider
  k_l_attn_fused<<<896, 256, 0, stream>>>(qkvb, o_buf, g_qkv, g_o);
  // L4: split-K wo GEMM + global wo rider
  k_gemm_sk_fused<<<248, 256, 0, stream>>>(o_buf, woT, proj, g_o, g_wo, part_wo);
  // L5: local LN2 + global LN2 rider
  k_l_ln2_fused<<<1736, 256, 0, stream>>>(proj, proj + 442368, res,
                                          l_l2g, l_l2b, t2b,
                                          part_wo, g_part, g_tw, g_tb,
                                          g_l2g, g_l2b, t2g);
  // L6: global mo
  k_g_mo<<<32, 256, 0, stream>>>(t2g, g_mow, g_mob, g_vec);
  // L7: mo GEMM + fused final (coalesced epilogue)
  k_gemm_mo_final<<<dim3(27, 4), 256, 0, stream>>>(t2b, moB, x, g_vec, l_mob, out);
}

// Round 13
// 99.778 us; speedup vs baseline: 2.2637x; 1.0870x over previous
//
#include <hip/hip_runtime.h>
#include <stdint.h>
#include <math.h>

#define DEVFN __device__ __forceinline__
typedef unsigned short u16;
typedef short bf16x8 __attribute__((ext_vector_type(8)));
typedef float f32x4  __attribute__((ext_vector_type(4)));

// ---------------------------------------------------------------- helpers
DEVFN float blk_sum(float v, float* s4) {          // 256-thread block sum
  #pragma unroll
  for (int o = 32; o > 0; o >>= 1) v += __shfl_down(v, o, 64);
  __syncthreads();
  if ((threadIdx.x & 63) == 0) s4[threadIdx.x >> 6] = v;
  __syncthreads();
  return s4[0] + s4[1] + s4[2] + s4[3];
}

DEVFN float gelu_f(float x) {
  return 0.5f * x * (1.f + erff(x * 0.7071067811865475f));
}

DEVFN u16 bf16_rne(float f) {                      // fp32 -> bf16 round-nearest-even
  uint32_t u = __float_as_uint(f);
  return (u16)((u + 0x7fffu + ((u >> 16) & 1u)) >> 16);
}

DEVFN float bf2f(u16 v) { return __uint_as_float(((uint32_t)v) << 16); }

// async global->LDS, 16B/lane; LDS dest = wave-uniform base + lane*16.
DEVFN void gload16(const u16* g, u16* l) {
  auto gp = (const __attribute__((address_space(1))) uint32_t*)(uintptr_t)g;
  auto lp = (__attribute__((address_space(3))) uint32_t*)(uintptr_t)l;
  __builtin_amdgcn_global_load_lds(gp, lp, 16, 0, 0);
}

// Stage 64 rows x 256 u16 (512B/row) of G (row stride gstride u16) into LDS
// linear [64][256], with XOR swizzle applied on the GLOBAL side (rule: linear
// dest + inverse-swizzled source + swizzled read): data (row, c16) lands at
// LDS (row, c16 ^ (row&7)). 8 issues/wave, 2 rows per issue.
DEVFN void stage64x256(const u16* G, size_t gstride, u16* L, int w, int lane) {
  #pragma unroll
  for (int i = 0; i < 8; ++i) {
    int row = w * 16 + 2 * i + (lane >> 5);
    int c16 = (lane & 31) ^ (row & 7);
    gload16(G + (size_t)row * gstride + c16 * 8, L + (w * 16 + 2 * i) * 256);
  }
}

// swizzled fragment read: row's k16-th 16B unit
DEVFN bf16x8 lread(const u16* L, int row, int k16) {
  return *(const bf16x8*)&L[row * 256 + ((k16 ^ (row & 7)) << 3)];
}

// ---------------------------------------------------------------- L1: local tok + weight prep rider
DEVFN void trc_tile(const float* __restrict__ in, u16* __restrict__ out,
                    int R, int C, int r0, int c0, float (*tile)[33], int tid) {
  int tx = tid & 31, ty = tid >> 5;
  for (int i = ty; i < 32; i += 8) tile[i][tx] = in[(size_t)(r0 + i) * C + c0 + tx];
  __syncthreads();
  for (int i = ty; i < 32; i += 8)
    out[(size_t)(c0 + i) * R + r0 + tx] = bf16_rne(tile[tx][i]);
}

__global__ __launch_bounds__(256) void k_l_tok_prep(
    const float* __restrict__ x, const float* __restrict__ pw,
    const float* __restrict__ pb, const float* __restrict__ g1,
    const float* __restrict__ b1, float* __restrict__ res,
    u16* __restrict__ eln_bf, float* __restrict__ g_part,
    const float* __restrict__ wq, const float* __restrict__ wk,
    const float* __restrict__ wv, const float* __restrict__ wo,
    const float* __restrict__ mow, u16* __restrict__ WcatT,
    u16* __restrict__ woT, u16* __restrict__ moB) {
  __shared__ __align__(16) char smem[8448];
  int bid0 = blockIdx.x, tid = threadIdx.x;
  if (bid0 < 1728) {
    float* pws = (float*)smem;
    float* s4 = (float*)(smem + 256);
    int t = bid0;
    int b = t / 216, s = t % 216;
    int z = s / 36, y = (s / 6) % 6, xx = s % 6;
    int d = z >> 1, p1 = z & 1, hh = y >> 1, p2 = y & 1, ww = xx >> 1, p3 = xx & 1;
    int p = p1 * 4 + p2 * 2 + p3;
    int c = tid;
    if (c < 64) pws[c] = pw[c];
    __syncthreads();
    const float* xb = x + (b * 256 + c) * 216 + (2 * d) * 36 + (2 * hh) * 6 + 2 * ww;
    float v = pb[p];
    float xs = 0.f;
    #pragma unroll
    for (int q1 = 0; q1 < 2; ++q1)
      #pragma unroll
      for (int q2 = 0; q2 < 2; ++q2)
        #pragma unroll
        for (int q3 = 0; q3 < 2; ++q3) {
          float xv = xb[q1 * 36 + q2 * 6 + q3];
          xs += xv;
          v += xv * pws[p * 8 + (q1 * 4 + q2 * 2 + q3)];
        }
    float bs = blk_sum(xs, s4);
    if (c == 0) g_part[t] = bs;
    res[t * 256 + c] = v;
    float mu = blk_sum(v, s4) * (1.f / 256.f);
    float dd = v - mu;
    float var = blk_sum(dd * dd, s4) * (1.f / 256.f);
    eln_bf[t * 256 + c] = bf16_rne(dd * rsqrtf(var + 1e-6f) * g1[c] + b1[c]);
  } else {
    float (*tile)[33] = (float(*)[33])smem;
    int bid = bid0 - 1728;
    if (bid < 768) {            // wq/wk/wv: [256][1024] -> [1024][256]
      int which = bid >> 8, b2 = bid & 255;
      const float* in = (which == 0) ? wq : (which == 1) ? wk : wv;
      u16* out = WcatT + which * 262144;
      int r0 = (b2 & 7) * 32, c0 = (b2 >> 3) * 32;
      trc_tile(in, out, 256, 1024, r0, c0, tile, tid);
    } else if (bid < 1024) {    // wo: [1024][256] -> [256][1024]
      int b2 = bid - 768;
      int r0 = (b2 & 31) * 32, c0 = (b2 >> 5) * 32;
      trc_tile(wo, woT, 1024, 256, r0, c0, tile, tid);
    } else {                    // mo_w cast
      int i = (bid - 1024) * 256 + tid;
      moB[i] = bf16_rne(mow[i]);
    }
  }
}

// ---------------------------------------------------------------- L2: local qkv GEMM + global qkv rider
// blocks [0,1296): full-K-preload MFMA GEMM (M=1728,N=3072,K=256).
// One vmcnt-drain + barrier total; swizzled LDS (conflict-free reads);
// bf16 output staged through LDS for full-line uint4 stores.
// blocks [1296,1344): fused global tok+LN1+qkv.
__global__ __launch_bounds__(256) void k_gemm_qkv_fused(
    const u16* __restrict__ A, const u16* __restrict__ BT, u16* __restrict__ C,
    const float* __restrict__ g_part, const float* __restrict__ tw_,
    const float* __restrict__ tb_, const float* __restrict__ g1,
    const float* __restrict__ b1, const float* __restrict__ wq,
    const float* __restrict__ wk, const float* __restrict__ wv,
    float* __restrict__ gqkv) {
  __shared__ __align__(16) char smem[65536];
  int bid = blockIdx.x, tid = threadIdx.x;
  if (bid < 1296) {
    const int N = 3072, K = 256;
    u16* aL = (u16*)smem;          // [64][256] swizzled
    u16* bL = (u16*)smem + 16384;  // [64][256] swizzled
    int rowblk = (bid % 27) * 64, colblk = (bid / 27) * 64;
    int lane = tid & 63, w = tid >> 6;
    int wr = (w >> 1) * 32, wc = (w & 1) * 32;
    int fm = lane & 15, lg = lane >> 4;
    stage64x256(A + (size_t)rowblk * K, K, aL, w, lane);
    stage64x256(BT + (size_t)colblk * K, K, bL, w, lane);
    __syncthreads();               // single drain of all 16 loads
    f32x4 acc[2][2] = {};
    #pragma unroll
    for (int kk = 0; kk < 8; ++kk) {
      int k16 = kk * 4 + lg;
      bf16x8 bn0 = lread(bL, wc + fm, k16);
      bf16x8 bn1 = lread(bL, wc + 16 + fm, k16);
      bf16x8 af0 = lread(aL, wr + fm, k16);
      bf16x8 af1 = lread(aL, wr + 16 + fm, k16);
      acc[0][0] = __builtin_amdgcn_mfma_f32_16x16x32_bf16(af0, bn0, acc[0][0], 0, 0, 0);
      acc[0][1] = __builtin_amdgcn_mfma_f32_16x16x32_bf16(af0, bn1, acc[0][1], 0, 0, 0);
      acc[1][0] = __builtin_amdgcn_mfma_f32_16x16x32_bf16(af1, bn0, acc[1][0], 0, 0, 0);
      acc[1][1] = __builtin_amdgcn_mfma_f32_16x16x32_bf16(af1, bn1, acc[1][1], 0, 0, 0);
    }
    __syncthreads();               // LDS safe to repurpose
    u16* ct = (u16*)smem;          // [64][64] bf16 C-tile
    #pragma unroll
    for (int mi = 0; mi < 2; ++mi)
      #pragma unroll
      for (int ni = 0; ni < 2; ++ni)
        #pragma unroll
        for (int r = 0; r < 4; ++r)
          ct[(wr + mi * 16 + lg * 4 + r) * 64 + wc + ni * 16 + fm] = bf16_rne(acc[mi][ni][r]);
    __syncthreads();
    #pragma unroll
    for (int pass = 0; pass < 2; ++pass) {
      int id = pass * 256 + tid;
      int r = id >> 3, u = id & 7;
      *(uint4*)&C[(size_t)(rowblk + r) * N + colblk + u * 8] = *(uint4*)&ct[r * 64 + u * 8];
    }
  } else {
    float* ts = (float*)smem;                       // 2048 f
    float (*red)[4][8] = (float(*)[4][8])(smem + 8192);
    float* s4 = (float*)(smem + 16384);
    float* m_s = (float*)(smem + 16400);
    int rb = bid - 1296;
    float tw = tw_[tid], tb = tb_[tid], gg = g1[tid], bb = b1[tid];
    float S1 = blk_sum(tw, s4);
    float S2 = blk_sum(tw * tw, s4);
    float S3 = blk_sum(tb, s4);
    float S4 = blk_sum(tb * tb, s4);
    float S5 = blk_sum(tw * tb, s4);
    {
      int b = tid >> 5, sl = tid & 31;
      float a = 0.f;
      for (int k = sl; k < 216; k += 32) a += g_part[b * 216 + k];
      #pragma unroll
      for (int o = 16; o > 0; o >>= 1) a += __shfl_down(a, o, 32);
      if (sl == 0) m_s[b] = a * (1.f / 442368.f);   // 8 * 55296 over-count
    }
    __syncthreads();
    #pragma unroll
    for (int b = 0; b < 8; ++b) {
      float m = m_s[b];
      float mu = (m * S1 + S3) * (1.f / 256.f);
      float var = (m * m * S2 + 2.f * m * S5 + S4) * (1.f / 256.f) - mu * mu;
      ts[b * 256 + tid] = (m * tw + tb - mu) * rsqrtf(var + 1e-6f) * gg + bb;
    }
    __syncthreads();
    int col0 = rb * 64;
    int cl = tid & 63, kq = tid >> 6;
    int col = col0 + cl;
    int m = col >> 10, cc = col & 1023;
    const float* W = (m == 0) ? wq : (m == 1) ? wk : wv;
    float acc[8] = {};
    for (int c = kq * 64; c < kq * 64 + 64; ++c) {
      float w = W[c * 1024 + cc];
      #pragma unroll
      for (int b = 0; b < 8; ++b) acc[b] = fmaf(ts[b * 256 + c], w, acc[b]);
    }
    #pragma unroll
    for (int b = 0; b < 8; ++b) red[cl][kq][b] = acc[b];
    __syncthreads();
    if (kq == 0) {
      #pragma unroll
      for (int b = 0; b < 8; ++b)
        gqkv[b * 3072 + col] = red[cl][0][b] + red[cl][1][b] + red[cl][2][b] + red[cl][3][b];
    }
  }
}

// ---------------------------------------------------------------- L3: local attention + global attn rider
__global__ __launch_bounds__(256) void k_l_attn_fused(
    const u16* __restrict__ qkv, u16* __restrict__ o_buf,
    const float* __restrict__ gq, float* __restrict__ g_o) {
  __shared__ __align__(16) uint4 Qb[256], Kb[256];
  __shared__ __align__(16) u16 vt[16][264];
  __shared__ __align__(16) u16 Pl[256][72];
  __shared__ float rqA[64][4], rkA[64][4], rlq[64][4], rlk[64][4], s_ab[2];
  int bid = blockIdx.x, tid = threadIdx.x;
  if (bid >= 864) {                       // ---- global attn rider
    float* ks = (float*)Qb;               // overlay: 1KB
    float* vs = ks + 256;
    float* s4 = (float*)Kb;
    int idx = bid - 864;
    int b = idx >> 2, h = idx & 3;
    int i = tid;
    const float* base = gq + b * 3072 + h * 256;
    float q = base[i];
    float k = base[1024 + i];
    ks[i] = k;
    vs[i] = base[2048 + i];
    float sq  = blk_sum(q, s4);
    float sq2 = blk_sum(q * q, s4);
    float sk  = blk_sum(k, s4);
    float sk2 = blk_sum(k * k, s4);
    float tot  = sq * sk * (1.f / 65536.f);
    float tot2 = sq2 * sk2 * (1.f / 65536.f);
    float rstd = rsqrtf(tot2 - tot * tot + 1e-5f);
    float A = rstd, B = -tot * rstd;
    float den = 0.f, num = 0.f;
    for (int j = 0; j < 256; ++j) {
      float w = __expf(fmaf(q * ks[j], A, B));
      den += w; num += w * vs[j];
    }
    g_o[b * 1024 + (i << 2) + h] = num / den;
    return;
  }
  int n = bid >> 2, h = bid & 3;
  int b = n / 27, patch = n % 27;
  int bz = 2 * (patch / 9), by = 2 * ((patch / 3) % 3), bx = 2 * (patch % 3);
  int tid2 = tid;
  {
    int c = tid2;
    u16 qv[8], kv[8], vv[8];
    #pragma unroll
    for (int p = 0; p < 8; ++p) {
      int t_l = b * 216 + (bz + (p >> 2)) * 36 + (by + ((p >> 1) & 1)) * 6 + (bx + (p & 1));
      const u16* row = qkv + (size_t)t_l * 3072 + (c << 2) + h;
      qv[p] = row[0]; kv[p] = row[1024]; vv[p] = row[2048];
    }
    uint32_t qw[4], kw[4];
    #pragma unroll
    for (int i = 0; i < 4; ++i) {
      qw[i] = (uint32_t)qv[2 * i] | ((uint32_t)qv[2 * i + 1] << 16);
      kw[i] = (uint32_t)kv[2 * i] | ((uint32_t)kv[2 * i + 1] << 16);
    }
    Qb[c] = make_uint4(qw[0], qw[1], qw[2], qw[3]);
    Kb[c] = make_uint4(kw[0], kw[1], kw[2], kw[3]);
    #pragma unroll
    for (int p = 0; p < 8; ++p) vt[p][c] = vv[p];
    vt[8][c] = 0x3F80u;                  // bf16(1.0): denominator ones-row
    #pragma unroll
    for (int r2 = 9; r2 < 16; ++r2) vt[r2][c] = 0;
  }
  __syncthreads();
  {
    int p = tid2 & 63, chunk = tid2 >> 6;
    int d = p >> 3, e = p & 7;
    float aq = 0.f, ak = 0.f, lq = 0.f, lk = 0.f;
    for (int cc = chunk * 64; cc < chunk * 64 + 64; ++cc) {
      const u16* qr = (const u16*)&Qb[cc];
      const u16* kr = (const u16*)&Kb[cc];
      float qd = bf2f(qr[d]), qe = bf2f(qr[e]);
      float kd = bf2f(kr[d]), ke = bf2f(kr[e]);
      aq = fmaf(qd, qe, aq); ak = fmaf(kd, ke, ak);
      if (e == 0) { lq += qd; lk += kd; }
    }
    rqA[p][chunk] = aq; rkA[p][chunk] = ak; rlq[p][chunk] = lq; rlk[p][chunk] = lk;
    __syncthreads();
    if (tid2 < 64) {
      float gq2 = rqA[tid2][0] + rqA[tid2][1] + rqA[tid2][2] + rqA[tid2][3];
      float gk = rkA[tid2][0] + rkA[tid2][1] + rkA[tid2][2] + rkA[tid2][3];
      float vprod = gq2 * gk, vmu = 0.f;
      if ((tid2 & 7) == 0) {
        float slq = rlq[tid2][0] + rlq[tid2][1] + rlq[tid2][2] + rlq[tid2][3];
        float slk = rlk[tid2][0] + rlk[tid2][1] + rlk[tid2][2] + rlk[tid2][3];
        vmu = slq * slk;
      }
      #pragma unroll
      for (int o = 32; o > 0; o >>= 1) {
        vprod += __shfl_down(vprod, o, 64);
        vmu   += __shfl_down(vmu, o, 64);
      }
      if (tid2 == 0) {
        float mu = vmu * (1.f / 65536.f), m2 = vprod * (1.f / 65536.f);
        float rstd = rsqrtf(m2 - mu * mu + 1e-5f);
        s_ab[0] = rstd; s_ab[1] = -mu * rstd;
      }
    }
    __syncthreads();
  }
  float Af = s_ab[0], Bf = s_ab[1];
  int lane = tid2 & 63, w = tid2 >> 6;
  int l15 = lane & 15, lg = lane >> 4;
  bf16x8 qf[4];
  #pragma unroll
  for (int qt = 0; qt < 4; ++qt)
    qf[qt] = *(const bf16x8*)&Qb[w * 64 + qt * 16 + l15];
  f32x4 acc_o[4] = {};
  #pragma unroll 1
  for (int jc = 0; jc < 4; ++jc) {
    bf16x8 kf[4];
    #pragma unroll
    for (int jt = 0; jt < 4; ++jt) {
      bf16x8 z = {};
      if (lg == 0) z = *(const bf16x8*)&Kb[jc * 64 + jt * 16 + l15];
      kf[jt] = z;
    }
    #pragma unroll
    for (int jt = 0; jt < 4; ++jt) {
      #pragma unroll
      for (int qt = 0; qt < 4; ++qt) {
        f32x4 zc = {};
        f32x4 s = __builtin_amdgcn_mfma_f32_16x16x32_bf16(kf[jt], qf[qt], zc, 0, 0, 0);
        float e0 = __expf(fmaf(s[0], Af, Bf));
        float e1 = __expf(fmaf(s[1], Af, Bf));
        float e2 = __expf(fmaf(s[2], Af, Bf));
        float e3 = __expf(fmaf(s[3], Af, Bf));
        uint32_t w0 = (__float_as_uint(e0) >> 16) | (__float_as_uint(e1) & 0xFFFF0000u);
        uint32_t w1 = (__float_as_uint(e2) >> 16) | (__float_as_uint(e3) & 0xFFFF0000u);
        int q = w * 64 + qt * 16 + l15;
        *(uint2*)&Pl[q][jt * 16 + lg * 4] = make_uint2(w0, w1);
      }
    }
    #pragma unroll
    for (int ks2 = 0; ks2 < 2; ++ks2) {
      bf16x8 vf = *(const bf16x8*)&vt[l15][jc * 64 + ks2 * 32 + lg * 8];
      #pragma unroll
      for (int qt = 0; qt < 4; ++qt) {
        bf16x8 pf = *(const bf16x8*)&Pl[w * 64 + qt * 16 + l15][ks2 * 32 + lg * 8];
        acc_o[qt] = __builtin_amdgcn_mfma_f32_16x16x32_bf16(pf, vf, acc_o[qt], 0, 0, 0);
      }
    }
  }
  int src = ((lane & 48) + 8) << 2;
  int p = l15;
  int t_l = b * 216 + (bz + (p >> 2)) * 36 + (by + ((p >> 1) & 1)) * 6 + (bx + (p & 1));
  #pragma unroll
  for (int qt = 0; qt < 4; ++qt) {
    #pragma unroll
    for (int r = 0; r < 4; ++r) {
      float den = __int_as_float(__builtin_amdgcn_ds_bpermute(src, __float_as_int(acc_o[qt][r])));
      if (p < 8) {
        int q = w * 64 + qt * 16 + lg * 4 + r;
        o_buf[(size_t)t_l * 1024 + (q << 2) + h] = bf16_rne(acc_o[qt][r] / den);
      }
    }
  }
}

// ---------------------------------------------------------------- L4: split-K wo GEMM + global wo rider
// blocks [0,216): split-K GEMM (M=1728,N=256,K=1024): per kz, 2 preload
// rounds of BK=256 (2 drains total vs 16); float4-coalesced epilogue.
// blocks [216,248): global wo partials.
__global__ __launch_bounds__(256) void k_gemm_sk_fused(
    const u16* __restrict__ A, const u16* __restrict__ BT, float* __restrict__ Cp,
    const float* __restrict__ g_o, const float* __restrict__ wo,
    float* __restrict__ part) {
  __shared__ __align__(16) char smem[65536];
  int bid = blockIdx.x, tid = threadIdx.x;
  if (bid < 216) {
    const int M = 1728, N = 256, K = 1024;
    u16* aL = (u16*)smem;
    u16* bL = (u16*)smem + 16384;
    int rowblk = (bid % 27) * 64, colblk = ((bid / 27) & 3) * 64;
    int kz = bid / 108;
    float* C = Cp + (size_t)kz * M * N;
    int lane = tid & 63, w = tid >> 6;
    int wr = (w >> 1) * 32, wc = (w & 1) * 32;
    int fm = lane & 15, lg = lane >> 4;
    f32x4 acc[2][2] = {};
    #pragma unroll 1
    for (int step = 0; step < 2; ++step) {
      int kt = kz * 512 + step * 256;
      __syncthreads();
      stage64x256(A + (size_t)rowblk * K + kt, K, aL, w, lane);
      stage64x256(BT + (size_t)colblk * K + kt, K, bL, w, lane);
      __syncthreads();
      #pragma unroll
      for (int kk = 0; kk < 8; ++kk) {
        int k16 = kk * 4 + lg;
        bf16x8 bn0 = lread(bL, wc + fm, k16);
        bf16x8 bn1 = lread(bL, wc + 16 + fm, k16);
        bf16x8 af0 = lread(aL, wr + fm, k16);
        bf16x8 af1 = lread(aL, wr + 16 + fm, k16);
        acc[0][0] = __builtin_amdgcn_mfma_f32_16x16x32_bf16(af0, bn0, acc[0][0], 0, 0, 0);
        acc[0][1] = __builtin_amdgcn_mfma_f32_16x16x32_bf16(af0, bn1, acc[0][1], 0, 0, 0);
        acc[1][0] = __builtin_amdgcn_mfma_f32_16x16x32_bf16(af1, bn0, acc[1][0], 0, 0, 0);
        acc[1][1] = __builtin_amdgcn_mfma_f32_16x16x32_bf16(af1, bn1, acc[1][1], 0, 0, 0);
      }
    }
    __syncthreads();
    float* ct = (float*)smem;       // [64][64] fp32 C-tile (16KB)
    #pragma unroll
    for (int mi = 0; mi < 2; ++mi)
      #pragma unroll
      for (int ni = 0; ni < 2; ++ni)
        #pragma unroll
        for (int r = 0; r < 4; ++r)
          ct[(wr + mi * 16 + lg * 4 + r) * 64 + wc + ni * 16 + fm] = acc[mi][ni][r];
    __syncthreads();
    #pragma unroll
    for (int pass = 0; pass < 4; ++pass) {
      int id = pass * 256 + tid;
      int r = id >> 4, u = id & 15;
      *(float4*)&C[(size_t)(rowblk + r) * N + colblk + u * 4] = *(float4*)&ct[r * 64 + u * 4];
    }
  } else {
    float* os = (float*)smem;               // 8 x 32
    int kc = bid - 216;
    os[tid] = g_o[(tid >> 5) * 1024 + kc * 32 + (tid & 31)];
    __syncthreads();
    float acc[8] = {};
    #pragma unroll
    for (int kk = 0; kk < 32; ++kk) {
      float w = wo[(size_t)(kc * 32 + kk) * 256 + tid];
      #pragma unroll
      for (int b = 0; b < 8; ++b) acc[b] = fmaf(os[b * 32 + kk], w, acc[b]);
    }
    #pragma unroll
    for (int b = 0; b < 8; ++b) part[kc * 2048 + b * 256 + tid] = acc[b];
  }
}

// ---------------------------------------------------------------- L5: local LN2 + global LN2 rider
__global__ __launch_bounds__(256) void k_l_ln2_fused(
    const float* __restrict__ proj0, const float* __restrict__ proj1,
    const float* __restrict__ res, const float* __restrict__ g2,
    const float* __restrict__ b2, u16* __restrict__ t2b,
    const float* __restrict__ part, const float* __restrict__ g_part,
    const float* __restrict__ tw_, const float* __restrict__ tb_,
    const float* __restrict__ gg2, const float* __restrict__ gb2,
    float* __restrict__ t2g) {
  __shared__ float s4[4];
  int bid = blockIdx.x, c = threadIdx.x;
  if (bid < 1728) {
    int t = bid;
    float v = proj0[t * 256 + c] + proj1[t * 256 + c] + res[t * 256 + c];
    float mu = blk_sum(v, s4) * (1.f / 256.f);
    float d = v - mu;
    float var = blk_sum(d * d, s4) * (1.f / 256.f);
    t2b[t * 256 + c] = bf16_rne(d * rsqrtf(var + 1e-6f) * g2[c] + b2[c]);
  } else {
    int b = bid - 1728;
    float a = (c < 216) ? g_part[b * 216 + c] : 0.f;
    float m = blk_sum(a, s4) * (1.f / 442368.f);
    float v = m * tw_[c] + tb_[c];
    #pragma unroll
    for (int kc = 0; kc < 32; ++kc) v += part[kc * 2048 + b * 256 + c];
    float mu = blk_sum(v, s4) * (1.f / 256.f);
    float d = v - mu;
    float var = blk_sum(d * d, s4) * (1.f / 256.f);
    t2g[b * 256 + c] = d * rsqrtf(var + 1e-6f) * gg2[c] + gb2[c];
  }
}

// ---------------------------------------------------------------- L6: global mo (standalone)
__global__ __launch_bounds__(256) void k_g_mo(
    const float* __restrict__ t2g, const float* __restrict__ mow,
    const float* __restrict__ mob, float* __restrict__ g_vec) {
  __shared__ float ts[2048];
  int tid = threadIdx.x;
  for (int i = tid; i < 2048; i += 256) ts[i] = t2g[i];
  __syncthreads();
  int ol = tid >> 5, cs = tid & 31;
  int o = blockIdx.x * 8 + ol;
  const float* wrow = mow + (size_t)o * 256;
  float acc[8] = {};
  #pragma unroll
  for (int i = 0; i < 8; ++i) {
    float w = wrow[i * 32 + cs];
    #pragma unroll
    for (int b = 0; b < 8; ++b) acc[b] = fmaf(ts[b * 256 + i * 32 + cs], w, acc[b]);
  }
  #pragma unroll
  for (int b = 0; b < 8; ++b) {
    float v = acc[b];
    #pragma unroll
    for (int off = 16; off > 0; off >>= 1) v += __shfl_down(v, off, 32);
    if (cs == 0) g_vec[b * 256 + o] = gelu_f(v + mob[o]);
  }
}

// ---------------------------------------------------------------- L7: mo GEMM + fused final
// Full-K preload + swizzled LDS; LDS-transposed coalesced epilogue.
__global__ __launch_bounds__(256) void k_gemm_mo_final(
    const u16* __restrict__ A, const u16* __restrict__ BT,
    const float* __restrict__ x, const float* __restrict__ gvec,
    const float* __restrict__ mob, float* __restrict__ out) {
  __shared__ __align__(16) char smem[65536];
  u16* aL = (u16*)smem;
  u16* bL = (u16*)smem + 16384;
  float (*ct)[65] = (float(*)[65])smem;       // reused after k-loop
  const int K = 256;
  int tid = threadIdx.x;
  int rowblk = blockIdx.x * 64, colblk = blockIdx.y * 64;
  int lane = tid & 63, w = tid >> 6;
  int wr = (w >> 1) * 32, wc = (w & 1) * 32;
  int fm = lane & 15, lg = lane >> 4;
  stage64x256(A + (size_t)rowblk * K, K, aL, w, lane);
  stage64x256(BT + (size_t)colblk * K, K, bL, w, lane);
  __syncthreads();
  f32x4 acc[2][2] = {};
  #pragma unroll
  for (int kk = 0; kk < 8; ++kk) {
    int k16 = kk * 4 + lg;
    bf16x8 bn0 = lread(bL, wc + fm, k16);
    bf16x8 bn1 = lread(bL, wc + 16 + fm, k16);
    bf16x8 af0 = lread(aL, wr + fm, k16);
    bf16x8 af1 = lread(aL, wr + 16 + fm, k16);
    acc[0][0] = __builtin_amdgcn_mfma_f32_16x16x32_bf16(af0, bn0, acc[0][0], 0, 0, 0);
    acc[0][1] = __builtin_amdgcn_mfma_f32_16x16x32_bf16(af0, bn1, acc[0][1], 0, 0, 0);
    acc[1][0] = __builtin_amdgcn_mfma_f32_16x16x32_bf16(af1, bn0, acc[1][0], 0, 0, 0);
    acc[1][1] = __builtin_amdgcn_mfma_f32_16x16x32_bf16(af1, bn1, acc[1][1], 0, 0, 0);
  }
  __syncthreads();                            // LDS safe to repurpose
  int row_l0 = wr + lg * 4;
  #pragma unroll
  for (int mi = 0; mi < 2; ++mi)
    #pragma unroll
    for (int ni = 0; ni < 2; ++ni)
      #pragma unroll
      for (int r = 0; r < 4; ++r)
        ct[row_l0 + mi * 16 + r][wc + ni * 16 + fm] = acc[mi][ni][r];
  __syncthreads();
  int s_l = tid & 63;
  #pragma unroll 4
  for (int pass = 0; pass < 16; ++pass) {
    int col_l = (tid >> 6) * 16 + pass;
    int row = rowblk + s_l, col = colblk + col_l;
    int b = row / 216, s = row - b * 216;
    size_t idx = (size_t)b * 55296 + (size_t)col * 216 + s;
    out[idx] = x[idx] + gvec[b * 256 + col] + gelu_f(ct[s_l][col_l] + mob[col]);
  }
}

// ---------------------------------------------------------------- launcher
extern "C" void kernel_launch(void* const* d_in, const int* in_sizes, int n_in,
                              void* d_out, int out_size, void* d_ws, size_t ws_size,
                              hipStream_t stream) {
  const float* x     = (const float*)d_in[0];
  const float* g_tw  = (const float*)d_in[1];
  const float* g_tb  = (const float*)d_in[2];
  const float* g_l1g = (const float*)d_in[3];
  const float* g_l1b = (const float*)d_in[4];
  const float* g_wq  = (const float*)d_in[5];
  const float* g_wk  = (const float*)d_in[6];
  const float* g_wv  = (const float*)d_in[7];
  const float* g_wo  = (const float*)d_in[8];
  const float* g_l2g = (const float*)d_in[9];
  const float* g_l2b = (const float*)d_in[10];
  const float* g_mow = (const float*)d_in[11];
  const float* g_mob = (const float*)d_in[12];
  const float* l_pw  = (const float*)d_in[13];
  const float* l_pb  = (const float*)d_in[14];
  const float* l_l1g = (const float*)d_in[15];
  const float* l_l1b = (const float*)d_in[16];
  const float* l_wq  = (const float*)d_in[17];
  const float* l_wk  = (const float*)d_in[18];
  const float* l_wv  = (const float*)d_in[19];
  const float* l_wo  = (const float*)d_in[20];
  const float* l_l2g = (const float*)d_in[21];
  const float* l_l2b = (const float*)d_in[22];
  const float* l_mow = (const float*)d_in[23];
  const float* l_mob = (const float*)d_in[24];
  float* out = (float*)d_out;
  float* ws  = (float*)d_ws;

  // workspace layout (float offsets; bf16 regions hold 2 vals per float slot)
  float* g_qkv  = ws + 4096;     // 24576
  float* g_o    = ws + 28672;    // 8192
  float* g_vec  = ws + 36864;    // 2048
  float* g_part = ws + 38912;    // 1728
  float* res    = ws + 40960;    // 442368 f32
  u16*   eln_bf = (u16*)(ws + 483328);   // 442368 u16
  u16*   WcatT  = (u16*)(ws + 704512);   // 786432 u16 [3072 j][256 c]
  u16*   woT    = (u16*)(ws + 1097728);  // 262144 u16 [256][1024]
  u16*   moB    = (u16*)(ws + 1228800);  // 65536  u16
  u16*   qkvb   = (u16*)(ws + 1261568);  // 5308416 u16 (bf16 qkv)
  u16*   o_buf  = (u16*)(ws + 6569984);  // 1769472 u16
  float* proj   = ws + 7454720;  // 2 x 442368 f32 (split-K partials)
  u16*   t2b    = (u16*)(ws + 8339456);  // 442368 u16
  float* part_wo= ws + 8560640;  // 65536 (32 kc x 8 b x 256 c)
  float* t2g    = ws + 8626176;  // 2048

  // L1: local tok + weight prep rider
  k_l_tok_prep<<<3008, 256, 0, stream>>>(x, l_pw, l_pb, l_l1g, l_l1b,
                                         res, eln_bf, g_part,
                                         l_wq, l_wk, l_wv, l_wo, l_mow,
                                         WcatT, woT, moB);
  // L2: local qkv GEMM (full-K preload) + global qkv rider
  k_gemm_qkv_fused<<<1344, 256, 0, stream>>>(eln_bf, WcatT, qkvb,
                                             g_part, g_tw, g_tb, g_l1g, g_l1b,
                                             g_wq, g_wk, g_wv, g_qkv);
  // L3: local attention (bf16 qkv) + global attn rider
  k_l_attn_fused<<<896, 256, 0, stream>>>(qkvb, o_buf, g_qkv, g_o);
  // L4: split-K wo GEMM (2-round preload) + global wo rider
  k_gemm_sk_fused<<<248, 256, 0, stream>>>(o_buf, woT, proj, g_o, g_wo, part_wo);
  // L5: local LN2 + global LN2 rider
  k_l_ln2_fused<<<1736, 256, 0, stream>>>(proj, proj + 442368, res,
                                          l_l2g, l_l2b, t2b,
                                          part_wo, g_part, g_tw, g_tb,
                                          g_l2g, g_l2b, t2g);
  // L6: global mo
  k_g_mo<<<32, 256, 0, stream>>>(t2g, g_mow, g_mob, g_vec);
  // L7: mo GEMM + fused final (full-K preload, coalesced epilogue)
  k_gemm_mo_final<<<dim3(27, 4), 256, 0, stream>>>(t2b, moB, x, g_vec, l_mob, out);
}